// Round 6
// baseline (624.371 us; speedup 1.0000x reference)
//
#include <hip/hip_runtime.h>
#include <math.h>

#define HRV 16
#define WRV 1024
#define NPIX 16384
#define NBEV 48400
#define BSZ 2

typedef __attribute__((ext_vector_type(8))) short short8;
typedef __attribute__((ext_vector_type(4))) float f32x4;

struct RVConsts {
  float steps[16];
  float means[16];
  float az_step_f;
  float pad_;
  double step_d;
  double az0;
  double az_half;
};

__device__ __forceinline__ float geluf(float x) {
  return 0.5f * x * (1.0f + erff(x * 0.70710678118654752440f));
}
__device__ __forceinline__ float sigmoidf_(float x) {
  return 1.0f / (1.0f + expf(-x));
}
__device__ __forceinline__ float softplusf_(float x) {
  return fmaxf(x, 0.0f) + log1pf(expf(-fabsf(x)));
}
__device__ __forceinline__ float azimf(int w, double step_d, double az0, double az_half) {
  double az = (double)w * step_d + az0;
  az += az_half;
  return (float)az;
}
__device__ __forceinline__ unsigned short f2bf(float f) {
  unsigned int u = __builtin_bit_cast(unsigned int, f);
  u = u + 0x7FFFu + ((u >> 16) & 1u);
  return (unsigned short)(u >> 16);
}
__device__ __forceinline__ float bf2f(unsigned short h) {
  unsigned int u = ((unsigned int)h) << 16;
  return __builtin_bit_cast(float, u);
}

// ---------------- K1: MFMA range-head conv1 (67->128) + Q0 conv (64->128) ----------------
__global__ __launch_bounds__(256) void k_rh1_q0(
    const float* __restrict__ x_rv,
    const unsigned short* __restrict__ rhW1p, const float* __restrict__ rh_b1,
    const unsigned short* __restrict__ wqp, const float* __restrict__ b_q,
    float* __restrict__ t1, float* __restrict__ q0, RVConsts C) {
  __shared__ unsigned short xin[64][104];
  int b = blockIdx.y;
  int n0 = blockIdx.x * 64;
  int tid = threadIdx.x;
  const float* src = x_rv + ((size_t)b * NPIX + n0) * 64;
  for (int i = tid; i < 1024; i += 256) {
    int p = i >> 4, c = (i & 15) * 4;
    float4 v4 = *(const float4*)(src + p * 64 + c);
    xin[p][c] = f2bf(v4.x);
    xin[p][c + 1] = f2bf(v4.y);
    xin[p][c + 2] = f2bf(v4.z);
    xin[p][c + 3] = f2bf(v4.w);
  }
  if (tid < 64) {
    int n = n0 + tid;
    int h = n >> 10, w = n & 1023;
    float E = C.means[h];
    float A = azimf(w, C.step_d, C.az0, C.az_half);
    float ce = cosf(E);
    xin[tid][64] = f2bf(ce * cosf(A));
    xin[tid][65] = f2bf(ce * sinf(A));
    xin[tid][66] = f2bf(sinf(E));
    for (int c = 67; c < 104; c++) xin[tid][c] = 0;
  }
  __syncthreads();
  int wave = tid >> 6, l = tid & 63;
  int lr = l & 15, lk = l >> 4;
  f32x4 acc[8], accq[8];
#pragma unroll
  for (int nt = 0; nt < 8; nt++) {
    float b1 = rh_b1[nt * 16 + lr], b2 = b_q[nt * 16 + lr];
    acc[nt] = (f32x4){b1, b1, b1, b1};
    accq[nt] = (f32x4){b2, b2, b2, b2};
  }
#pragma unroll
  for (int ks = 0; ks < 3; ks++) {
    short8 a = *(const short8*)&xin[wave * 16 + lr][ks * 32 + lk * 8];
#pragma unroll
    for (int nt = 0; nt < 8; nt++) {
      short8 b1v = *(const short8*)(rhW1p + (size_t)(nt * 16 + lr) * 96 + ks * 32 + lk * 8);
      acc[nt] = __builtin_amdgcn_mfma_f32_16x16x32_bf16(a, b1v, acc[nt], 0, 0, 0);
      short8 b2v = *(const short8*)(wqp + (size_t)(nt * 16 + lr) * 96 + ks * 32 + lk * 8);
      accq[nt] = __builtin_amdgcn_mfma_f32_16x16x32_bf16(a, b2v, accq[nt], 0, 0, 0);
    }
  }
#pragma unroll
  for (int nt = 0; nt < 8; nt++) {
    int n = nt * 16 + lr;
#pragma unroll
    for (int r = 0; r < 4; r++) {
      int p = n0 + wave * 16 + lk * 4 + r;
      size_t o = ((size_t)b * NPIX + p) * 128 + n;
      t1[o] = acc[nt][r];
      q0[o] = accq[nt][r];
    }
  }
}

// ---------------- GroupNorm partial sums ----------------
template <int CCH, int CGRP>
__global__ __launch_bounds__(256) void k_gnsum(const float* __restrict__ src,
                                               float* __restrict__ sums) {
  int chunk = blockIdx.x;
  int g = blockIdx.y;
  int b = blockIdx.z;
  const int npx = NPIX / 16;
  int n0 = chunk * npx;
  int tid = threadIdx.x;
  float s = 0.f, ss = 0.f;
  const float* base = src + (size_t)b * NPIX * CCH + (size_t)g * CGRP;
  const int total = npx * CGRP;
  for (int i = tid; i < total; i += 256) {
    int n = i / CGRP;
    int cc = i % CGRP;
    float x = base[(size_t)(n0 + n) * CCH + cc];
    s += x; ss += x * x;
  }
#pragma unroll
  for (int o2 = 32; o2 > 0; o2 >>= 1) { s += __shfl_down(s, o2); ss += __shfl_down(ss, o2); }
  __shared__ float wsum[4][2];
  if ((tid & 63) == 0) { wsum[tid >> 6][0] = s; wsum[tid >> 6][1] = ss; }
  __syncthreads();
  if (tid == 0) {
    float S = wsum[0][0] + wsum[1][0] + wsum[2][0] + wsum[3][0];
    float SS = wsum[0][1] + wsum[1][1] + wsum[2][1] + wsum[3][1];
    sums[((b * 8 + g) * 16 + chunk) * 2 + 0] = S;
    sums[((b * 8 + g) * 16 + chunk) * 2 + 1] = SS;
  }
}

__global__ void k_gnfin(const float* __restrict__ sums, float* __restrict__ stats, float invN) {
  int i = threadIdx.x;
  if (i >= 16) return;
  float S = 0.f, SS = 0.f;
  for (int ch = 0; ch < 16; ch++) { S += sums[(i * 16 + ch) * 2]; SS += sums[(i * 16 + ch) * 2 + 1]; }
  float m = S * invN;
  float var = SS * invN - m * m;
  stats[i * 2] = m;
  stats[i * 2 + 1] = rsqrtf(var + 1e-5f);
}

// ---------------- K3: apply GN1 + GELU -> bf16 h1 ----------------
__global__ __launch_bounds__(256) void k_gn1_gelu(
    const float* __restrict__ t1, const float* __restrict__ stats1,
    const float* __restrict__ g1, const float* __restrict__ bt1,
    unsigned short* __restrict__ h1) {
  size_t i4 = ((size_t)blockIdx.x * 256 + threadIdx.x) * 4;
  int c = (int)(i4 & 127);
  int bidx = (int)(i4 >> 21);
  int g = c >> 4;
  float m = stats1[(bidx * 8 + g) * 2], is = stats1[(bidx * 8 + g) * 2 + 1];
  float4 x4 = *(const float4*)(t1 + i4);
  float y0 = geluf((x4.x - m) * is * g1[c] + bt1[c]);
  float y1 = geluf((x4.y - m) * is * g1[c + 1] + bt1[c + 1]);
  float y2 = geluf((x4.z - m) * is * g1[c + 2] + bt1[c + 2]);
  float y3 = geluf((x4.w - m) * is * g1[c + 3] + bt1[c + 3]);
  uint2 o;
  o.x = (unsigned int)f2bf(y0) | ((unsigned int)f2bf(y1) << 16);
  o.y = (unsigned int)f2bf(y2) | ((unsigned int)f2bf(y3) << 16);
  *(uint2*)(h1 + i4) = o;
}

// ---------------- K4: MFMA 3x3 circular conv (128 -> 64), 9 shifted GEMMs ----------------
__device__ __forceinline__ int cswz(int rw, int c) {
  int byte = (rw << 8) + (c << 1);
  return byte ^ ((rw & 7) << 4);
}
__global__ __launch_bounds__(256) void k_conv3(const unsigned short* __restrict__ h1,
                                               const unsigned short* __restrict__ w2p,
                                               float* __restrict__ t2) {
  __shared__ unsigned short tile[3 * 66 * 128];  // 50688 B
  int b = blockIdx.y;
  int n0 = blockIdx.x * 64;
  int h = n0 >> 10;
  int w0 = n0 & 1023;
  int tid = threadIdx.x;
  for (int i = tid; i < 3 * 66 * 16; i += 256) {
    int r = i / (66 * 16);
    int rem = i - r * 66 * 16;
    int w = rem >> 4;
    int c0 = (rem & 15) * 8;
    int hh = (h + r - 1 + HRV) & (HRV - 1);
    int wc = (w0 + w - 1 + WRV) & (WRV - 1);
    uint4 v = *(const uint4*)(h1 + ((size_t)b * NPIX + hh * WRV + wc) * 128 + c0);
    *(uint4*)((char*)tile + cswz(r * 66 + w, c0)) = v;
  }
  __syncthreads();
  int wave = tid >> 6, l = tid & 63;
  int lr = l & 15, lk = l >> 4;
  f32x4 acc[4];
#pragma unroll
  for (int nt = 0; nt < 4; nt++) acc[nt] = (f32x4){0.f, 0.f, 0.f, 0.f};
#pragma unroll
  for (int kpos = 0; kpos < 9; kpos++) {
    int ky = kpos / 3, kx = kpos - ky * 3;
    int rw = ky * 66 + wave * 16 + lr + kx;
#pragma unroll
    for (int ks = 0; ks < 4; ks++) {
      short8 a = *(const short8*)((const char*)tile + cswz(rw, ks * 32 + lk * 8));
#pragma unroll
      for (int nt = 0; nt < 4; nt++) {
        short8 bv = *(const short8*)(w2p + (size_t)(kpos * 64 + nt * 16 + lr) * 128 +
                                     ks * 32 + lk * 8);
        acc[nt] = __builtin_amdgcn_mfma_f32_16x16x32_bf16(a, bv, acc[nt], 0, 0, 0);
      }
    }
  }
#pragma unroll
  for (int nt = 0; nt < 4; nt++) {
    int o = nt * 16 + lr;
#pragma unroll
    for (int r = 0; r < 4; r++) {
      int p = n0 + wave * 16 + lk * 4 + r;
      t2[((size_t)b * NPIX + p) * 64 + o] = acc[nt][r];
    }
  }
}

// ---------------- K6: GN2+GELU -> head(4) -> params + KL ----------------
__global__ __launch_bounds__(256) void k_head(
    const float* __restrict__ t2, const float* __restrict__ stats2,
    const float* __restrict__ g2, const float* __restrict__ bt2,
    const float* __restrict__ rh_w3, const float* __restrict__ rh_b3,
    const float* __restrict__ l2e, float* __restrict__ params,
    float* __restrict__ klpart, RVConsts C) {
  int b = blockIdx.y;
  int n = blockIdx.x * 256 + threadIdx.x;
  int h = n >> 10, w = n & 1023;
  const float* t = t2 + ((size_t)b * NPIX + n) * 64;
  float hd0 = rh_b3[0], hd1 = rh_b3[1], hd2 = rh_b3[2], hd3 = rh_b3[3];
  for (int c = 0; c < 64; c++) {
    int g = c >> 3;
    float m = stats2[(b * 8 + g) * 2], is = stats2[(b * 8 + g) * 2 + 1];
    float xv = geluf((t[c] - m) * is * g2[c] + bt2[c]);
    hd0 += rh_w3[c] * xv;
    hd1 += rh_w3[64 + c] * xv;
    hd2 += rh_w3[128 + c] * xv;
    hd3 += rh_w3[192 + c] * xv;
  }
  float mu = sigmoidf_(hd0) * 55.0f;
  float sd = softplusf_(hd1) + 1e-3f;
  float stepw = C.steps[w & 15];
  float se = sigmoidf_(hd2) * stepw + 1e-3f;
  float sa = sigmoidf_(hd3) * C.az_step_f + 1e-3f;
  float E0 = C.means[h];
  float A0 = azimf(w, C.step_d, C.az0, C.az_half);
  float* P = params + ((size_t)b * NPIX + n) * 16;
  P[0] = sd; P[1] = se; P[2] = sa;
  float M00 = l2e[0], M01 = l2e[1], M10 = l2e[4], M11 = l2e[5];
  float M20 = l2e[8], M21 = l2e[9], M30 = l2e[12], M31 = l2e[13];
#pragma unroll
  for (int k = 0; k < 5; k++) {
    float off = -0.6f + 0.3f * (float)k;
    float d = mu + sd * off;
    float E = E0 + se * off;
    float A = A0 + sa * off;
    float ce = cosf(E);
    float xl = d * ce * cosf(A), yl = d * ce * sinf(A), zl = d * sinf(E);
    float px = xl * M00 + yl * M10 + zl * M20 + M30;
    float py = xl * M01 + yl * M11 + zl * M21 + M31;
    P[3 + 2 * k] = sigmoidf_(4.0f * ((px + 55.0f) * (1.0f / 110.0f) - 0.5f));
    P[4 + 2 * k] = sigmoidf_(4.0f * ((py + 55.0f) * (1.0f / 110.0f) - 0.5f));
  }
  float mu_n = mu * (1.0f / 55.0f);
  float sr = fmaxf(sd, 1e-6f);
  float saz = sa / C.az_step_f;
  float sel = se / stepw;
  float L = 0.5f * (mu_n * mu_n + sr * sr - logf(sr * sr) - 1.0f) +
            0.5f * (saz * saz - logf(saz * saz) - 1.0f) +
            0.5f * (sel * sel - logf(sel * sel) - 1.0f);
#pragma unroll
  for (int o2 = 32; o2 > 0; o2 >>= 1) L += __shfl_down(L, o2);
  __shared__ float wsum[4];
  if ((threadIdx.x & 63) == 0) wsum[threadIdx.x >> 6] = L;
  __syncthreads();
  if (threadIdx.x == 0)
    klpart[blockIdx.y * 64 + blockIdx.x] = wsum[0] + wsum[1] + wsum[2] + wsum[3];
}

// ---------------- K7: MFMA query MLP ----------------
__global__ __launch_bounds__(256) void k_query(
    const float* __restrict__ q0, const float* __restrict__ params,
    const unsigned short* __restrict__ qsW1p, const float* __restrict__ qs_b1,
    const float* __restrict__ qs_w1f,
    const unsigned short* __restrict__ qsW2p, const float* __restrict__ qs_b2,
    float* __restrict__ query) {
  __shared__ unsigned short qin[64][136];
  __shared__ unsigned short hq[64][136];
  __shared__ float sigf[64][6];
  int b = blockIdx.y;
  int n0 = blockIdx.x * 64;
  int tid = threadIdx.x;
  const float* src = q0 + ((size_t)b * NPIX + n0) * 128;
  for (int i = tid; i < 2048; i += 256) {
    int p = i >> 5, c = (i & 31) * 4;
    float4 v4 = *(const float4*)(src + p * 128 + c);
    qin[p][c] = f2bf(v4.x);
    qin[p][c + 1] = f2bf(v4.y);
    qin[p][c + 2] = f2bf(v4.z);
    qin[p][c + 3] = f2bf(v4.w);
  }
  if (tid < 64) {
    const float* P = params + ((size_t)b * NPIX + n0 + tid) * 16;
    float sd = P[0], se = P[1], sa = P[2];
    sigf[tid][0] = sd; sigf[tid][1] = se; sigf[tid][2] = sa;
    sigf[tid][3] = 1.0f / (sd + 1e-6f);
    sigf[tid][4] = 1.0f / (se + 1e-6f);
    sigf[tid][5] = 1.0f / (sa + 1e-6f);
  }
  __syncthreads();
  int wave = tid >> 6, l = tid & 63;
  int lr = l & 15, lk = l >> 4;
  f32x4 acc[8];
#pragma unroll
  for (int nt = 0; nt < 8; nt++) {
    int n = nt * 16 + lr;
    float wt[6];
#pragma unroll
    for (int c = 0; c < 6; c++) wt[c] = qs_w1f[(size_t)n * 134 + 128 + c];
    float bias = qs_b1[n];
#pragma unroll
    for (int r = 0; r < 4; r++) {
      int pl = wave * 16 + lk * 4 + r;
      float a = bias;
#pragma unroll
      for (int c = 0; c < 6; c++) a += wt[c] * sigf[pl][c];
      acc[nt][r] = a;
    }
  }
#pragma unroll
  for (int ks = 0; ks < 4; ks++) {
    short8 a = *(const short8*)&qin[wave * 16 + lr][ks * 32 + lk * 8];
#pragma unroll
    for (int nt = 0; nt < 8; nt++) {
      short8 bv = *(const short8*)(qsW1p + (size_t)(nt * 16 + lr) * 128 + ks * 32 + lk * 8);
      acc[nt] = __builtin_amdgcn_mfma_f32_16x16x32_bf16(a, bv, acc[nt], 0, 0, 0);
    }
  }
#pragma unroll
  for (int nt = 0; nt < 8; nt++)
#pragma unroll
    for (int r = 0; r < 4; r++)
      hq[wave * 16 + lk * 4 + r][nt * 16 + lr] = f2bf(geluf(acc[nt][r]));
  __syncthreads();
#pragma unroll
  for (int nt = 0; nt < 8; nt++) {
    float bias = qs_b2[nt * 16 + lr];
    acc[nt] = (f32x4){bias, bias, bias, bias};
  }
#pragma unroll
  for (int ks = 0; ks < 4; ks++) {
    short8 a = *(const short8*)&hq[wave * 16 + lr][ks * 32 + lk * 8];
#pragma unroll
    for (int nt = 0; nt < 8; nt++) {
      short8 bv = *(const short8*)(qsW2p + (size_t)(nt * 16 + lr) * 128 + ks * 32 + lk * 8);
      acc[nt] = __builtin_amdgcn_mfma_f32_16x16x32_bf16(a, bv, acc[nt], 0, 0, 0);
    }
  }
#pragma unroll
  for (int nt = 0; nt < 8; nt++) {
    int n = nt * 16 + lr;
#pragma unroll
    for (int r = 0; r < 4; r++) {
      int p = n0 + wave * 16 + lk * 4 + r;
      query[((size_t)b * NPIX + p) * 128 + n] = acc[nt][r];
    }
  }
}

// ---------------- K8: pack weights to bf16 ----------------
__global__ __launch_bounds__(256) void k_pack(
    const float* __restrict__ val_w, const float* __restrict__ w_v,
    const float* __restrict__ b_v, const float* __restrict__ val_b,
    const float* __restrict__ off_w, const float* __restrict__ off_b,
    const float* __restrict__ aw_w, const float* __restrict__ aw_b,
    const float* __restrict__ out_w, const float* __restrict__ qs_w1,
    const float* __restrict__ qs_w2, const float* __restrict__ rh_w1,
    const float* __restrict__ w_q, const float* __restrict__ w_o,
    const float* __restrict__ rh_w2,
    unsigned short* __restrict__ wvv_bf, float* __restrict__ bvv,
    unsigned short* __restrict__ projW, float* __restrict__ projB,
    unsigned short* __restrict__ outW, unsigned short* __restrict__ qsW1p,
    unsigned short* __restrict__ qsW2p, unsigned short* __restrict__ rhW1p,
    unsigned short* __restrict__ wqp, unsigned short* __restrict__ woP,
    unsigned short* __restrict__ w2p) {
  int idx = blockIdx.x * 256 + threadIdx.x;
  if (idx < 16384) {
    int o = idx >> 7, c = idx & 127;
    float acc = 0.0f;
    for (int m = 0; m < 128; m++) acc += val_w[o * 128 + m] * w_v[m * 128 + c];
    wvv_bf[idx] = f2bf(acc);
  } else if (idx < 16512) {
    int o = idx - 16384;
    float acc = val_b[o];
    for (int m = 0; m < 128; m++) acc += val_w[o * 128 + m] * b_v[m];
    bvv[o] = acc;
  } else if (idx < 82048) {
    int j = idx - 16512;
    int r = j >> 7, c = j & 127;
    float w = (r < 320) ? off_w[r * 128 + c] : ((r < 480) ? aw_w[(r - 320) * 128 + c] : 0.0f);
    projW[j] = f2bf(w);
  } else if (idx < 82560) {
    int r = idx - 82048;
    projB[r] = (r < 320) ? off_b[r] : ((r < 480) ? aw_b[r - 320] : 0.0f);
  } else if (idx < 98944) {
    int j = idx - 82560;
    outW[j] = f2bf(out_w[j]);
  } else if (idx < 115328) {
    int j = idx - 98944;
    int r = j >> 7, c = j & 127;
    qsW1p[j] = f2bf(qs_w1[r * 134 + c]);
  } else if (idx < 131712) {
    int j = idx - 115328;
    qsW2p[j] = f2bf(qs_w2[j]);
  } else if (idx < 144000) {
    int j = idx - 131712;
    int r = j / 96, c = j - r * 96;
    rhW1p[j] = (c < 67) ? f2bf(rh_w1[r * 67 + c]) : 0;
  } else if (idx < 156288) {
    int j = idx - 144000;
    int r = j / 96, c = j - r * 96;
    wqp[j] = (c < 64) ? f2bf(w_q[r * 64 + c]) : 0;
  } else if (idx < 172672) {
    int j = idx - 156288;
    woP[j] = f2bf(w_o[j]);
  } else if (idx < 246400) {
    int j = idx - 172672;          // [kpos][o][c]
    int kpos = j >> 13;
    int rem = j & 8191;
    int o = rem >> 7, c = rem & 127;
    int ky = kpos / 3, kx = kpos - ky * 3;
    w2p[j] = f2bf(rh_w2[((size_t)(o * 128 + c) * 3 + ky) * 3 + kx]);
  }
}

// ---------------- K9: MFMA value projection -> f32 v ----------------
__global__ __launch_bounds__(256) void k_value(
    const float* __restrict__ bev, const unsigned short* __restrict__ wvv_bf,
    const float* __restrict__ bvv, float* __restrict__ v) {
  __shared__ float lds[128 * 66];
  int b = blockIdx.y;
  int p0 = blockIdx.x * 64;
  int tid = threadIdx.x;
  int npx = NBEV - p0; if (npx > 64) npx = 64;
  for (int i = tid; i < 128 * 64; i += 256) {
    int c = i >> 6, p = i & 63;
    lds[c * 66 + p] = (p < npx) ? bev[((size_t)b * 128 + c) * NBEV + p0 + p] : 0.0f;
  }
  __syncthreads();
  int wave = tid >> 6, l = tid & 63;
  int lr = l & 15, lk = l >> 4;
  int ploc = wave * 16 + lr;
  f32x4 acc[8];
#pragma unroll
  for (int nt = 0; nt < 8; nt++) {
    float bias = bvv[nt * 16 + lr];
    acc[nt] = (f32x4){bias, bias, bias, bias};
  }
#pragma unroll
  for (int ks = 0; ks < 4; ks++) {
    int k0 = ks * 32 + lk * 8;
    short8 a;
#pragma unroll
    for (int j = 0; j < 8; j++) a[j] = (short)f2bf(lds[(k0 + j) * 66 + ploc]);
#pragma unroll
    for (int nt = 0; nt < 8; nt++) {
      short8 bf = *(const short8*)(wvv_bf + (size_t)(nt * 16 + lr) * 128 + k0);
      acc[nt] = __builtin_amdgcn_mfma_f32_16x16x32_bf16(a, bf, acc[nt], 0, 0, 0);
    }
  }
#pragma unroll
  for (int nt = 0; nt < 8; nt++) {
    int n = nt * 16 + lr;
#pragma unroll
    for (int r = 0; r < 4; r++) {
      int p = p0 + wave * 16 + lk * 4 + r;
      if (p < NBEV) v[((size_t)b * NBEV + p) * 128 + n] = acc[nt][r];
    }
  }
}

// ---------------- K10: fused MFMA projection + softmax + bilinear sampler ----------------
// Block = 32 pixels. Phase A: proj (512 outs) via MFMA into LDS. Phase B/C: one thread
// per (pixel, head): softmax in registers (20 exps), descriptors once, 4 f32x4 loads/tap.
__global__ __launch_bounds__(256) void k_fsamp(
    const float* __restrict__ query, const unsigned short* __restrict__ projW,
    const float* __restrict__ projB, const float* __restrict__ params,
    const float* __restrict__ v, unsigned short* __restrict__ S) {
  __shared__ unsigned short pl[32][520];  // padded row: breaks px-stride bank aliasing
  int b = blockIdx.y;
  int bid = blockIdx.x;
  int pb = (bid & 7) * 64 + (bid >> 3);  // XCD-chunked swizzle (512 = 8*64)
  int npx0 = pb * 32;
  int tid = threadIdx.x;
  int wave = tid >> 6, l = tid & 63;
  int lr = l & 15, lk = l >> 4;
  {  // Phase A: 4 waves: (px-half, n-half)
    int px16 = (wave & 1) * 16;
    int n0 = (wave >> 1) * 256;
    f32x4 acc[16];
#pragma unroll
    for (int nt = 0; nt < 16; nt++) {
      float bias = projB[n0 + nt * 16 + lr];
      acc[nt] = (f32x4){bias, bias, bias, bias};
    }
    const float* ap = query + ((size_t)b * NPIX + npx0 + px16 + lr) * 128 + lk * 8;
#pragma unroll
    for (int ks = 0; ks < 4; ks++) {
      float4 a0 = *(const float4*)(ap + ks * 32);
      float4 a1 = *(const float4*)(ap + ks * 32 + 4);
      short8 a;
      a[0] = (short)f2bf(a0.x); a[1] = (short)f2bf(a0.y);
      a[2] = (short)f2bf(a0.z); a[3] = (short)f2bf(a0.w);
      a[4] = (short)f2bf(a1.x); a[5] = (short)f2bf(a1.y);
      a[6] = (short)f2bf(a1.z); a[7] = (short)f2bf(a1.w);
#pragma unroll
      for (int nt = 0; nt < 16; nt++) {
        short8 bf = *(const short8*)(projW + (size_t)(n0 + nt * 16 + lr) * 128 +
                                     ks * 32 + lk * 8);
        acc[nt] = __builtin_amdgcn_mfma_f32_16x16x32_bf16(a, bf, acc[nt], 0, 0, 0);
      }
    }
#pragma unroll
    for (int nt = 0; nt < 16; nt++)
#pragma unroll
      for (int r = 0; r < 4; r++)
        pl[px16 + lk * 4 + r][n0 + nt * 16 + lr] = f2bf(acc[nt][r]);
  }
  __syncthreads();
  {  // Phase B/C: thread = (pixel, head)
    int px = tid >> 3, hh = tid & 7;
    int n = npx0 + px;
    // softmax over 20 logits, kept in registers
    float e[20];
    const unsigned int* lg = (const unsigned int*)&pl[px][320 + hh * 20];
#pragma unroll
    for (int i = 0; i < 10; i++) {
      unsigned int u = lg[i];
      e[2 * i] = bf2f((unsigned short)(u & 0xffffu));
      e[2 * i + 1] = bf2f((unsigned short)(u >> 16));
    }
    float mx = e[0];
#pragma unroll
    for (int i = 1; i < 20; i++) mx = fmaxf(mx, e[i]);
    float s = 0.0f;
#pragma unroll
    for (int i = 0; i < 20; i++) { e[i] = expf(e[i] - mx); s += e[i]; }
    float rs = 1.0f / s;
    const float* P = params + ((size_t)b * NPIX + n) * 16;
    const float* vb = v + (size_t)b * NBEV * 128 + hh * 16;
    float acc[16];
#pragma unroll
    for (int c = 0; c < 16; c++) acc[c] = 0.0f;
#pragma unroll
    for (int k = 0; k < 5; k++) {
      float rx = P[3 + 2 * k] * 220.0f - 0.5f;
      float ry = P[4 + 2 * k] * 220.0f - 0.5f;
      const unsigned int* ofs = (const unsigned int*)&pl[px][hh * 40 + k * 8];
#pragma unroll
      for (int pp = 0; pp < 4; pp++) {
        unsigned int u = ofs[pp];
        float X = rx + bf2f((unsigned short)(u & 0xffffu));
        float Y = ry + bf2f((unsigned short)(u >> 16));
        float xf = floorf(X), yf = floorf(Y);
        float wx = X - xf, wy = Y - yf;
        int x0 = (int)xf, y0 = (int)yf;
        float wx0 = ((unsigned)x0 < 220u) ? (1.0f - wx) : 0.0f;
        float wx1 = ((unsigned)(x0 + 1) < 220u) ? wx : 0.0f;
        float wy0 = ((unsigned)y0 < 220u) ? (1.0f - wy) : 0.0f;
        float wy1 = ((unsigned)(y0 + 1) < 220u) ? wy : 0.0f;
        int cx0 = min(max(x0, 0), 219), cx1 = min(max(x0 + 1, 0), 219);
        int cy0 = min(max(y0, 0), 219) * 220, cy1 = min(max(y0 + 1, 0), 219) * 220;
        float a = e[k * 4 + pp] * rs;
        float u0 = a * wy0, u1 = a * wy1;
        float w00 = u0 * wx0, w01 = u0 * wx1, w10 = u1 * wx0, w11 = u1 * wx1;
        int i00 = cy0 + cx0, i01 = cy0 + cx1, i10 = cy1 + cx0, i11 = cy1 + cx1;
#pragma unroll
        for (int t = 0; t < 4; t++) {
          int idx = t == 0 ? i00 : (t == 1 ? i01 : (t == 2 ? i10 : i11));
          float w = t == 0 ? w00 : (t == 1 ? w01 : (t == 2 ? w10 : w11));
          const float4* sp = (const float4*)(vb + (size_t)idx * 128);
          float4 v0 = sp[0], v1 = sp[1], v2 = sp[2], v3 = sp[3];
          acc[0] += w * v0.x; acc[1] += w * v0.y; acc[2] += w * v0.z; acc[3] += w * v0.w;
          acc[4] += w * v1.x; acc[5] += w * v1.y; acc[6] += w * v1.z; acc[7] += w * v1.w;
          acc[8] += w * v2.x; acc[9] += w * v2.y; acc[10] += w * v2.z; acc[11] += w * v2.w;
          acc[12] += w * v3.x; acc[13] += w * v3.y; acc[14] += w * v3.z; acc[15] += w * v3.w;
        }
      }
    }
    uint4 o1, o2;
    o1.x = (unsigned int)f2bf(acc[0]) | ((unsigned int)f2bf(acc[1]) << 16);
    o1.y = (unsigned int)f2bf(acc[2]) | ((unsigned int)f2bf(acc[3]) << 16);
    o1.z = (unsigned int)f2bf(acc[4]) | ((unsigned int)f2bf(acc[5]) << 16);
    o1.w = (unsigned int)f2bf(acc[6]) | ((unsigned int)f2bf(acc[7]) << 16);
    o2.x = (unsigned int)f2bf(acc[8]) | ((unsigned int)f2bf(acc[9]) << 16);
    o2.y = (unsigned int)f2bf(acc[10]) | ((unsigned int)f2bf(acc[11]) << 16);
    o2.z = (unsigned int)f2bf(acc[12]) | ((unsigned int)f2bf(acc[13]) << 16);
    o2.w = (unsigned int)f2bf(acc[14]) | ((unsigned int)f2bf(acc[15]) << 16);
    unsigned short* dst = S + ((size_t)b * NPIX + n) * 128 + hh * 16;
    *(uint4*)dst = o1;
    *(uint4*)(dst + 8) = o2;
  }
}

// ---------------- K12: MFMA out-projection + residual ----------------
__global__ __launch_bounds__(256) void k_out(
    const unsigned short* __restrict__ S, const unsigned short* __restrict__ outW,
    const float* __restrict__ out_b, const float* __restrict__ query,
    float* __restrict__ ymsda) {
  int b = blockIdx.y;
  int wave = threadIdx.x >> 6, l = threadIdx.x & 63;
  int lr = l & 15, lk = l >> 4;
  int p0 = blockIdx.x * 64 + wave * 16;
  f32x4 acc[8];
#pragma unroll
  for (int nt = 0; nt < 8; nt++) {
    float bias = out_b[nt * 16 + lr];
    acc[nt] = (f32x4){bias, bias, bias, bias};
  }
  const unsigned short* ap = S + ((size_t)b * NPIX + p0 + lr) * 128 + lk * 8;
#pragma unroll
  for (int ks = 0; ks < 4; ks++) {
    short8 a = *(const short8*)(ap + ks * 32);
#pragma unroll
    for (int nt = 0; nt < 8; nt++) {
      short8 bf = *(const short8*)(outW + (size_t)(nt * 16 + lr) * 128 + ks * 32 + lk * 8);
      acc[nt] = __builtin_amdgcn_mfma_f32_16x16x32_bf16(a, bf, acc[nt], 0, 0, 0);
    }
  }
#pragma unroll
  for (int nt = 0; nt < 8; nt++) {
    int n = nt * 16 + lr;
#pragma unroll
    for (int r = 0; r < 4; r++) {
      int p = p0 + lk * 4 + r;
      size_t o = ((size_t)b * NPIX + p) * 128 + n;
      ymsda[o] = acc[nt][r] + query[o];
    }
  }
}

// ---------------- K13: MFMA final conv1x1 + transposed NCHW store ----------------
__global__ __launch_bounds__(256) void k_final(
    const float* __restrict__ ymsda, const unsigned short* __restrict__ woP,
    const float* __restrict__ b_o, float* __restrict__ out) {
  __shared__ float yt[128][67];
  int b = blockIdx.y;
  int p0 = blockIdx.x * 64;
  int tid = threadIdx.x;
  int wave = tid >> 6, l = tid & 63;
  int lr = l & 15, lk = l >> 4;
  f32x4 acc[8];
#pragma unroll
  for (int nt = 0; nt < 8; nt++) {
    float bias = b_o[nt * 16 + lr];
    acc[nt] = (f32x4){bias, bias, bias, bias};
  }
  const float* ap = ymsda + ((size_t)b * NPIX + p0 + wave * 16 + lr) * 128 + lk * 8;
#pragma unroll
  for (int ks = 0; ks < 4; ks++) {
    float4 a0 = *(const float4*)(ap + ks * 32);
    float4 a1 = *(const float4*)(ap + ks * 32 + 4);
    short8 a;
    a[0] = (short)f2bf(a0.x); a[1] = (short)f2bf(a0.y);
    a[2] = (short)f2bf(a0.z); a[3] = (short)f2bf(a0.w);
    a[4] = (short)f2bf(a1.x); a[5] = (short)f2bf(a1.y);
    a[6] = (short)f2bf(a1.z); a[7] = (short)f2bf(a1.w);
#pragma unroll
    for (int nt = 0; nt < 8; nt++) {
      short8 bf = *(const short8*)(woP + (size_t)(nt * 16 + lr) * 128 + ks * 32 + lk * 8);
      acc[nt] = __builtin_amdgcn_mfma_f32_16x16x32_bf16(a, bf, acc[nt], 0, 0, 0);
    }
  }
#pragma unroll
  for (int nt = 0; nt < 8; nt++)
#pragma unroll
    for (int r = 0; r < 4; r++)
      yt[nt * 16 + lr][wave * 16 + lk * 4 + r] = acc[nt][r];
  __syncthreads();
  int n = tid >> 1, half = tid & 1;
  float* dst = out + ((size_t)(b * 128 + n)) * NPIX + p0 + half * 32;
#pragma unroll
  for (int j = 0; j < 8; j++) {
    float4 v4 = {yt[n][half * 32 + j * 4], yt[n][half * 32 + j * 4 + 1],
                 yt[n][half * 32 + j * 4 + 2], yt[n][half * 32 + j * 4 + 3]};
    *(float4*)(dst + j * 4) = v4;
  }
}

__global__ void k_klfin(const float* __restrict__ klpart, float* __restrict__ out) {
  if (threadIdx.x == 0) {
    float s = 0.0f;
    for (int i = 0; i < 128; i++) s += klpart[i];
    out[(size_t)BSZ * 128 * NPIX] = 1e-4f * (s / 32768.0f);
  }
}

// ---------------- host ----------------
static RVConsts make_consts() {
  static const float ELEV[32] = {
      -30.67f, -29.33f, -28.0f, -26.66f, -25.33f, -24.0f, -22.67f, -21.33f,
      -20.0f,  -18.67f, -17.33f, -16.0f, -14.67f, -13.33f, -12.0f, -10.67f,
      -9.33f,  -8.0f,   -6.66f,  -5.33f, -4.0f,   -2.67f,  -1.33f, 0.0f,
      1.33f,   2.67f,   4.0f,    5.33f,  6.67f,   8.0f,    9.33f,  10.67f};
  RVConsts C;
  const float d2r = 0.017453292519943295f;
  for (int r = 0; r < 16; r++) {
    float a = ELEV[31 - 2 * r], b = ELEV[30 - 2 * r];
    float mx = fmaxf(a, b), mn = fminf(a, b);
    C.steps[r] = (mx - mn) * d2r;
    C.means[r] = ((a + b) * 0.5f) * d2r;
  }
  const double PI_D = 3.14159265358979323846;
  double step_d = (PI_D - (-PI_D)) / 1024.0;
  double az0 = -PI_D;
  double az1 = az0 + step_d;
  double az_step_d = az1 - az0;
  C.az_step_f = (float)az_step_d;
  C.pad_ = 0.0f;
  C.step_d = step_d;
  C.az0 = az0;
  C.az_half = az_step_d * 0.5;
  return C;
}

// Workspace layout (f32 words). Peak 21,620,608 words = 86.5 MB.
// v (f32, 12,390,400 w @ 0) overlays t1/h1/t2/q0 — all dead before k_value.
#define OFF_T1     0u
#define OFF_H1     4194304u    /* bf16 x 4,194,304 -> 2,097,152 w */
#define OFF_T2     8388608u
#define OFF_Q0     10485760u
#define OFF_PARAMS 14680064u
#define OFF_QUERY  15204352u
#define OFF_S      19398656u
#define OFF_SUMS1  21495808u
#define OFF_SUMS2  21496320u
#define OFF_STATS1 21496832u
#define OFF_STATS2 21496864u
#define OFF_KL     21496896u
#define OFF_V      0u          /* f32 x 12,390,400 (after query; ends 12,390,400 < PARAMS) */
#define OFF_YMSDA  0u          /* f32 x 4,194,304 (after fsamp consumes v) */
#define OFF_WVV    21497088u
#define OFF_BVV    21505280u
#define OFF_PROJW  21505408u
#define OFF_PROJB  21538176u
#define OFF_OUTW   21538688u
#define OFF_QSW1   21546880u
#define OFF_QSW2   21555072u
#define OFF_RHW1   21563264u
#define OFF_WQP    21569408u
#define OFF_WOP    21575552u
#define OFF_W2P    21583744u   /* bf16 x 73728 -> 36864 w */

extern "C" void kernel_launch(void* const* d_in, const int* in_sizes, int n_in,
                              void* d_out, int out_size, void* d_ws, size_t ws_size,
                              hipStream_t stream) {
  const float* x_rv = (const float*)d_in[0];
  const float* bev = (const float*)d_in[1];
  const float* l2e = (const float*)d_in[2];
  const float* w_q = (const float*)d_in[3];
  const float* b_q = (const float*)d_in[4];
  const float* w_v = (const float*)d_in[5];
  const float* b_v = (const float*)d_in[6];
  const float* w_o = (const float*)d_in[7];
  const float* b_o = (const float*)d_in[8];
  const float* qs_w1 = (const float*)d_in[9];
  const float* qs_b1 = (const float*)d_in[10];
  const float* qs_w2 = (const float*)d_in[11];
  const float* qs_b2 = (const float*)d_in[12];
  const float* rh_w1 = (const float*)d_in[13];
  const float* rh_b1 = (const float*)d_in[14];
  const float* rh_g1 = (const float*)d_in[15];
  const float* rh_bt1 = (const float*)d_in[16];
  const float* rh_w2 = (const float*)d_in[17];
  const float* rh_g2 = (const float*)d_in[18];
  const float* rh_bt2 = (const float*)d_in[19];
  const float* rh_w3 = (const float*)d_in[20];
  const float* rh_b3 = (const float*)d_in[21];
  const float* off_w = (const float*)d_in[22];
  const float* off_b = (const float*)d_in[23];
  const float* aw_w = (const float*)d_in[24];
  const float* aw_b = (const float*)d_in[25];
  const float* val_w = (const float*)d_in[26];
  const float* val_b = (const float*)d_in[27];
  const float* out_w = (const float*)d_in[28];
  const float* out_b = (const float*)d_in[29];

  float* ws = (float*)d_ws;
  float* t1 = ws + OFF_T1;
  float* t2 = ws + OFF_T2;
  float* q0 = ws + OFF_Q0;
  float* params = ws + OFF_PARAMS;
  float* query = ws + OFF_QUERY;
  float* sums1 = ws + OFF_SUMS1;
  float* sums2 = ws + OFF_SUMS2;
  float* stats1 = ws + OFF_STATS1;
  float* stats2 = ws + OFF_STATS2;
  float* klpart = ws + OFF_KL;
  float* bvv = ws + OFF_BVV;
  float* projB = ws + OFF_PROJB;
  float* ymsda = ws + OFF_YMSDA;
  float* v_f32 = ws + OFF_V;
  unsigned short* h1bf = (unsigned short*)(ws + OFF_H1);
  unsigned short* S_bf = (unsigned short*)(ws + OFF_S);
  unsigned short* wvv_bf = (unsigned short*)(ws + OFF_WVV);
  unsigned short* projW = (unsigned short*)(ws + OFF_PROJW);
  unsigned short* outW = (unsigned short*)(ws + OFF_OUTW);
  unsigned short* qsW1p = (unsigned short*)(ws + OFF_QSW1);
  unsigned short* qsW2p = (unsigned short*)(ws + OFF_QSW2);
  unsigned short* rhW1p = (unsigned short*)(ws + OFF_RHW1);
  unsigned short* wqp = (unsigned short*)(ws + OFF_WQP);
  unsigned short* woP = (unsigned short*)(ws + OFF_WOP);
  unsigned short* w2p = (unsigned short*)(ws + OFF_W2P);

  RVConsts C = make_consts();
  dim3 blk(256);

  k_pack<<<963, blk, 0, stream>>>(val_w, w_v, b_v, val_b, off_w, off_b, aw_w, aw_b, out_w,
                                  qs_w1, qs_w2, rh_w1, w_q, w_o, rh_w2,
                                  wvv_bf, bvv, projW, projB, outW, qsW1p, qsW2p, rhW1p,
                                  wqp, woP, w2p);
  k_rh1_q0<<<dim3(256, BSZ), blk, 0, stream>>>(x_rv, rhW1p, rh_b1, wqp, b_q, t1, q0, C);
  k_gnsum<128, 16><<<dim3(16, 8, BSZ), blk, 0, stream>>>(t1, sums1);
  k_gnfin<<<1, 64, 0, stream>>>(sums1, stats1, 1.0f / 262144.0f);
  k_gn1_gelu<<<4096, blk, 0, stream>>>(t1, stats1, rh_g1, rh_bt1, h1bf);
  k_conv3<<<dim3(256, BSZ), blk, 0, stream>>>(h1bf, w2p, t2);
  k_gnsum<64, 8><<<dim3(16, 8, BSZ), blk, 0, stream>>>(t2, sums2);
  k_gnfin<<<1, 64, 0, stream>>>(sums2, stats2, 1.0f / 131072.0f);
  k_head<<<dim3(64, BSZ), blk, 0, stream>>>(t2, stats2, rh_g2, rh_bt2, rh_w3, rh_b3,
                                            l2e, params, klpart, C);
  k_query<<<dim3(256, BSZ), blk, 0, stream>>>(q0, params, qsW1p, qs_b1, qs_w1, qsW2p,
                                              qs_b2, query);
  k_value<<<dim3(757, BSZ), blk, 0, stream>>>(bev, wvv_bf, bvv, v_f32);
  k_fsamp<<<dim3(512, BSZ), blk, 0, stream>>>(query, projW, projB, params, v_f32, S_bf);
  k_out<<<dim3(256, BSZ), blk, 0, stream>>>(S_bf, outW, out_b, query, ymsda);
  k_final<<<dim3(256, BSZ), blk, 0, stream>>>(ymsda, woP, b_o, (float*)d_out);
  k_klfin<<<1, 64, 0, stream>>>(klpart, (float*)d_out);
}

// Round 7
// 355.566 us; speedup vs baseline: 1.7560x; 1.7560x over previous
//
#include <hip/hip_runtime.h>
#include <math.h>

#define HRV 16
#define WRV 1024
#define NPIX 16384
#define NBEV 48400
#define BSZ 2

typedef __attribute__((ext_vector_type(8))) short short8;
typedef __attribute__((ext_vector_type(4))) float f32x4;

struct RVConsts {
  float steps[16];
  float means[16];
  float az_step_f;
  float pad_;
  double step_d;
  double az0;
  double az_half;
};

__device__ __forceinline__ float geluf(float x) {
  return 0.5f * x * (1.0f + erff(x * 0.70710678118654752440f));
}
__device__ __forceinline__ float sigmoidf_(float x) {
  return 1.0f / (1.0f + expf(-x));
}
__device__ __forceinline__ float softplusf_(float x) {
  return fmaxf(x, 0.0f) + log1pf(expf(-fabsf(x)));
}
__device__ __forceinline__ float azimf(int w, double step_d, double az0, double az_half) {
  double az = (double)w * step_d + az0;
  az += az_half;
  return (float)az;
}
__device__ __forceinline__ unsigned short f2bf(float f) {
  unsigned int u = __builtin_bit_cast(unsigned int, f);
  u = u + 0x7FFFu + ((u >> 16) & 1u);
  return (unsigned short)(u >> 16);
}
__device__ __forceinline__ float bf2f(unsigned short h) {
  unsigned int u = ((unsigned int)h) << 16;
  return __builtin_bit_cast(float, u);
}

// ---------------- K1: MFMA range-head conv1 (67->128) + Q0 conv (64->128) ----------------
__global__ __launch_bounds__(256) void k_rh1_q0(
    const float* __restrict__ x_rv,
    const unsigned short* __restrict__ rhW1p, const float* __restrict__ rh_b1,
    const unsigned short* __restrict__ wqp, const float* __restrict__ b_q,
    float* __restrict__ t1, float* __restrict__ q0, RVConsts C) {
  __shared__ unsigned short xin[64][104];
  int b = blockIdx.y;
  int n0 = blockIdx.x * 64;
  int tid = threadIdx.x;
  const float* src = x_rv + ((size_t)b * NPIX + n0) * 64;
  for (int i = tid; i < 1024; i += 256) {
    int p = i >> 4, c = (i & 15) * 4;
    float4 v4 = *(const float4*)(src + p * 64 + c);
    xin[p][c] = f2bf(v4.x);
    xin[p][c + 1] = f2bf(v4.y);
    xin[p][c + 2] = f2bf(v4.z);
    xin[p][c + 3] = f2bf(v4.w);
  }
  if (tid < 64) {
    int n = n0 + tid;
    int h = n >> 10, w = n & 1023;
    float E = C.means[h];
    float A = azimf(w, C.step_d, C.az0, C.az_half);
    float ce = cosf(E);
    xin[tid][64] = f2bf(ce * cosf(A));
    xin[tid][65] = f2bf(ce * sinf(A));
    xin[tid][66] = f2bf(sinf(E));
    for (int c = 67; c < 104; c++) xin[tid][c] = 0;
  }
  __syncthreads();
  int wave = tid >> 6, l = tid & 63;
  int lr = l & 15, lk = l >> 4;
  f32x4 acc[8], accq[8];
#pragma unroll
  for (int nt = 0; nt < 8; nt++) {
    float b1 = rh_b1[nt * 16 + lr], b2 = b_q[nt * 16 + lr];
    acc[nt] = (f32x4){b1, b1, b1, b1};
    accq[nt] = (f32x4){b2, b2, b2, b2};
  }
#pragma unroll
  for (int ks = 0; ks < 3; ks++) {
    short8 a = *(const short8*)&xin[wave * 16 + lr][ks * 32 + lk * 8];
#pragma unroll
    for (int nt = 0; nt < 8; nt++) {
      short8 b1v = *(const short8*)(rhW1p + (size_t)(nt * 16 + lr) * 96 + ks * 32 + lk * 8);
      acc[nt] = __builtin_amdgcn_mfma_f32_16x16x32_bf16(a, b1v, acc[nt], 0, 0, 0);
      short8 b2v = *(const short8*)(wqp + (size_t)(nt * 16 + lr) * 96 + ks * 32 + lk * 8);
      accq[nt] = __builtin_amdgcn_mfma_f32_16x16x32_bf16(a, b2v, accq[nt], 0, 0, 0);
    }
  }
#pragma unroll
  for (int nt = 0; nt < 8; nt++) {
    int n = nt * 16 + lr;
#pragma unroll
    for (int r = 0; r < 4; r++) {
      int p = n0 + wave * 16 + lk * 4 + r;
      size_t o = ((size_t)b * NPIX + p) * 128 + n;
      t1[o] = acc[nt][r];
      q0[o] = accq[nt][r];
    }
  }
}

// ---------------- GroupNorm partial sums ----------------
template <int CCH, int CGRP>
__global__ __launch_bounds__(256) void k_gnsum(const float* __restrict__ src,
                                               float* __restrict__ sums) {
  int chunk = blockIdx.x;
  int g = blockIdx.y;
  int b = blockIdx.z;
  const int npx = NPIX / 16;
  int n0 = chunk * npx;
  int tid = threadIdx.x;
  float s = 0.f, ss = 0.f;
  const float* base = src + (size_t)b * NPIX * CCH + (size_t)g * CGRP;
  const int total = npx * CGRP;
  for (int i = tid; i < total; i += 256) {
    int n = i / CGRP;
    int cc = i % CGRP;
    float x = base[(size_t)(n0 + n) * CCH + cc];
    s += x; ss += x * x;
  }
#pragma unroll
  for (int o2 = 32; o2 > 0; o2 >>= 1) { s += __shfl_down(s, o2); ss += __shfl_down(ss, o2); }
  __shared__ float wsum[4][2];
  if ((tid & 63) == 0) { wsum[tid >> 6][0] = s; wsum[tid >> 6][1] = ss; }
  __syncthreads();
  if (tid == 0) {
    float S = wsum[0][0] + wsum[1][0] + wsum[2][0] + wsum[3][0];
    float SS = wsum[0][1] + wsum[1][1] + wsum[2][1] + wsum[3][1];
    sums[((b * 8 + g) * 16 + chunk) * 2 + 0] = S;
    sums[((b * 8 + g) * 16 + chunk) * 2 + 1] = SS;
  }
}

__global__ void k_gnfin(const float* __restrict__ sums, float* __restrict__ stats, float invN) {
  int i = threadIdx.x;
  if (i >= 16) return;
  float S = 0.f, SS = 0.f;
  for (int ch = 0; ch < 16; ch++) { S += sums[(i * 16 + ch) * 2]; SS += sums[(i * 16 + ch) * 2 + 1]; }
  float m = S * invN;
  float var = SS * invN - m * m;
  stats[i * 2] = m;
  stats[i * 2 + 1] = rsqrtf(var + 1e-5f);
}

// ---------------- K3: apply GN1 + GELU -> bf16 h1 ----------------
__global__ __launch_bounds__(256) void k_gn1_gelu(
    const float* __restrict__ t1, const float* __restrict__ stats1,
    const float* __restrict__ g1, const float* __restrict__ bt1,
    unsigned short* __restrict__ h1) {
  size_t i4 = ((size_t)blockIdx.x * 256 + threadIdx.x) * 4;
  int c = (int)(i4 & 127);
  int bidx = (int)(i4 >> 21);
  int g = c >> 4;
  float m = stats1[(bidx * 8 + g) * 2], is = stats1[(bidx * 8 + g) * 2 + 1];
  float4 x4 = *(const float4*)(t1 + i4);
  float y0 = geluf((x4.x - m) * is * g1[c] + bt1[c]);
  float y1 = geluf((x4.y - m) * is * g1[c + 1] + bt1[c + 1]);
  float y2 = geluf((x4.z - m) * is * g1[c + 2] + bt1[c + 2]);
  float y3 = geluf((x4.w - m) * is * g1[c + 3] + bt1[c + 3]);
  uint2 o;
  o.x = (unsigned int)f2bf(y0) | ((unsigned int)f2bf(y1) << 16);
  o.y = (unsigned int)f2bf(y2) | ((unsigned int)f2bf(y3) << 16);
  *(uint2*)(h1 + i4) = o;
}

// ---------------- K4: MFMA 3x3 circular conv (128 -> 64), 9 shifted GEMMs ----------------
__device__ __forceinline__ int cswz(int rw, int c) {
  int byte = (rw << 8) + (c << 1);
  return byte ^ ((rw & 7) << 4);
}
__global__ __launch_bounds__(256) void k_conv3(const unsigned short* __restrict__ h1,
                                               const unsigned short* __restrict__ w2p,
                                               float* __restrict__ t2) {
  __shared__ unsigned short tile[3 * 66 * 128];  // 50688 B
  int b = blockIdx.y;
  int n0 = blockIdx.x * 64;
  int h = n0 >> 10;
  int w0 = n0 & 1023;
  int tid = threadIdx.x;
  for (int i = tid; i < 3 * 66 * 16; i += 256) {
    int r = i / (66 * 16);
    int rem = i - r * 66 * 16;
    int w = rem >> 4;
    int c0 = (rem & 15) * 8;
    int hh = (h + r - 1 + HRV) & (HRV - 1);
    int wc = (w0 + w - 1 + WRV) & (WRV - 1);
    uint4 v = *(const uint4*)(h1 + ((size_t)b * NPIX + hh * WRV + wc) * 128 + c0);
    *(uint4*)((char*)tile + cswz(r * 66 + w, c0)) = v;
  }
  __syncthreads();
  int wave = tid >> 6, l = tid & 63;
  int lr = l & 15, lk = l >> 4;
  f32x4 acc[4];
#pragma unroll
  for (int nt = 0; nt < 4; nt++) acc[nt] = (f32x4){0.f, 0.f, 0.f, 0.f};
#pragma unroll
  for (int kpos = 0; kpos < 9; kpos++) {
    int ky = kpos / 3, kx = kpos - ky * 3;
    int rw = ky * 66 + wave * 16 + lr + kx;
#pragma unroll
    for (int ks = 0; ks < 4; ks++) {
      short8 a = *(const short8*)((const char*)tile + cswz(rw, ks * 32 + lk * 8));
#pragma unroll
      for (int nt = 0; nt < 4; nt++) {
        short8 bv = *(const short8*)(w2p + (size_t)(kpos * 64 + nt * 16 + lr) * 128 +
                                     ks * 32 + lk * 8);
        acc[nt] = __builtin_amdgcn_mfma_f32_16x16x32_bf16(a, bv, acc[nt], 0, 0, 0);
      }
    }
  }
#pragma unroll
  for (int nt = 0; nt < 4; nt++) {
    int o = nt * 16 + lr;
#pragma unroll
    for (int r = 0; r < 4; r++) {
      int p = n0 + wave * 16 + lk * 4 + r;
      t2[((size_t)b * NPIX + p) * 64 + o] = acc[nt][r];
    }
  }
}

// ---------------- K6: GN2+GELU -> head(4) -> params + KL ----------------
__global__ __launch_bounds__(256) void k_head(
    const float* __restrict__ t2, const float* __restrict__ stats2,
    const float* __restrict__ g2, const float* __restrict__ bt2,
    const float* __restrict__ rh_w3, const float* __restrict__ rh_b3,
    const float* __restrict__ l2e, float* __restrict__ params,
    float* __restrict__ klpart, RVConsts C) {
  int b = blockIdx.y;
  int n = blockIdx.x * 256 + threadIdx.x;
  int h = n >> 10, w = n & 1023;
  const float* t = t2 + ((size_t)b * NPIX + n) * 64;
  float hd0 = rh_b3[0], hd1 = rh_b3[1], hd2 = rh_b3[2], hd3 = rh_b3[3];
  for (int c = 0; c < 64; c++) {
    int g = c >> 3;
    float m = stats2[(b * 8 + g) * 2], is = stats2[(b * 8 + g) * 2 + 1];
    float xv = geluf((t[c] - m) * is * g2[c] + bt2[c]);
    hd0 += rh_w3[c] * xv;
    hd1 += rh_w3[64 + c] * xv;
    hd2 += rh_w3[128 + c] * xv;
    hd3 += rh_w3[192 + c] * xv;
  }
  float mu = sigmoidf_(hd0) * 55.0f;
  float sd = softplusf_(hd1) + 1e-3f;
  float stepw = C.steps[w & 15];
  float se = sigmoidf_(hd2) * stepw + 1e-3f;
  float sa = sigmoidf_(hd3) * C.az_step_f + 1e-3f;
  float E0 = C.means[h];
  float A0 = azimf(w, C.step_d, C.az0, C.az_half);
  float* P = params + ((size_t)b * NPIX + n) * 16;
  P[0] = sd; P[1] = se; P[2] = sa;
  float M00 = l2e[0], M01 = l2e[1], M10 = l2e[4], M11 = l2e[5];
  float M20 = l2e[8], M21 = l2e[9], M30 = l2e[12], M31 = l2e[13];
#pragma unroll
  for (int k = 0; k < 5; k++) {
    float off = -0.6f + 0.3f * (float)k;
    float d = mu + sd * off;
    float E = E0 + se * off;
    float A = A0 + sa * off;
    float ce = cosf(E);
    float xl = d * ce * cosf(A), yl = d * ce * sinf(A), zl = d * sinf(E);
    float px = xl * M00 + yl * M10 + zl * M20 + M30;
    float py = xl * M01 + yl * M11 + zl * M21 + M31;
    P[3 + 2 * k] = sigmoidf_(4.0f * ((px + 55.0f) * (1.0f / 110.0f) - 0.5f));
    P[4 + 2 * k] = sigmoidf_(4.0f * ((py + 55.0f) * (1.0f / 110.0f) - 0.5f));
  }
  float mu_n = mu * (1.0f / 55.0f);
  float sr = fmaxf(sd, 1e-6f);
  float saz = sa / C.az_step_f;
  float sel = se / stepw;
  float L = 0.5f * (mu_n * mu_n + sr * sr - logf(sr * sr) - 1.0f) +
            0.5f * (saz * saz - logf(saz * saz) - 1.0f) +
            0.5f * (sel * sel - logf(sel * sel) - 1.0f);
#pragma unroll
  for (int o2 = 32; o2 > 0; o2 >>= 1) L += __shfl_down(L, o2);
  __shared__ float wsum[4];
  if ((threadIdx.x & 63) == 0) wsum[threadIdx.x >> 6] = L;
  __syncthreads();
  if (threadIdx.x == 0)
    klpart[blockIdx.y * 64 + blockIdx.x] = wsum[0] + wsum[1] + wsum[2] + wsum[3];
}

// ---------------- K7: MFMA query MLP ----------------
__global__ __launch_bounds__(256) void k_query(
    const float* __restrict__ q0, const float* __restrict__ params,
    const unsigned short* __restrict__ qsW1p, const float* __restrict__ qs_b1,
    const float* __restrict__ qs_w1f,
    const unsigned short* __restrict__ qsW2p, const float* __restrict__ qs_b2,
    float* __restrict__ query) {
  __shared__ unsigned short qin[64][136];
  __shared__ unsigned short hq[64][136];
  __shared__ float sigf[64][6];
  int b = blockIdx.y;
  int n0 = blockIdx.x * 64;
  int tid = threadIdx.x;
  const float* src = q0 + ((size_t)b * NPIX + n0) * 128;
  for (int i = tid; i < 2048; i += 256) {
    int p = i >> 5, c = (i & 31) * 4;
    float4 v4 = *(const float4*)(src + p * 128 + c);
    qin[p][c] = f2bf(v4.x);
    qin[p][c + 1] = f2bf(v4.y);
    qin[p][c + 2] = f2bf(v4.z);
    qin[p][c + 3] = f2bf(v4.w);
  }
  if (tid < 64) {
    const float* P = params + ((size_t)b * NPIX + n0 + tid) * 16;
    float sd = P[0], se = P[1], sa = P[2];
    sigf[tid][0] = sd; sigf[tid][1] = se; sigf[tid][2] = sa;
    sigf[tid][3] = 1.0f / (sd + 1e-6f);
    sigf[tid][4] = 1.0f / (se + 1e-6f);
    sigf[tid][5] = 1.0f / (sa + 1e-6f);
  }
  __syncthreads();
  int wave = tid >> 6, l = tid & 63;
  int lr = l & 15, lk = l >> 4;
  f32x4 acc[8];
#pragma unroll
  for (int nt = 0; nt < 8; nt++) {
    int n = nt * 16 + lr;
    float wt[6];
#pragma unroll
    for (int c = 0; c < 6; c++) wt[c] = qs_w1f[(size_t)n * 134 + 128 + c];
    float bias = qs_b1[n];
#pragma unroll
    for (int r = 0; r < 4; r++) {
      int pl = wave * 16 + lk * 4 + r;
      float a = bias;
#pragma unroll
      for (int c = 0; c < 6; c++) a += wt[c] * sigf[pl][c];
      acc[nt][r] = a;
    }
  }
#pragma unroll
  for (int ks = 0; ks < 4; ks++) {
    short8 a = *(const short8*)&qin[wave * 16 + lr][ks * 32 + lk * 8];
#pragma unroll
    for (int nt = 0; nt < 8; nt++) {
      short8 bv = *(const short8*)(qsW1p + (size_t)(nt * 16 + lr) * 128 + ks * 32 + lk * 8);
      acc[nt] = __builtin_amdgcn_mfma_f32_16x16x32_bf16(a, bv, acc[nt], 0, 0, 0);
    }
  }
#pragma unroll
  for (int nt = 0; nt < 8; nt++)
#pragma unroll
    for (int r = 0; r < 4; r++)
      hq[wave * 16 + lk * 4 + r][nt * 16 + lr] = f2bf(geluf(acc[nt][r]));
  __syncthreads();
#pragma unroll
  for (int nt = 0; nt < 8; nt++) {
    float bias = qs_b2[nt * 16 + lr];
    acc[nt] = (f32x4){bias, bias, bias, bias};
  }
#pragma unroll
  for (int ks = 0; ks < 4; ks++) {
    short8 a = *(const short8*)&hq[wave * 16 + lr][ks * 32 + lk * 8];
#pragma unroll
    for (int nt = 0; nt < 8; nt++) {
      short8 bv = *(const short8*)(qsW2p + (size_t)(nt * 16 + lr) * 128 + ks * 32 + lk * 8);
      acc[nt] = __builtin_amdgcn_mfma_f32_16x16x32_bf16(a, bv, acc[nt], 0, 0, 0);
    }
  }
#pragma unroll
  for (int nt = 0; nt < 8; nt++) {
    int n = nt * 16 + lr;
#pragma unroll
    for (int r = 0; r < 4; r++) {
      int p = n0 + wave * 16 + lk * 4 + r;
      query[((size_t)b * NPIX + p) * 128 + n] = acc[nt][r];
    }
  }
}

// ---------------- K8: pack weights to bf16 ----------------
__global__ __launch_bounds__(256) void k_pack(
    const float* __restrict__ val_w, const float* __restrict__ w_v,
    const float* __restrict__ b_v, const float* __restrict__ val_b,
    const float* __restrict__ off_w, const float* __restrict__ off_b,
    const float* __restrict__ aw_w, const float* __restrict__ aw_b,
    const float* __restrict__ out_w, const float* __restrict__ qs_w1,
    const float* __restrict__ qs_w2, const float* __restrict__ rh_w1,
    const float* __restrict__ w_q, const float* __restrict__ w_o,
    const float* __restrict__ rh_w2,
    unsigned short* __restrict__ wvv_bf, float* __restrict__ bvv,
    unsigned short* __restrict__ projW, float* __restrict__ projB,
    unsigned short* __restrict__ outW, unsigned short* __restrict__ qsW1p,
    unsigned short* __restrict__ qsW2p, unsigned short* __restrict__ rhW1p,
    unsigned short* __restrict__ wqp, unsigned short* __restrict__ woP,
    unsigned short* __restrict__ w2p) {
  int idx = blockIdx.x * 256 + threadIdx.x;
  if (idx < 16384) {
    int o = idx >> 7, c = idx & 127;
    float acc = 0.0f;
    for (int m = 0; m < 128; m++) acc += val_w[o * 128 + m] * w_v[m * 128 + c];
    wvv_bf[idx] = f2bf(acc);
  } else if (idx < 16512) {
    int o = idx - 16384;
    float acc = val_b[o];
    for (int m = 0; m < 128; m++) acc += val_w[o * 128 + m] * b_v[m];
    bvv[o] = acc;
  } else if (idx < 82048) {
    int j = idx - 16512;
    int r = j >> 7, c = j & 127;
    float w = (r < 320) ? off_w[r * 128 + c] : ((r < 480) ? aw_w[(r - 320) * 128 + c] : 0.0f);
    projW[j] = f2bf(w);
  } else if (idx < 82560) {
    int r = idx - 82048;
    projB[r] = (r < 320) ? off_b[r] : ((r < 480) ? aw_b[r - 320] : 0.0f);
  } else if (idx < 98944) {
    int j = idx - 82560;
    outW[j] = f2bf(out_w[j]);
  } else if (idx < 115328) {
    int j = idx - 98944;
    int r = j >> 7, c = j & 127;
    qsW1p[j] = f2bf(qs_w1[r * 134 + c]);
  } else if (idx < 131712) {
    int j = idx - 115328;
    qsW2p[j] = f2bf(qs_w2[j]);
  } else if (idx < 144000) {
    int j = idx - 131712;
    int r = j / 96, c = j - r * 96;
    rhW1p[j] = (c < 67) ? f2bf(rh_w1[r * 67 + c]) : 0;
  } else if (idx < 156288) {
    int j = idx - 144000;
    int r = j / 96, c = j - r * 96;
    wqp[j] = (c < 64) ? f2bf(w_q[r * 64 + c]) : 0;
  } else if (idx < 172672) {
    int j = idx - 156288;
    woP[j] = f2bf(w_o[j]);
  } else if (idx < 246400) {
    int j = idx - 172672;          // [kpos][o][c]
    int kpos = j >> 13;
    int rem = j & 8191;
    int o = rem >> 7, c = rem & 127;
    int ky = kpos / 3, kx = kpos - ky * 3;
    w2p[j] = f2bf(rh_w2[((size_t)(o * 128 + c) * 3 + ky) * 3 + kx]);
  }
}

// ---------------- K9: MFMA value projection -> bf16 v ----------------
__global__ __launch_bounds__(256) void k_value(
    const float* __restrict__ bev, const unsigned short* __restrict__ wvv_bf,
    const float* __restrict__ bvv, unsigned short* __restrict__ v) {
  __shared__ float lds[128 * 66];
  int b = blockIdx.y;
  int p0 = blockIdx.x * 64;
  int tid = threadIdx.x;
  int npx = NBEV - p0; if (npx > 64) npx = 64;
  for (int i = tid; i < 128 * 64; i += 256) {
    int c = i >> 6, p = i & 63;
    lds[c * 66 + p] = (p < npx) ? bev[((size_t)b * 128 + c) * NBEV + p0 + p] : 0.0f;
  }
  __syncthreads();
  int wave = tid >> 6, l = tid & 63;
  int lr = l & 15, lk = l >> 4;
  int ploc = wave * 16 + lr;
  f32x4 acc[8];
#pragma unroll
  for (int nt = 0; nt < 8; nt++) {
    float bias = bvv[nt * 16 + lr];
    acc[nt] = (f32x4){bias, bias, bias, bias};
  }
#pragma unroll
  for (int ks = 0; ks < 4; ks++) {
    int k0 = ks * 32 + lk * 8;
    short8 a;
#pragma unroll
    for (int j = 0; j < 8; j++) a[j] = (short)f2bf(lds[(k0 + j) * 66 + ploc]);
#pragma unroll
    for (int nt = 0; nt < 8; nt++) {
      short8 bf = *(const short8*)(wvv_bf + (size_t)(nt * 16 + lr) * 128 + k0);
      acc[nt] = __builtin_amdgcn_mfma_f32_16x16x32_bf16(a, bf, acc[nt], 0, 0, 0);
    }
  }
#pragma unroll
  for (int nt = 0; nt < 8; nt++) {
    int n = nt * 16 + lr;
#pragma unroll
    for (int r = 0; r < 4; r++) {
      int p = p0 + wave * 16 + lk * 4 + r;
      if (p < NBEV) v[((size_t)b * NBEV + p) * 128 + n] = f2bf(acc[nt][r]);
    }
  }
}

// ---------------- K10: MFMA projection (query -> 512 outs, bf16) ----------------
__global__ __launch_bounds__(256) void k_proj(
    const float* __restrict__ query, const unsigned short* __restrict__ projW,
    const float* __restrict__ projB, unsigned short* __restrict__ proj) {
  int b = blockIdx.z;
  int wave = threadIdx.x >> 6, l = threadIdx.x & 63;
  int lr = l & 15, lk = l >> 4;
  int p0 = blockIdx.x * 64 + wave * 16;
  int n0 = blockIdx.y * 128;
  f32x4 acc[8];
#pragma unroll
  for (int nt = 0; nt < 8; nt++) {
    float bias = projB[n0 + nt * 16 + lr];
    acc[nt] = (f32x4){bias, bias, bias, bias};
  }
  const float* ap = query + ((size_t)b * NPIX + p0 + lr) * 128 + lk * 8;
#pragma unroll
  for (int ks = 0; ks < 4; ks++) {
    float4 a0 = *(const float4*)(ap + ks * 32);
    float4 a1 = *(const float4*)(ap + ks * 32 + 4);
    short8 a;
    a[0] = (short)f2bf(a0.x); a[1] = (short)f2bf(a0.y);
    a[2] = (short)f2bf(a0.z); a[3] = (short)f2bf(a0.w);
    a[4] = (short)f2bf(a1.x); a[5] = (short)f2bf(a1.y);
    a[6] = (short)f2bf(a1.z); a[7] = (short)f2bf(a1.w);
#pragma unroll
    for (int nt = 0; nt < 8; nt++) {
      short8 bf = *(const short8*)(projW + (size_t)(n0 + nt * 16 + lr) * 128 + ks * 32 + lk * 8);
      acc[nt] = __builtin_amdgcn_mfma_f32_16x16x32_bf16(a, bf, acc[nt], 0, 0, 0);
    }
  }
#pragma unroll
  for (int nt = 0; nt < 8; nt++) {
    int n = n0 + nt * 16 + lr;
#pragma unroll
    for (int r = 0; r < 4; r++) {
      int p = p0 + lk * 4 + r;
      proj[((size_t)b * NPIX + p) * 512 + n] = f2bf(acc[nt][r]);
    }
  }
}

// ---------------- K11: sampler — 4 lanes per (pixel,head), tap-split + shfl softmax ----------------
// Lane q of a 4-lane group owns taps kp = q*5 .. q*5+4 for ALL 16 channels; softmax
// max/sum via __shfl_xor(1/2); final acc reduced across the group; lane q==0 stores.
__global__ __launch_bounds__(256) void k_samp(
    const unsigned short* __restrict__ proj, const float* __restrict__ params,
    const unsigned short* __restrict__ v, unsigned short* __restrict__ S) {
  int b = blockIdx.y;
  int bid = blockIdx.x;
  int pb = (bid & 7) * 256 + (bid >> 3);  // XCD-chunked swizzle (2048 = 8*256)
  int tid = threadIdx.x;
  int q = tid & 3, hh = (tid >> 2) & 7, pl = tid >> 5;
  int n = pb * 8 + pl;
  const unsigned short* base = proj + ((size_t)b * NPIX + n) * 512;
  // 5 logits owned by this lane
  float lg[5];
#pragma unroll
  for (int t = 0; t < 5; t++) lg[t] = bf2f(base[320 + hh * 20 + q * 5 + t]);
  float mx = fmaxf(fmaxf(fmaxf(lg[0], lg[1]), fmaxf(lg[2], lg[3])), lg[4]);
  mx = fmaxf(mx, __shfl_xor(mx, 1));
  mx = fmaxf(mx, __shfl_xor(mx, 2));
  float e[5];
  float s = 0.0f;
#pragma unroll
  for (int t = 0; t < 5; t++) { e[t] = expf(lg[t] - mx); s += e[t]; }
  s += __shfl_xor(s, 1);
  s += __shfl_xor(s, 2);
  float rs = 1.0f / s;
  const float* P = params + ((size_t)b * NPIX + n) * 16;
  const unsigned short* vb = v + (size_t)b * NBEV * 128 + hh * 16;
  float acc[16];
#pragma unroll
  for (int c = 0; c < 16; c++) acc[c] = 0.0f;
#pragma unroll
  for (int t = 0; t < 5; t++) {
    int kp = q * 5 + t;
    int k = kp >> 2;
    unsigned int u = *(const unsigned int*)(base + hh * 40 + kp * 2);
    float X = P[3 + 2 * k] * 220.0f - 0.5f + bf2f((unsigned short)(u & 0xffffu));
    float Y = P[4 + 2 * k] * 220.0f - 0.5f + bf2f((unsigned short)(u >> 16));
    float xf = floorf(X), yf = floorf(Y);
    float wx = X - xf, wy = Y - yf;
    int x0 = (int)xf, y0 = (int)yf;
    float wx0 = ((unsigned)x0 < 220u) ? (1.0f - wx) : 0.0f;
    float wx1 = ((unsigned)(x0 + 1) < 220u) ? wx : 0.0f;
    float wy0 = ((unsigned)y0 < 220u) ? (1.0f - wy) : 0.0f;
    float wy1 = ((unsigned)(y0 + 1) < 220u) ? wy : 0.0f;
    int cx0 = min(max(x0, 0), 219), cx1 = min(max(x0 + 1, 0), 219);
    int cy0 = min(max(y0, 0), 219) * 220, cy1 = min(max(y0 + 1, 0), 219) * 220;
    float a = e[t] * rs;
    float u0 = a * wy0, u1 = a * wy1;
    float w4[4] = {u0 * wx0, u0 * wx1, u1 * wx0, u1 * wx1};
    int i4[4] = {cy0 + cx0, cy0 + cx1, cy1 + cx0, cy1 + cx1};
#pragma unroll
    for (int c2 = 0; c2 < 4; c2++) {
      float w = w4[c2];
      const uint4* sp = (const uint4*)(vb + (size_t)i4[c2] * 128);
      uint4 r0 = sp[0], r1 = sp[1];
      acc[0] += w * bf2f((unsigned short)(r0.x & 0xffffu));
      acc[1] += w * bf2f((unsigned short)(r0.x >> 16));
      acc[2] += w * bf2f((unsigned short)(r0.y & 0xffffu));
      acc[3] += w * bf2f((unsigned short)(r0.y >> 16));
      acc[4] += w * bf2f((unsigned short)(r0.z & 0xffffu));
      acc[5] += w * bf2f((unsigned short)(r0.z >> 16));
      acc[6] += w * bf2f((unsigned short)(r0.w & 0xffffu));
      acc[7] += w * bf2f((unsigned short)(r0.w >> 16));
      acc[8] += w * bf2f((unsigned short)(r1.x & 0xffffu));
      acc[9] += w * bf2f((unsigned short)(r1.x >> 16));
      acc[10] += w * bf2f((unsigned short)(r1.y & 0xffffu));
      acc[11] += w * bf2f((unsigned short)(r1.y >> 16));
      acc[12] += w * bf2f((unsigned short)(r1.z & 0xffffu));
      acc[13] += w * bf2f((unsigned short)(r1.z >> 16));
      acc[14] += w * bf2f((unsigned short)(r1.w & 0xffffu));
      acc[15] += w * bf2f((unsigned short)(r1.w >> 16));
    }
  }
#pragma unroll
  for (int c = 0; c < 16; c++) {
    acc[c] += __shfl_xor(acc[c], 1);
    acc[c] += __shfl_xor(acc[c], 2);
  }
  if (q == 0) {
    uint4 o1, o2;
    o1.x = (unsigned int)f2bf(acc[0]) | ((unsigned int)f2bf(acc[1]) << 16);
    o1.y = (unsigned int)f2bf(acc[2]) | ((unsigned int)f2bf(acc[3]) << 16);
    o1.z = (unsigned int)f2bf(acc[4]) | ((unsigned int)f2bf(acc[5]) << 16);
    o1.w = (unsigned int)f2bf(acc[6]) | ((unsigned int)f2bf(acc[7]) << 16);
    o2.x = (unsigned int)f2bf(acc[8]) | ((unsigned int)f2bf(acc[9]) << 16);
    o2.y = (unsigned int)f2bf(acc[10]) | ((unsigned int)f2bf(acc[11]) << 16);
    o2.z = (unsigned int)f2bf(acc[12]) | ((unsigned int)f2bf(acc[13]) << 16);
    o2.w = (unsigned int)f2bf(acc[14]) | ((unsigned int)f2bf(acc[15]) << 16);
    unsigned short* dst = S + ((size_t)b * NPIX + n) * 128 + hh * 16;
    *(uint4*)dst = o1;
    *(uint4*)(dst + 8) = o2;
  }
}

// ---------------- K12: MFMA out-projection + residual ----------------
__global__ __launch_bounds__(256) void k_out(
    const unsigned short* __restrict__ S, const unsigned short* __restrict__ outW,
    const float* __restrict__ out_b, const float* __restrict__ query,
    float* __restrict__ ymsda) {
  int b = blockIdx.y;
  int wave = threadIdx.x >> 6, l = threadIdx.x & 63;
  int lr = l & 15, lk = l >> 4;
  int p0 = blockIdx.x * 64 + wave * 16;
  f32x4 acc[8];
#pragma unroll
  for (int nt = 0; nt < 8; nt++) {
    float bias = out_b[nt * 16 + lr];
    acc[nt] = (f32x4){bias, bias, bias, bias};
  }
  const unsigned short* ap = S + ((size_t)b * NPIX + p0 + lr) * 128 + lk * 8;
#pragma unroll
  for (int ks = 0; ks < 4; ks++) {
    short8 a = *(const short8*)(ap + ks * 32);
#pragma unroll
    for (int nt = 0; nt < 8; nt++) {
      short8 bf = *(const short8*)(outW + (size_t)(nt * 16 + lr) * 128 + ks * 32 + lk * 8);
      acc[nt] = __builtin_amdgcn_mfma_f32_16x16x32_bf16(a, bf, acc[nt], 0, 0, 0);
    }
  }
#pragma unroll
  for (int nt = 0; nt < 8; nt++) {
    int n = nt * 16 + lr;
#pragma unroll
    for (int r = 0; r < 4; r++) {
      int p = p0 + lk * 4 + r;
      size_t o = ((size_t)b * NPIX + p) * 128 + n;
      ymsda[o] = acc[nt][r] + query[o];
    }
  }
}

// ---------------- K13: MFMA final conv1x1 + transposed NCHW store ----------------
__global__ __launch_bounds__(256) void k_final(
    const float* __restrict__ ymsda, const unsigned short* __restrict__ woP,
    const float* __restrict__ b_o, float* __restrict__ out) {
  __shared__ float yt[128][67];
  int b = blockIdx.y;
  int p0 = blockIdx.x * 64;
  int tid = threadIdx.x;
  int wave = tid >> 6, l = tid & 63;
  int lr = l & 15, lk = l >> 4;
  f32x4 acc[8];
#pragma unroll
  for (int nt = 0; nt < 8; nt++) {
    float bias = b_o[nt * 16 + lr];
    acc[nt] = (f32x4){bias, bias, bias, bias};
  }
  const float* ap = ymsda + ((size_t)b * NPIX + p0 + wave * 16 + lr) * 128 + lk * 8;
#pragma unroll
  for (int ks = 0; ks < 4; ks++) {
    float4 a0 = *(const float4*)(ap + ks * 32);
    float4 a1 = *(const float4*)(ap + ks * 32 + 4);
    short8 a;
    a[0] = (short)f2bf(a0.x); a[1] = (short)f2bf(a0.y);
    a[2] = (short)f2bf(a0.z); a[3] = (short)f2bf(a0.w);
    a[4] = (short)f2bf(a1.x); a[5] = (short)f2bf(a1.y);
    a[6] = (short)f2bf(a1.z); a[7] = (short)f2bf(a1.w);
#pragma unroll
    for (int nt = 0; nt < 8; nt++) {
      short8 bf = *(const short8*)(woP + (size_t)(nt * 16 + lr) * 128 + ks * 32 + lk * 8);
      acc[nt] = __builtin_amdgcn_mfma_f32_16x16x32_bf16(a, bf, acc[nt], 0, 0, 0);
    }
  }
#pragma unroll
  for (int nt = 0; nt < 8; nt++)
#pragma unroll
    for (int r = 0; r < 4; r++)
      yt[nt * 16 + lr][wave * 16 + lk * 4 + r] = acc[nt][r];
  __syncthreads();
  int n = tid >> 1, half = tid & 1;
  float* dst = out + ((size_t)(b * 128 + n)) * NPIX + p0 + half * 32;
#pragma unroll
  for (int j = 0; j < 8; j++) {
    float4 v4 = {yt[n][half * 32 + j * 4], yt[n][half * 32 + j * 4 + 1],
                 yt[n][half * 32 + j * 4 + 2], yt[n][half * 32 + j * 4 + 3]};
    *(float4*)(dst + j * 4) = v4;
  }
}

__global__ void k_klfin(const float* __restrict__ klpart, float* __restrict__ out) {
  if (threadIdx.x == 0) {
    float s = 0.0f;
    for (int i = 0; i < 128; i++) s += klpart[i];
    out[(size_t)BSZ * 128 * NPIX] = 1e-4f * (s / 32768.0f);
  }
}

// ---------------- host ----------------
static RVConsts make_consts() {
  static const float ELEV[32] = {
      -30.67f, -29.33f, -28.0f, -26.66f, -25.33f, -24.0f, -22.67f, -21.33f,
      -20.0f,  -18.67f, -17.33f, -16.0f, -14.67f, -13.33f, -12.0f, -10.67f,
      -9.33f,  -8.0f,   -6.66f,  -5.33f, -4.0f,   -2.67f,  -1.33f, 0.0f,
      1.33f,   2.67f,   4.0f,    5.33f,  6.67f,   8.0f,    9.33f,  10.67f};
  RVConsts C;
  const float d2r = 0.017453292519943295f;
  for (int r = 0; r < 16; r++) {
    float a = ELEV[31 - 2 * r], b = ELEV[30 - 2 * r];
    float mx = fmaxf(a, b), mn = fminf(a, b);
    C.steps[r] = (mx - mn) * d2r;
    C.means[r] = ((a + b) * 0.5f) * d2r;
  }
  const double PI_D = 3.14159265358979323846;
  double step_d = (PI_D - (-PI_D)) / 1024.0;
  double az0 = -PI_D;
  double az1 = az0 + step_d;
  double az_step_d = az1 - az0;
  C.az_step_f = (float)az_step_d;
  C.pad_ = 0.0f;
  C.step_d = step_d;
  C.az0 = az0;
  C.az_half = az_step_d * 0.5;
  return C;
}

// Workspace layout (f32 words). Peak 21,620,608 words = 86.5 MB.
#define OFF_T1     0u
#define OFF_H1     4194304u    /* bf16 x 4,194,304 -> 2,097,152 w */
#define OFF_T2     8388608u
#define OFF_Q0     10485760u
#define OFF_PARAMS 14680064u
#define OFF_QUERY  15204352u
#define OFF_S      19398656u
#define OFF_SUMS1  21495808u
#define OFF_SUMS2  21496320u
#define OFF_STATS1 21496832u
#define OFF_STATS2 21496864u
#define OFF_KL     21496896u
#define OFF_PROJ   0u          /* bf16 x 16,777,216 = 8,388,608 w (after conv3; t1/h1 dead) */
#define OFF_V      8388608u    /* bf16 x 12,390,400 = 6,195,200 w (after head+query) */
#define OFF_YMSDA  0u          /* f32 x 4,194,304 (after samp consumes proj) */
#define OFF_WVV    21497088u
#define OFF_BVV    21505280u
#define OFF_PROJW  21505408u
#define OFF_PROJB  21538176u
#define OFF_OUTW   21538688u
#define OFF_QSW1   21546880u
#define OFF_QSW2   21555072u
#define OFF_RHW1   21563264u
#define OFF_WQP    21569408u
#define OFF_WOP    21575552u
#define OFF_W2P    21583744u   /* bf16 x 73728 -> 36864 w */

extern "C" void kernel_launch(void* const* d_in, const int* in_sizes, int n_in,
                              void* d_out, int out_size, void* d_ws, size_t ws_size,
                              hipStream_t stream) {
  const float* x_rv = (const float*)d_in[0];
  const float* bev = (const float*)d_in[1];
  const float* l2e = (const float*)d_in[2];
  const float* w_q = (const float*)d_in[3];
  const float* b_q = (const float*)d_in[4];
  const float* w_v = (const float*)d_in[5];
  const float* b_v = (const float*)d_in[6];
  const float* w_o = (const float*)d_in[7];
  const float* b_o = (const float*)d_in[8];
  const float* qs_w1 = (const float*)d_in[9];
  const float* qs_b1 = (const float*)d_in[10];
  const float* qs_w2 = (const float*)d_in[11];
  const float* qs_b2 = (const float*)d_in[12];
  const float* rh_w1 = (const float*)d_in[13];
  const float* rh_b1 = (const float*)d_in[14];
  const float* rh_g1 = (const float*)d_in[15];
  const float* rh_bt1 = (const float*)d_in[16];
  const float* rh_w2 = (const float*)d_in[17];
  const float* rh_g2 = (const float*)d_in[18];
  const float* rh_bt2 = (const float*)d_in[19];
  const float* rh_w3 = (const float*)d_in[20];
  const float* rh_b3 = (const float*)d_in[21];
  const float* off_w = (const float*)d_in[22];
  const float* off_b = (const float*)d_in[23];
  const float* aw_w = (const float*)d_in[24];
  const float* aw_b = (const float*)d_in[25];
  const float* val_w = (const float*)d_in[26];
  const float* val_b = (const float*)d_in[27];
  const float* out_w = (const float*)d_in[28];
  const float* out_b = (const float*)d_in[29];

  float* ws = (float*)d_ws;
  float* t1 = ws + OFF_T1;
  float* t2 = ws + OFF_T2;
  float* q0 = ws + OFF_Q0;
  float* params = ws + OFF_PARAMS;
  float* query = ws + OFF_QUERY;
  float* sums1 = ws + OFF_SUMS1;
  float* sums2 = ws + OFF_SUMS2;
  float* stats1 = ws + OFF_STATS1;
  float* stats2 = ws + OFF_STATS2;
  float* klpart = ws + OFF_KL;
  float* bvv = ws + OFF_BVV;
  float* projB = ws + OFF_PROJB;
  float* ymsda = ws + OFF_YMSDA;
  unsigned short* h1bf = (unsigned short*)(ws + OFF_H1);
  unsigned short* S_bf = (unsigned short*)(ws + OFF_S);
  unsigned short* proj_bf = (unsigned short*)(ws + OFF_PROJ);
  unsigned short* v_bf = (unsigned short*)(ws + OFF_V);
  unsigned short* wvv_bf = (unsigned short*)(ws + OFF_WVV);
  unsigned short* projW = (unsigned short*)(ws + OFF_PROJW);
  unsigned short* outW = (unsigned short*)(ws + OFF_OUTW);
  unsigned short* qsW1p = (unsigned short*)(ws + OFF_QSW1);
  unsigned short* qsW2p = (unsigned short*)(ws + OFF_QSW2);
  unsigned short* rhW1p = (unsigned short*)(ws + OFF_RHW1);
  unsigned short* wqp = (unsigned short*)(ws + OFF_WQP);
  unsigned short* woP = (unsigned short*)(ws + OFF_WOP);
  unsigned short* w2p = (unsigned short*)(ws + OFF_W2P);

  RVConsts C = make_consts();
  dim3 blk(256);

  k_pack<<<963, blk, 0, stream>>>(val_w, w_v, b_v, val_b, off_w, off_b, aw_w, aw_b, out_w,
                                  qs_w1, qs_w2, rh_w1, w_q, w_o, rh_w2,
                                  wvv_bf, bvv, projW, projB, outW, qsW1p, qsW2p, rhW1p,
                                  wqp, woP, w2p);
  k_rh1_q0<<<dim3(256, BSZ), blk, 0, stream>>>(x_rv, rhW1p, rh_b1, wqp, b_q, t1, q0, C);
  k_gnsum<128, 16><<<dim3(16, 8, BSZ), blk, 0, stream>>>(t1, sums1);
  k_gnfin<<<1, 64, 0, stream>>>(sums1, stats1, 1.0f / 262144.0f);
  k_gn1_gelu<<<4096, blk, 0, stream>>>(t1, stats1, rh_g1, rh_bt1, h1bf);
  k_conv3<<<dim3(256, BSZ), blk, 0, stream>>>(h1bf, w2p, t2);
  k_gnsum<64, 8><<<dim3(16, 8, BSZ), blk, 0, stream>>>(t2, sums2);
  k_gnfin<<<1, 64, 0, stream>>>(sums2, stats2, 1.0f / 131072.0f);
  k_head<<<dim3(64, BSZ), blk, 0, stream>>>(t2, stats2, rh_g2, rh_bt2, rh_w3, rh_b3,
                                            l2e, params, klpart, C);
  k_query<<<dim3(256, BSZ), blk, 0, stream>>>(q0, params, qsW1p, qs_b1, qs_w1, qsW2p,
                                              qs_b2, query);
  k_value<<<dim3(757, BSZ), blk, 0, stream>>>(bev, wvv_bf, bvv, v_bf);
  k_proj<<<dim3(256, 4, BSZ), blk, 0, stream>>>(query, projW, projB, proj_bf);
  k_samp<<<dim3(2048, BSZ), blk, 0, stream>>>(proj_bf, params, v_bf, S_bf);
  k_out<<<dim3(256, BSZ), blk, 0, stream>>>(S_bf, outW, out_b, query, ymsda);
  k_final<<<dim3(256, BSZ), blk, 0, stream>>>(ymsda, woP, b_o, (float*)d_out);
  k_klfin<<<1, 64, 0, stream>>>(klpart, (float*)d_out);
}

// Round 8
// 335.526 us; speedup vs baseline: 1.8609x; 1.0597x over previous
//
#include <hip/hip_runtime.h>
#include <math.h>

#define HRV 16
#define WRV 1024
#define NPIX 16384
#define NBEV 48400
#define BSZ 2

typedef __attribute__((ext_vector_type(8))) short short8;
typedef __attribute__((ext_vector_type(4))) float f32x4;

struct RVConsts {
  float steps[16];
  float means[16];
  float az_step_f;
  float pad_;
  double step_d;
  double az0;
  double az_half;
};

__device__ __forceinline__ float geluf(float x) {
  return 0.5f * x * (1.0f + erff(x * 0.70710678118654752440f));
}
__device__ __forceinline__ float sigmoidf_(float x) {
  return 1.0f / (1.0f + expf(-x));
}
__device__ __forceinline__ float softplusf_(float x) {
  return fmaxf(x, 0.0f) + log1pf(expf(-fabsf(x)));
}
__device__ __forceinline__ float azimf(int w, double step_d, double az0, double az_half) {
  double az = (double)w * step_d + az0;
  az += az_half;
  return (float)az;
}
__device__ __forceinline__ unsigned short f2bf(float f) {
  unsigned int u = __builtin_bit_cast(unsigned int, f);
  u = u + 0x7FFFu + ((u >> 16) & 1u);
  return (unsigned short)(u >> 16);
}
__device__ __forceinline__ float bf2f(unsigned short h) {
  unsigned int u = ((unsigned int)h) << 16;
  return __builtin_bit_cast(float, u);
}

// ---------------- K1: MFMA range-head conv1 (67->128) + Q0 conv (64->128) ----------------
__global__ __launch_bounds__(256) void k_rh1_q0(
    const float* __restrict__ x_rv,
    const unsigned short* __restrict__ rhW1p, const float* __restrict__ rh_b1,
    const unsigned short* __restrict__ wqp, const float* __restrict__ b_q,
    float* __restrict__ t1, unsigned short* __restrict__ q0, RVConsts C) {
  __shared__ unsigned short xin[64][104];
  int b = blockIdx.y;
  int n0 = blockIdx.x * 64;
  int tid = threadIdx.x;
  const float* src = x_rv + ((size_t)b * NPIX + n0) * 64;
  for (int i = tid; i < 1024; i += 256) {
    int p = i >> 4, c = (i & 15) * 4;
    float4 v4 = *(const float4*)(src + p * 64 + c);
    xin[p][c] = f2bf(v4.x);
    xin[p][c + 1] = f2bf(v4.y);
    xin[p][c + 2] = f2bf(v4.z);
    xin[p][c + 3] = f2bf(v4.w);
  }
  if (tid < 64) {
    int n = n0 + tid;
    int h = n >> 10, w = n & 1023;
    float E = C.means[h];
    float A = azimf(w, C.step_d, C.az0, C.az_half);
    float ce = cosf(E);
    xin[tid][64] = f2bf(ce * cosf(A));
    xin[tid][65] = f2bf(ce * sinf(A));
    xin[tid][66] = f2bf(sinf(E));
    for (int c = 67; c < 104; c++) xin[tid][c] = 0;
  }
  __syncthreads();
  int wave = tid >> 6, l = tid & 63;
  int lr = l & 15, lk = l >> 4;
  f32x4 acc[8], accq[8];
#pragma unroll
  for (int nt = 0; nt < 8; nt++) {
    float b1 = rh_b1[nt * 16 + lr], b2 = b_q[nt * 16 + lr];
    acc[nt] = (f32x4){b1, b1, b1, b1};
    accq[nt] = (f32x4){b2, b2, b2, b2};
  }
#pragma unroll
  for (int ks = 0; ks < 3; ks++) {
    short8 a = *(const short8*)&xin[wave * 16 + lr][ks * 32 + lk * 8];
#pragma unroll
    for (int nt = 0; nt < 8; nt++) {
      short8 b1v = *(const short8*)(rhW1p + (size_t)(nt * 16 + lr) * 96 + ks * 32 + lk * 8);
      acc[nt] = __builtin_amdgcn_mfma_f32_16x16x32_bf16(a, b1v, acc[nt], 0, 0, 0);
      short8 b2v = *(const short8*)(wqp + (size_t)(nt * 16 + lr) * 96 + ks * 32 + lk * 8);
      accq[nt] = __builtin_amdgcn_mfma_f32_16x16x32_bf16(a, b2v, accq[nt], 0, 0, 0);
    }
  }
#pragma unroll
  for (int nt = 0; nt < 8; nt++) {
    int n = nt * 16 + lr;
#pragma unroll
    for (int r = 0; r < 4; r++) {
      int p = n0 + wave * 16 + lk * 4 + r;
      size_t o = ((size_t)b * NPIX + p) * 128 + n;
      t1[o] = acc[nt][r];
      q0[o] = f2bf(accq[nt][r]);
    }
  }
}

// ---------------- GroupNorm partial sums ----------------
template <int CCH, int CGRP>
__global__ __launch_bounds__(256) void k_gnsum(const float* __restrict__ src,
                                               float* __restrict__ sums) {
  int chunk = blockIdx.x;
  int g = blockIdx.y;
  int b = blockIdx.z;
  const int npx = NPIX / 16;
  int n0 = chunk * npx;
  int tid = threadIdx.x;
  float s = 0.f, ss = 0.f;
  const float* base = src + (size_t)b * NPIX * CCH + (size_t)g * CGRP;
  const int total = npx * CGRP;
  for (int i = tid; i < total; i += 256) {
    int n = i / CGRP;
    int cc = i % CGRP;
    float x = base[(size_t)(n0 + n) * CCH + cc];
    s += x; ss += x * x;
  }
#pragma unroll
  for (int o2 = 32; o2 > 0; o2 >>= 1) { s += __shfl_down(s, o2); ss += __shfl_down(ss, o2); }
  __shared__ float wsum[4][2];
  if ((tid & 63) == 0) { wsum[tid >> 6][0] = s; wsum[tid >> 6][1] = ss; }
  __syncthreads();
  if (tid == 0) {
    float S = wsum[0][0] + wsum[1][0] + wsum[2][0] + wsum[3][0];
    float SS = wsum[0][1] + wsum[1][1] + wsum[2][1] + wsum[3][1];
    sums[((b * 8 + g) * 16 + chunk) * 2 + 0] = S;
    sums[((b * 8 + g) * 16 + chunk) * 2 + 1] = SS;
  }
}

// ---------------- K3: apply GN1 + GELU -> bf16 h1 (stats inlined from sums) ----------------
__global__ __launch_bounds__(256) void k_gn1_gelu(
    const float* __restrict__ t1, const float* __restrict__ sums1,
    const float* __restrict__ g1, const float* __restrict__ bt1,
    unsigned short* __restrict__ h1) {
  __shared__ float st[8][2];
  size_t i4 = ((size_t)blockIdx.x * 256 + threadIdx.x) * 4;
  int bidx = (int)(i4 >> 21);
  if (threadIdx.x < 8) {
    int g = threadIdx.x;
    float S = 0.f, SS = 0.f;
    for (int ch = 0; ch < 16; ch++) {
      S += sums1[((bidx * 8 + g) * 16 + ch) * 2];
      SS += sums1[((bidx * 8 + g) * 16 + ch) * 2 + 1];
    }
    float m = S * (1.0f / 262144.0f);
    float var = SS * (1.0f / 262144.0f) - m * m;
    st[g][0] = m;
    st[g][1] = rsqrtf(var + 1e-5f);
  }
  __syncthreads();
  int c = (int)(i4 & 127);
  int g = c >> 4;
  float m = st[g][0], is = st[g][1];
  float4 x4 = *(const float4*)(t1 + i4);
  float y0 = geluf((x4.x - m) * is * g1[c] + bt1[c]);
  float y1 = geluf((x4.y - m) * is * g1[c + 1] + bt1[c + 1]);
  float y2 = geluf((x4.z - m) * is * g1[c + 2] + bt1[c + 2]);
  float y3 = geluf((x4.w - m) * is * g1[c + 3] + bt1[c + 3]);
  uint2 o;
  o.x = (unsigned int)f2bf(y0) | ((unsigned int)f2bf(y1) << 16);
  o.y = (unsigned int)f2bf(y2) | ((unsigned int)f2bf(y3) << 16);
  *(uint2*)(h1 + i4) = o;
}

// ---------------- K4: MFMA 3x3 circular conv, 16-rows x 8-cols tile (no vertical halo) ----------------
// LDS: [16 h-rows][10 w-cols][128 c] bf16, swizzle byte ^= ((row&7)<<4). 40 KB.
__device__ __forceinline__ int cswz2(int row, int colw, int c) {
  int byte = ((row * 10 + colw) << 8) + (c << 1);
  return byte ^ ((row & 7) << 4);
}
__global__ __launch_bounds__(256) void k_conv3(const unsigned short* __restrict__ h1,
                                               const unsigned short* __restrict__ w2p,
                                               float* __restrict__ t2) {
  __shared__ unsigned short tile[16 * 10 * 128];  // 40960 B
  int b = blockIdx.y;
  int w0 = blockIdx.x * 8;
  int tid = threadIdx.x;
  // stage: 16 rows x 10 cols x 16 chunks of 8 bf16 (16B); 2560 items, 10/thread
  for (int i = tid; i < 2560; i += 256) {
    int row = i / 160;
    int rem = i - row * 160;
    int colw = rem >> 4;
    int c0 = (rem & 15) * 8;
    int wc = (w0 + colw - 1 + WRV) & (WRV - 1);
    uint4 v = *(const uint4*)(h1 + ((size_t)b * NPIX + row * WRV + wc) * 128 + c0);
    *(uint4*)((char*)tile + cswz2(row, colw, c0)) = v;
  }
  __syncthreads();
  int wave = tid >> 6, l = tid & 63;
  int lr = l & 15, lk = l >> 4;
  f32x4 acc[2][4];
#pragma unroll
  for (int cc2 = 0; cc2 < 2; cc2++)
#pragma unroll
    for (int nt = 0; nt < 4; nt++) acc[cc2][nt] = (f32x4){0.f, 0.f, 0.f, 0.f};
#pragma unroll
  for (int kpos = 0; kpos < 9; kpos++) {
    int ky = kpos / 3, kx = kpos - ky * 3;
    int arow = (lr + ky - 1 + 16) & 15;
#pragma unroll
    for (int cc2 = 0; cc2 < 2; cc2++) {
      int acol = wave * 2 + cc2 + kx;  // lds col: pixel col (wave*2+cc2) + kx - 1 + 1
#pragma unroll
      for (int ks = 0; ks < 4; ks++) {
        short8 a = *(const short8*)((const char*)tile + cswz2(arow, acol, ks * 32 + lk * 8));
#pragma unroll
        for (int nt = 0; nt < 4; nt++) {
          short8 bv = *(const short8*)(w2p + (size_t)(kpos * 64 + nt * 16 + lr) * 128 +
                                       ks * 32 + lk * 8);
          acc[cc2][nt] = __builtin_amdgcn_mfma_f32_16x16x32_bf16(a, bv, acc[cc2][nt], 0, 0, 0);
        }
      }
    }
  }
#pragma unroll
  for (int cc2 = 0; cc2 < 2; cc2++) {
    int cc = wave * 2 + cc2;
#pragma unroll
    for (int nt = 0; nt < 4; nt++) {
      int o = nt * 16 + lr;
#pragma unroll
      for (int r = 0; r < 4; r++) {
        int p = (lk * 4 + r) * WRV + w0 + cc;
        t2[((size_t)b * NPIX + p) * 64 + o] = acc[cc2][nt][r];
      }
    }
  }
}

// ---------------- K6: GN2+GELU -> head(4) -> params + KL (stats2 inlined) ----------------
__global__ __launch_bounds__(256) void k_head(
    const float* __restrict__ t2, const float* __restrict__ sums2,
    const float* __restrict__ g2, const float* __restrict__ bt2,
    const float* __restrict__ rh_w3, const float* __restrict__ rh_b3,
    const float* __restrict__ l2e, float* __restrict__ params,
    float* __restrict__ klpart, RVConsts C) {
  __shared__ float st2[8][2];
  int b = blockIdx.y;
  if (threadIdx.x < 8) {
    int g = threadIdx.x;
    float S = 0.f, SS = 0.f;
    for (int ch = 0; ch < 16; ch++) {
      S += sums2[((b * 8 + g) * 16 + ch) * 2];
      SS += sums2[((b * 8 + g) * 16 + ch) * 2 + 1];
    }
    float m = S * (1.0f / 131072.0f);
    float var = SS * (1.0f / 131072.0f) - m * m;
    st2[g][0] = m;
    st2[g][1] = rsqrtf(var + 1e-5f);
  }
  __syncthreads();
  int n = blockIdx.x * 256 + threadIdx.x;
  int h = n >> 10, w = n & 1023;
  const float* t = t2 + ((size_t)b * NPIX + n) * 64;
  float hd0 = rh_b3[0], hd1 = rh_b3[1], hd2 = rh_b3[2], hd3 = rh_b3[3];
  for (int c = 0; c < 64; c++) {
    int g = c >> 3;
    float xv = geluf((t[c] - st2[g][0]) * st2[g][1] * g2[c] + bt2[c]);
    hd0 += rh_w3[c] * xv;
    hd1 += rh_w3[64 + c] * xv;
    hd2 += rh_w3[128 + c] * xv;
    hd3 += rh_w3[192 + c] * xv;
  }
  float mu = sigmoidf_(hd0) * 55.0f;
  float sd = softplusf_(hd1) + 1e-3f;
  float stepw = C.steps[w & 15];
  float se = sigmoidf_(hd2) * stepw + 1e-3f;
  float sa = sigmoidf_(hd3) * C.az_step_f + 1e-3f;
  float E0 = C.means[h];
  float A0 = azimf(w, C.step_d, C.az0, C.az_half);
  float* P = params + ((size_t)b * NPIX + n) * 16;
  P[0] = sd; P[1] = se; P[2] = sa;
  float M00 = l2e[0], M01 = l2e[1], M10 = l2e[4], M11 = l2e[5];
  float M20 = l2e[8], M21 = l2e[9], M30 = l2e[12], M31 = l2e[13];
#pragma unroll
  for (int k = 0; k < 5; k++) {
    float off = -0.6f + 0.3f * (float)k;
    float d = mu + sd * off;
    float E = E0 + se * off;
    float A = A0 + sa * off;
    float ce = cosf(E);
    float xl = d * ce * cosf(A), yl = d * ce * sinf(A), zl = d * sinf(E);
    float px = xl * M00 + yl * M10 + zl * M20 + M30;
    float py = xl * M01 + yl * M11 + zl * M21 + M31;
    P[3 + 2 * k] = sigmoidf_(4.0f * ((px + 55.0f) * (1.0f / 110.0f) - 0.5f));
    P[4 + 2 * k] = sigmoidf_(4.0f * ((py + 55.0f) * (1.0f / 110.0f) - 0.5f));
  }
  float mu_n = mu * (1.0f / 55.0f);
  float sr = fmaxf(sd, 1e-6f);
  float saz = sa / C.az_step_f;
  float sel = se / stepw;
  float L = 0.5f * (mu_n * mu_n + sr * sr - logf(sr * sr) - 1.0f) +
            0.5f * (saz * saz - logf(saz * saz) - 1.0f) +
            0.5f * (sel * sel - logf(sel * sel) - 1.0f);
#pragma unroll
  for (int o2 = 32; o2 > 0; o2 >>= 1) L += __shfl_down(L, o2);
  __shared__ float wsum[4];
  if ((threadIdx.x & 63) == 0) wsum[threadIdx.x >> 6] = L;
  __syncthreads();
  if (threadIdx.x == 0)
    klpart[blockIdx.y * 64 + blockIdx.x] = wsum[0] + wsum[1] + wsum[2] + wsum[3];
}

// ---------------- K7: MFMA query MLP (q0 bf16 in, query bf16 out) ----------------
__global__ __launch_bounds__(256) void k_query(
    const unsigned short* __restrict__ q0, const float* __restrict__ params,
    const unsigned short* __restrict__ qsW1p, const float* __restrict__ qs_b1,
    const float* __restrict__ qs_w1f,
    const unsigned short* __restrict__ qsW2p, const float* __restrict__ qs_b2,
    unsigned short* __restrict__ query) {
  __shared__ unsigned short qin[64][136];
  __shared__ unsigned short hq[64][136];
  __shared__ float sigf[64][6];
  int b = blockIdx.y;
  int n0 = blockIdx.x * 64;
  int tid = threadIdx.x;
  const unsigned short* src = q0 + ((size_t)b * NPIX + n0) * 128;
  for (int i = tid; i < 1024; i += 256) {
    int p = i >> 4, c0 = (i & 15) * 8;
    uint4 v = *(const uint4*)(src + p * 128 + c0);
    *(uint4*)&qin[p][c0] = v;
  }
  if (tid < 64) {
    const float* P = params + ((size_t)b * NPIX + n0 + tid) * 16;
    float sd = P[0], se = P[1], sa = P[2];
    sigf[tid][0] = sd; sigf[tid][1] = se; sigf[tid][2] = sa;
    sigf[tid][3] = 1.0f / (sd + 1e-6f);
    sigf[tid][4] = 1.0f / (se + 1e-6f);
    sigf[tid][5] = 1.0f / (sa + 1e-6f);
  }
  __syncthreads();
  int wave = tid >> 6, l = tid & 63;
  int lr = l & 15, lk = l >> 4;
  f32x4 acc[8];
#pragma unroll
  for (int nt = 0; nt < 8; nt++) {
    int n = nt * 16 + lr;
    float wt[6];
#pragma unroll
    for (int c = 0; c < 6; c++) wt[c] = qs_w1f[(size_t)n * 134 + 128 + c];
    float bias = qs_b1[n];
#pragma unroll
    for (int r = 0; r < 4; r++) {
      int pl = wave * 16 + lk * 4 + r;
      float a = bias;
#pragma unroll
      for (int c = 0; c < 6; c++) a += wt[c] * sigf[pl][c];
      acc[nt][r] = a;
    }
  }
#pragma unroll
  for (int ks = 0; ks < 4; ks++) {
    short8 a = *(const short8*)&qin[wave * 16 + lr][ks * 32 + lk * 8];
#pragma unroll
    for (int nt = 0; nt < 8; nt++) {
      short8 bv = *(const short8*)(qsW1p + (size_t)(nt * 16 + lr) * 128 + ks * 32 + lk * 8);
      acc[nt] = __builtin_amdgcn_mfma_f32_16x16x32_bf16(a, bv, acc[nt], 0, 0, 0);
    }
  }
#pragma unroll
  for (int nt = 0; nt < 8; nt++)
#pragma unroll
    for (int r = 0; r < 4; r++)
      hq[wave * 16 + lk * 4 + r][nt * 16 + lr] = f2bf(geluf(acc[nt][r]));
  __syncthreads();
#pragma unroll
  for (int nt = 0; nt < 8; nt++) {
    float bias = qs_b2[nt * 16 + lr];
    acc[nt] = (f32x4){bias, bias, bias, bias};
  }
#pragma unroll
  for (int ks = 0; ks < 4; ks++) {
    short8 a = *(const short8*)&hq[wave * 16 + lr][ks * 32 + lk * 8];
#pragma unroll
    for (int nt = 0; nt < 8; nt++) {
      short8 bv = *(const short8*)(qsW2p + (size_t)(nt * 16 + lr) * 128 + ks * 32 + lk * 8);
      acc[nt] = __builtin_amdgcn_mfma_f32_16x16x32_bf16(a, bv, acc[nt], 0, 0, 0);
    }
  }
#pragma unroll
  for (int nt = 0; nt < 8; nt++) {
    int n = nt * 16 + lr;
#pragma unroll
    for (int r = 0; r < 4; r++) {
      int p = n0 + wave * 16 + lk * 4 + r;
      query[((size_t)b * NPIX + p) * 128 + n] = f2bf(acc[nt][r]);
    }
  }
}

// ---------------- K8: pack weights to bf16 ----------------
__global__ __launch_bounds__(256) void k_pack(
    const float* __restrict__ val_w, const float* __restrict__ w_v,
    const float* __restrict__ b_v, const float* __restrict__ val_b,
    const float* __restrict__ off_w, const float* __restrict__ off_b,
    const float* __restrict__ aw_w, const float* __restrict__ aw_b,
    const float* __restrict__ out_w, const float* __restrict__ qs_w1,
    const float* __restrict__ qs_w2, const float* __restrict__ rh_w1,
    const float* __restrict__ w_q, const float* __restrict__ w_o,
    const float* __restrict__ rh_w2,
    unsigned short* __restrict__ wvv_bf, float* __restrict__ bvv,
    unsigned short* __restrict__ projW, float* __restrict__ projB,
    unsigned short* __restrict__ outW, unsigned short* __restrict__ qsW1p,
    unsigned short* __restrict__ qsW2p, unsigned short* __restrict__ rhW1p,
    unsigned short* __restrict__ wqp, unsigned short* __restrict__ woP,
    unsigned short* __restrict__ w2p) {
  int idx = blockIdx.x * 256 + threadIdx.x;
  if (idx < 16384) {
    int o = idx >> 7, c = idx & 127;
    float acc = 0.0f;
    for (int m = 0; m < 128; m++) acc += val_w[o * 128 + m] * w_v[m * 128 + c];
    wvv_bf[idx] = f2bf(acc);
  } else if (idx < 16512) {
    int o = idx - 16384;
    float acc = val_b[o];
    for (int m = 0; m < 128; m++) acc += val_w[o * 128 + m] * b_v[m];
    bvv[o] = acc;
  } else if (idx < 82048) {
    int j = idx - 16512;
    int r = j >> 7, c = j & 127;
    float w = (r < 320) ? off_w[r * 128 + c] : ((r < 480) ? aw_w[(r - 320) * 128 + c] : 0.0f);
    projW[j] = f2bf(w);
  } else if (idx < 82560) {
    int r = idx - 82048;
    projB[r] = (r < 320) ? off_b[r] : ((r < 480) ? aw_b[r - 320] : 0.0f);
  } else if (idx < 98944) {
    int j = idx - 82560;
    outW[j] = f2bf(out_w[j]);
  } else if (idx < 115328) {
    int j = idx - 98944;
    int r = j >> 7, c = j & 127;
    qsW1p[j] = f2bf(qs_w1[r * 134 + c]);
  } else if (idx < 131712) {
    int j = idx - 115328;
    qsW2p[j] = f2bf(qs_w2[j]);
  } else if (idx < 144000) {
    int j = idx - 131712;
    int r = j / 96, c = j - r * 96;
    rhW1p[j] = (c < 67) ? f2bf(rh_w1[r * 67 + c]) : 0;
  } else if (idx < 156288) {
    int j = idx - 144000;
    int r = j / 96, c = j - r * 96;
    wqp[j] = (c < 64) ? f2bf(w_q[r * 64 + c]) : 0;
  } else if (idx < 172672) {
    int j = idx - 156288;
    woP[j] = f2bf(w_o[j]);
  } else if (idx < 246400) {
    int j = idx - 172672;          // [kpos][o][c]
    int kpos = j >> 13;
    int rem = j & 8191;
    int o = rem >> 7, c = rem & 127;
    int ky = kpos / 3, kx = kpos - ky * 3;
    w2p[j] = f2bf(rh_w2[((size_t)(o * 128 + c) * 3 + ky) * 3 + kx]);
  }
}

// ---------------- K9: MFMA value projection -> bf16 v ----------------
__global__ __launch_bounds__(256) void k_value(
    const float* __restrict__ bev, const unsigned short* __restrict__ wvv_bf,
    const float* __restrict__ bvv, unsigned short* __restrict__ v) {
  __shared__ float lds[128 * 66];
  int b = blockIdx.y;
  int p0 = blockIdx.x * 64;
  int tid = threadIdx.x;
  int npx = NBEV - p0; if (npx > 64) npx = 64;
  for (int i = tid; i < 128 * 64; i += 256) {
    int c = i >> 6, p = i & 63;
    lds[c * 66 + p] = (p < npx) ? bev[((size_t)b * 128 + c) * NBEV + p0 + p] : 0.0f;
  }
  __syncthreads();
  int wave = tid >> 6, l = tid & 63;
  int lr = l & 15, lk = l >> 4;
  int ploc = wave * 16 + lr;
  f32x4 acc[8];
#pragma unroll
  for (int nt = 0; nt < 8; nt++) {
    float bias = bvv[nt * 16 + lr];
    acc[nt] = (f32x4){bias, bias, bias, bias};
  }
#pragma unroll
  for (int ks = 0; ks < 4; ks++) {
    int k0 = ks * 32 + lk * 8;
    short8 a;
#pragma unroll
    for (int j = 0; j < 8; j++) a[j] = (short)f2bf(lds[(k0 + j) * 66 + ploc]);
#pragma unroll
    for (int nt = 0; nt < 8; nt++) {
      short8 bf = *(const short8*)(wvv_bf + (size_t)(nt * 16 + lr) * 128 + k0);
      acc[nt] = __builtin_amdgcn_mfma_f32_16x16x32_bf16(a, bf, acc[nt], 0, 0, 0);
    }
  }
#pragma unroll
  for (int nt = 0; nt < 8; nt++) {
    int n = nt * 16 + lr;
#pragma unroll
    for (int r = 0; r < 4; r++) {
      int p = p0 + wave * 16 + lk * 4 + r;
      if (p < NBEV) v[((size_t)b * NBEV + p) * 128 + n] = f2bf(acc[nt][r]);
    }
  }
}

// ---------------- K10: MFMA projection (query bf16 -> 512 outs, bf16) ----------------
__global__ __launch_bounds__(256) void k_proj(
    const unsigned short* __restrict__ query, const unsigned short* __restrict__ projW,
    const float* __restrict__ projB, unsigned short* __restrict__ proj) {
  int b = blockIdx.z;
  int wave = threadIdx.x >> 6, l = threadIdx.x & 63;
  int lr = l & 15, lk = l >> 4;
  int p0 = blockIdx.x * 64 + wave * 16;
  int n0 = blockIdx.y * 128;
  f32x4 acc[8];
#pragma unroll
  for (int nt = 0; nt < 8; nt++) {
    float bias = projB[n0 + nt * 16 + lr];
    acc[nt] = (f32x4){bias, bias, bias, bias};
  }
  const unsigned short* ap = query + ((size_t)b * NPIX + p0 + lr) * 128 + lk * 8;
#pragma unroll
  for (int ks = 0; ks < 4; ks++) {
    short8 a = *(const short8*)(ap + ks * 32);
#pragma unroll
    for (int nt = 0; nt < 8; nt++) {
      short8 bf = *(const short8*)(projW + (size_t)(n0 + nt * 16 + lr) * 128 + ks * 32 + lk * 8);
      acc[nt] = __builtin_amdgcn_mfma_f32_16x16x32_bf16(a, bf, acc[nt], 0, 0, 0);
    }
  }
#pragma unroll
  for (int nt = 0; nt < 8; nt++) {
    int n = n0 + nt * 16 + lr;
#pragma unroll
    for (int r = 0; r < 4; r++) {
      int p = p0 + lk * 4 + r;
      proj[((size_t)b * NPIX + p) * 512 + n] = f2bf(acc[nt][r]);
    }
  }
}

// ---------------- K11: sampler — 4 lanes per (pixel,head), tap-split + shfl softmax ----------------
__global__ __launch_bounds__(256) void k_samp(
    const unsigned short* __restrict__ proj, const float* __restrict__ params,
    const unsigned short* __restrict__ v, unsigned short* __restrict__ S) {
  int b = blockIdx.y;
  int bid = blockIdx.x;
  int pb = (bid & 7) * 256 + (bid >> 3);  // XCD-chunked swizzle
  int tid = threadIdx.x;
  int q = tid & 3, hh = (tid >> 2) & 7, pl = tid >> 5;
  int n = pb * 8 + pl;
  const unsigned short* base = proj + ((size_t)b * NPIX + n) * 512;
  float lg[5];
#pragma unroll
  for (int t = 0; t < 5; t++) lg[t] = bf2f(base[320 + hh * 20 + q * 5 + t]);
  float mx = fmaxf(fmaxf(fmaxf(lg[0], lg[1]), fmaxf(lg[2], lg[3])), lg[4]);
  mx = fmaxf(mx, __shfl_xor(mx, 1));
  mx = fmaxf(mx, __shfl_xor(mx, 2));
  float e[5];
  float s = 0.0f;
#pragma unroll
  for (int t = 0; t < 5; t++) { e[t] = expf(lg[t] - mx); s += e[t]; }
  s += __shfl_xor(s, 1);
  s += __shfl_xor(s, 2);
  float rs = 1.0f / s;
  const float* P = params + ((size_t)b * NPIX + n) * 16;
  const unsigned short* vb = v + (size_t)b * NBEV * 128 + hh * 16;
  float acc[16];
#pragma unroll
  for (int c = 0; c < 16; c++) acc[c] = 0.0f;
#pragma unroll
  for (int t = 0; t < 5; t++) {
    int kp = q * 5 + t;
    int k = kp >> 2;
    unsigned int u = *(const unsigned int*)(base + hh * 40 + kp * 2);
    float X = P[3 + 2 * k] * 220.0f - 0.5f + bf2f((unsigned short)(u & 0xffffu));
    float Y = P[4 + 2 * k] * 220.0f - 0.5f + bf2f((unsigned short)(u >> 16));
    float xf = floorf(X), yf = floorf(Y);
    float wx = X - xf, wy = Y - yf;
    int x0 = (int)xf, y0 = (int)yf;
    float wx0 = ((unsigned)x0 < 220u) ? (1.0f - wx) : 0.0f;
    float wx1 = ((unsigned)(x0 + 1) < 220u) ? wx : 0.0f;
    float wy0 = ((unsigned)y0 < 220u) ? (1.0f - wy) : 0.0f;
    float wy1 = ((unsigned)(y0 + 1) < 220u) ? wy : 0.0f;
    int cx0 = min(max(x0, 0), 219), cx1 = min(max(x0 + 1, 0), 219);
    int cy0 = min(max(y0, 0), 219) * 220, cy1 = min(max(y0 + 1, 0), 219) * 220;
    float a = e[t] * rs;
    float u0 = a * wy0, u1 = a * wy1;
    float w4[4] = {u0 * wx0, u0 * wx1, u1 * wx0, u1 * wx1};
    int i4[4] = {cy0 + cx0, cy0 + cx1, cy1 + cx0, cy1 + cx1};
#pragma unroll
    for (int c2 = 0; c2 < 4; c2++) {
      float w = w4[c2];
      const uint4* sp = (const uint4*)(vb + (size_t)i4[c2] * 128);
      uint4 r0 = sp[0], r1 = sp[1];
      acc[0] += w * bf2f((unsigned short)(r0.x & 0xffffu));
      acc[1] += w * bf2f((unsigned short)(r0.x >> 16));
      acc[2] += w * bf2f((unsigned short)(r0.y & 0xffffu));
      acc[3] += w * bf2f((unsigned short)(r0.y >> 16));
      acc[4] += w * bf2f((unsigned short)(r0.z & 0xffffu));
      acc[5] += w * bf2f((unsigned short)(r0.z >> 16));
      acc[6] += w * bf2f((unsigned short)(r0.w & 0xffffu));
      acc[7] += w * bf2f((unsigned short)(r0.w >> 16));
      acc[8] += w * bf2f((unsigned short)(r1.x & 0xffffu));
      acc[9] += w * bf2f((unsigned short)(r1.x >> 16));
      acc[10] += w * bf2f((unsigned short)(r1.y & 0xffffu));
      acc[11] += w * bf2f((unsigned short)(r1.y >> 16));
      acc[12] += w * bf2f((unsigned short)(r1.z & 0xffffu));
      acc[13] += w * bf2f((unsigned short)(r1.z >> 16));
      acc[14] += w * bf2f((unsigned short)(r1.w & 0xffffu));
      acc[15] += w * bf2f((unsigned short)(r1.w >> 16));
    }
  }
#pragma unroll
  for (int c = 0; c < 16; c++) {
    acc[c] += __shfl_xor(acc[c], 1);
    acc[c] += __shfl_xor(acc[c], 2);
  }
  if (q == 0) {
    uint4 o1, o2;
    o1.x = (unsigned int)f2bf(acc[0]) | ((unsigned int)f2bf(acc[1]) << 16);
    o1.y = (unsigned int)f2bf(acc[2]) | ((unsigned int)f2bf(acc[3]) << 16);
    o1.z = (unsigned int)f2bf(acc[4]) | ((unsigned int)f2bf(acc[5]) << 16);
    o1.w = (unsigned int)f2bf(acc[6]) | ((unsigned int)f2bf(acc[7]) << 16);
    o2.x = (unsigned int)f2bf(acc[8]) | ((unsigned int)f2bf(acc[9]) << 16);
    o2.y = (unsigned int)f2bf(acc[10]) | ((unsigned int)f2bf(acc[11]) << 16);
    o2.z = (unsigned int)f2bf(acc[12]) | ((unsigned int)f2bf(acc[13]) << 16);
    o2.w = (unsigned int)f2bf(acc[14]) | ((unsigned int)f2bf(acc[15]) << 16);
    unsigned short* dst = S + ((size_t)b * NPIX + n) * 128 + hh * 16;
    *(uint4*)dst = o1;
    *(uint4*)(dst + 8) = o2;
  }
}

// ---------------- K12: MFMA out-projection + residual -> ymsda bf16 ----------------
__global__ __launch_bounds__(256) void k_out(
    const unsigned short* __restrict__ S, const unsigned short* __restrict__ outW,
    const float* __restrict__ out_b, const unsigned short* __restrict__ query,
    unsigned short* __restrict__ ymsda) {
  int b = blockIdx.y;
  int wave = threadIdx.x >> 6, l = threadIdx.x & 63;
  int lr = l & 15, lk = l >> 4;
  int p0 = blockIdx.x * 64 + wave * 16;
  f32x4 acc[8];
#pragma unroll
  for (int nt = 0; nt < 8; nt++) {
    float bias = out_b[nt * 16 + lr];
    acc[nt] = (f32x4){bias, bias, bias, bias};
  }
  const unsigned short* ap = S + ((size_t)b * NPIX + p0 + lr) * 128 + lk * 8;
#pragma unroll
  for (int ks = 0; ks < 4; ks++) {
    short8 a = *(const short8*)(ap + ks * 32);
#pragma unroll
    for (int nt = 0; nt < 8; nt++) {
      short8 bf = *(const short8*)(outW + (size_t)(nt * 16 + lr) * 128 + ks * 32 + lk * 8);
      acc[nt] = __builtin_amdgcn_mfma_f32_16x16x32_bf16(a, bf, acc[nt], 0, 0, 0);
    }
  }
#pragma unroll
  for (int nt = 0; nt < 8; nt++) {
    int n = nt * 16 + lr;
#pragma unroll
    for (int r = 0; r < 4; r++) {
      int p = p0 + lk * 4 + r;
      size_t o = ((size_t)b * NPIX + p) * 128 + n;
      ymsda[o] = f2bf(acc[nt][r] + bf2f(query[o]));
    }
  }
}

// ---------------- K13: MFMA final conv1x1 + transposed NCHW store ----------------
__global__ __launch_bounds__(256) void k_final(
    const unsigned short* __restrict__ ymsda, const unsigned short* __restrict__ woP,
    const float* __restrict__ b_o, float* __restrict__ out) {
  __shared__ float yt[128][67];
  int b = blockIdx.y;
  int p0 = blockIdx.x * 64;
  int tid = threadIdx.x;
  int wave = tid >> 6, l = tid & 63;
  int lr = l & 15, lk = l >> 4;
  f32x4 acc[8];
#pragma unroll
  for (int nt = 0; nt < 8; nt++) {
    float bias = b_o[nt * 16 + lr];
    acc[nt] = (f32x4){bias, bias, bias, bias};
  }
  const unsigned short* ap = ymsda + ((size_t)b * NPIX + p0 + wave * 16 + lr) * 128 + lk * 8;
#pragma unroll
  for (int ks = 0; ks < 4; ks++) {
    short8 a = *(const short8*)(ap + ks * 32);
#pragma unroll
    for (int nt = 0; nt < 8; nt++) {
      short8 bf = *(const short8*)(woP + (size_t)(nt * 16 + lr) * 128 + ks * 32 + lk * 8);
      acc[nt] = __builtin_amdgcn_mfma_f32_16x16x32_bf16(a, bf, acc[nt], 0, 0, 0);
    }
  }
#pragma unroll
  for (int nt = 0; nt < 8; nt++)
#pragma unroll
    for (int r = 0; r < 4; r++)
      yt[nt * 16 + lr][wave * 16 + lk * 4 + r] = acc[nt][r];
  __syncthreads();
  int n = tid >> 1, half = tid & 1;
  float* dst = out + ((size_t)(b * 128 + n)) * NPIX + p0 + half * 32;
#pragma unroll
  for (int j = 0; j < 8; j++) {
    float4 v4 = {yt[n][half * 32 + j * 4], yt[n][half * 32 + j * 4 + 1],
                 yt[n][half * 32 + j * 4 + 2], yt[n][half * 32 + j * 4 + 3]};
    *(float4*)(dst + j * 4) = v4;
  }
}

__global__ void k_klfin(const float* __restrict__ klpart, float* __restrict__ out) {
  if (threadIdx.x == 0) {
    float s = 0.0f;
    for (int i = 0; i < 128; i++) s += klpart[i];
    out[(size_t)BSZ * 128 * NPIX] = 1e-4f * (s / 32768.0f);
  }
}

// ---------------- host ----------------
static RVConsts make_consts() {
  static const float ELEV[32] = {
      -30.67f, -29.33f, -28.0f, -26.66f, -25.33f, -24.0f, -22.67f, -21.33f,
      -20.0f,  -18.67f, -17.33f, -16.0f, -14.67f, -13.33f, -12.0f, -10.67f,
      -9.33f,  -8.0f,   -6.66f,  -5.33f, -4.0f,   -2.67f,  -1.33f, 0.0f,
      1.33f,   2.67f,   4.0f,    5.33f,  6.67f,   8.0f,    9.33f,  10.67f};
  RVConsts C;
  const float d2r = 0.017453292519943295f;
  for (int r = 0; r < 16; r++) {
    float a = ELEV[31 - 2 * r], b = ELEV[30 - 2 * r];
    float mx = fmaxf(a, b), mn = fminf(a, b);
    C.steps[r] = (mx - mn) * d2r;
    C.means[r] = ((a + b) * 0.5f) * d2r;
  }
  const double PI_D = 3.14159265358979323846;
  double step_d = (PI_D - (-PI_D)) / 1024.0;
  double az0 = -PI_D;
  double az1 = az0 + step_d;
  double az_step_d = az1 - az0;
  C.az_step_f = (float)az_step_d;
  C.pad_ = 0.0f;
  C.step_d = step_d;
  C.az0 = az0;
  C.az_half = az_step_d * 0.5;
  return C;
}

// Workspace layout (f32 words). Peak 21,620,608 words = 86.5 MB.
#define OFF_T1     0u
#define OFF_H1     4194304u    /* bf16 x 4,194,304 -> 2,097,152 w */
#define OFF_T2     8388608u
#define OFF_Q0     10485760u   /* bf16 x 4,194,304 -> 2,097,152 w */
#define OFF_PARAMS 14680064u
#define OFF_QUERY  15204352u   /* bf16 x 4,194,304 -> 2,097,152 w */
#define OFF_S      19398656u
#define OFF_SUMS1  21495808u
#define OFF_SUMS2  21496320u
#define OFF_KL     21496896u
#define OFF_PROJ   0u          /* bf16 x 16,777,216 (after conv3; t1/h1 dead) */
#define OFF_V      8388608u    /* bf16 x 12,390,400 (after head+query; t2/q0 dead) */
#define OFF_YMSDA  0u          /* bf16 x 4,194,304 (after samp consumes proj) */
#define OFF_WVV    21497088u
#define OFF_BVV    21505280u
#define OFF_PROJW  21505408u
#define OFF_PROJB  21538176u
#define OFF_OUTW   21538688u
#define OFF_QSW1   21546880u
#define OFF_QSW2   21555072u
#define OFF_RHW1   21563264u
#define OFF_WQP    21569408u
#define OFF_WOP    21575552u
#define OFF_W2P    21583744u

extern "C" void kernel_launch(void* const* d_in, const int* in_sizes, int n_in,
                              void* d_out, int out_size, void* d_ws, size_t ws_size,
                              hipStream_t stream) {
  const float* x_rv = (const float*)d_in[0];
  const float* bev = (const float*)d_in[1];
  const float* l2e = (const float*)d_in[2];
  const float* w_q = (const float*)d_in[3];
  const float* b_q = (const float*)d_in[4];
  const float* w_v = (const float*)d_in[5];
  const float* b_v = (const float*)d_in[6];
  const float* w_o = (const float*)d_in[7];
  const float* b_o = (const float*)d_in[8];
  const float* qs_w1 = (const float*)d_in[9];
  const float* qs_b1 = (const float*)d_in[10];
  const float* qs_w2 = (const float*)d_in[11];
  const float* qs_b2 = (const float*)d_in[12];
  const float* rh_w1 = (const float*)d_in[13];
  const float* rh_b1 = (const float*)d_in[14];
  const float* rh_g1 = (const float*)d_in[15];
  const float* rh_bt1 = (const float*)d_in[16];
  const float* rh_w2 = (const float*)d_in[17];
  const float* rh_g2 = (const float*)d_in[18];
  const float* rh_bt2 = (const float*)d_in[19];
  const float* rh_w3 = (const float*)d_in[20];
  const float* rh_b3 = (const float*)d_in[21];
  const float* off_w = (const float*)d_in[22];
  const float* off_b = (const float*)d_in[23];
  const float* aw_w = (const float*)d_in[24];
  const float* aw_b = (const float*)d_in[25];
  const float* val_w = (const float*)d_in[26];
  const float* val_b = (const float*)d_in[27];
  const float* out_w = (const float*)d_in[28];
  const float* out_b = (const float*)d_in[29];

  float* ws = (float*)d_ws;
  float* t1 = ws + OFF_T1;
  float* t2 = ws + OFF_T2;
  float* params = ws + OFF_PARAMS;
  float* sums1 = ws + OFF_SUMS1;
  float* sums2 = ws + OFF_SUMS2;
  float* klpart = ws + OFF_KL;
  float* bvv = ws + OFF_BVV;
  float* projB = ws + OFF_PROJB;
  unsigned short* h1bf = (unsigned short*)(ws + OFF_H1);
  unsigned short* q0bf = (unsigned short*)(ws + OFF_Q0);
  unsigned short* querybf = (unsigned short*)(ws + OFF_QUERY);
  unsigned short* ymsdabf = (unsigned short*)(ws + OFF_YMSDA);
  unsigned short* S_bf = (unsigned short*)(ws + OFF_S);
  unsigned short* proj_bf = (unsigned short*)(ws + OFF_PROJ);
  unsigned short* v_bf = (unsigned short*)(ws + OFF_V);
  unsigned short* wvv_bf = (unsigned short*)(ws + OFF_WVV);
  unsigned short* projW = (unsigned short*)(ws + OFF_PROJW);
  unsigned short* outW = (unsigned short*)(ws + OFF_OUTW);
  unsigned short* qsW1p = (unsigned short*)(ws + OFF_QSW1);
  unsigned short* qsW2p = (unsigned short*)(ws + OFF_QSW2);
  unsigned short* rhW1p = (unsigned short*)(ws + OFF_RHW1);
  unsigned short* wqp = (unsigned short*)(ws + OFF_WQP);
  unsigned short* woP = (unsigned short*)(ws + OFF_WOP);
  unsigned short* w2p = (unsigned short*)(ws + OFF_W2P);

  RVConsts C = make_consts();
  dim3 blk(256);

  k_pack<<<963, blk, 0, stream>>>(val_w, w_v, b_v, val_b, off_w, off_b, aw_w, aw_b, out_w,
                                  qs_w1, qs_w2, rh_w1, w_q, w_o, rh_w2,
                                  wvv_bf, bvv, projW, projB, outW, qsW1p, qsW2p, rhW1p,
                                  wqp, woP, w2p);
  k_rh1_q0<<<dim3(256, BSZ), blk, 0, stream>>>(x_rv, rhW1p, rh_b1, wqp, b_q, t1, q0bf, C);
  k_gnsum<128, 16><<<dim3(16, 8, BSZ), blk, 0, stream>>>(t1, sums1);
  k_gn1_gelu<<<4096, blk, 0, stream>>>(t1, sums1, rh_g1, rh_bt1, h1bf);
  k_conv3<<<dim3(128, BSZ), blk, 0, stream>>>(h1bf, w2p, t2);
  k_gnsum<64, 8><<<dim3(16, 8, BSZ), blk, 0, stream>>>(t2, sums2);
  k_head<<<dim3(64, BSZ), blk, 0, stream>>>(t2, sums2, rh_g2, rh_bt2, rh_w3, rh_b3,
                                            l2e, params, klpart, C);
  k_query<<<dim3(256, BSZ), blk, 0, stream>>>(q0bf, params, qsW1p, qs_b1, qs_w1, qsW2p,
                                              qs_b2, querybf);
  k_value<<<dim3(757, BSZ), blk, 0, stream>>>(bev, wvv_bf, bvv, v_bf);
  k_proj<<<dim3(256, 4, BSZ), blk, 0, stream>>>(querybf, projW, projB, proj_bf);
  k_samp<<<dim3(2048, BSZ), blk, 0, stream>>>(proj_bf, params, v_bf, S_bf);
  k_out<<<dim3(256, BSZ), blk, 0, stream>>>(S_bf, outW, out_b, querybf, ymsdabf);
  k_final<<<dim3(256, BSZ), blk, 0, stream>>>(ymsdabf, woP, b_o, (float*)d_out);
  k_klfin<<<1, 64, 0, stream>>>(klpart, (float*)d_out);
}

// Round 9
// 294.181 us; speedup vs baseline: 2.1224x; 1.1405x over previous
//
#include <hip/hip_runtime.h>
#include <math.h>

#define HRV 16
#define WRV 1024
#define NPIX 16384
#define NBEV 48400
#define BSZ 2

typedef __attribute__((ext_vector_type(8))) short short8;
typedef __attribute__((ext_vector_type(4))) float f32x4;

struct RVConsts {
  float steps[16];
  float means[16];
  float az_step_f;
  float pad_;
  double step_d;
  double az0;
  double az_half;
};

__device__ __forceinline__ float geluf(float x) {
  return 0.5f * x * (1.0f + erff(x * 0.70710678118654752440f));
}
__device__ __forceinline__ float sigmoidf_(float x) {
  return 1.0f / (1.0f + expf(-x));
}
__device__ __forceinline__ float softplusf_(float x) {
  return fmaxf(x, 0.0f) + log1pf(expf(-fabsf(x)));
}
__device__ __forceinline__ float azimf(int w, double step_d, double az0, double az_half) {
  double az = (double)w * step_d + az0;
  az += az_half;
  return (float)az;
}
__device__ __forceinline__ unsigned short f2bf(float f) {
  unsigned int u = __builtin_bit_cast(unsigned int, f);
  u = u + 0x7FFFu + ((u >> 16) & 1u);
  return (unsigned short)(u >> 16);
}
__device__ __forceinline__ float bf2f(unsigned short h) {
  unsigned int u = ((unsigned int)h) << 16;
  return __builtin_bit_cast(float, u);
}

// ---------------- K1: MFMA rh-conv1 + Q0 conv + fused gnsum1 partials ----------------
__global__ __launch_bounds__(256) void k_rh1_q0(
    const float* __restrict__ x_rv,
    const unsigned short* __restrict__ rhW1p, const float* __restrict__ rh_b1,
    const unsigned short* __restrict__ wqp, const float* __restrict__ b_q,
    float* __restrict__ t1, unsigned short* __restrict__ q0,
    float* __restrict__ sums1, RVConsts C) {
  __shared__ unsigned short xin[64][104];
  __shared__ float wred[4][8][2];
  int b = blockIdx.y;
  int n0 = blockIdx.x * 64;
  int tid = threadIdx.x;
  const float* src = x_rv + ((size_t)b * NPIX + n0) * 64;
  for (int i = tid; i < 1024; i += 256) {
    int p = i >> 4, c = (i & 15) * 4;
    float4 v4 = *(const float4*)(src + p * 64 + c);
    xin[p][c] = f2bf(v4.x);
    xin[p][c + 1] = f2bf(v4.y);
    xin[p][c + 2] = f2bf(v4.z);
    xin[p][c + 3] = f2bf(v4.w);
  }
  if (tid < 64) {
    int n = n0 + tid;
    int h = n >> 10, w = n & 1023;
    float E = C.means[h];
    float A = azimf(w, C.step_d, C.az0, C.az_half);
    float ce = cosf(E);
    xin[tid][64] = f2bf(ce * cosf(A));
    xin[tid][65] = f2bf(ce * sinf(A));
    xin[tid][66] = f2bf(sinf(E));
    for (int c = 67; c < 104; c++) xin[tid][c] = 0;
  }
  __syncthreads();
  int wave = tid >> 6, l = tid & 63;
  int lr = l & 15, lk = l >> 4;
  f32x4 acc[8], accq[8];
#pragma unroll
  for (int nt = 0; nt < 8; nt++) {
    float b1 = rh_b1[nt * 16 + lr], b2 = b_q[nt * 16 + lr];
    acc[nt] = (f32x4){b1, b1, b1, b1};
    accq[nt] = (f32x4){b2, b2, b2, b2};
  }
#pragma unroll
  for (int ks = 0; ks < 3; ks++) {
    short8 a = *(const short8*)&xin[wave * 16 + lr][ks * 32 + lk * 8];
#pragma unroll
    for (int nt = 0; nt < 8; nt++) {
      short8 b1v = *(const short8*)(rhW1p + (size_t)(nt * 16 + lr) * 96 + ks * 32 + lk * 8);
      acc[nt] = __builtin_amdgcn_mfma_f32_16x16x32_bf16(a, b1v, acc[nt], 0, 0, 0);
      short8 b2v = *(const short8*)(wqp + (size_t)(nt * 16 + lr) * 96 + ks * 32 + lk * 8);
      accq[nt] = __builtin_amdgcn_mfma_f32_16x16x32_bf16(a, b2v, accq[nt], 0, 0, 0);
    }
  }
#pragma unroll
  for (int nt = 0; nt < 8; nt++) {
    int n = nt * 16 + lr;
#pragma unroll
    for (int r = 0; r < 4; r++) {
      int p = n0 + wave * 16 + lk * 4 + r;
      size_t o = ((size_t)b * NPIX + p) * 128 + n;
      t1[o] = acc[nt][r];
      q0[o] = f2bf(accq[nt][r]);
    }
  }
  // fused gnsum1 partial: group g == nt (n = nt*16 + lr, lr<16)
  float s1[8], ss1[8];
#pragma unroll
  for (int nt = 0; nt < 8; nt++) {
    float a0 = acc[nt][0], a1 = acc[nt][1], a2 = acc[nt][2], a3 = acc[nt][3];
    s1[nt] = a0 + a1 + a2 + a3;
    ss1[nt] = a0 * a0 + a1 * a1 + a2 * a2 + a3 * a3;
  }
#pragma unroll
  for (int nt = 0; nt < 8; nt++) {
    s1[nt] += __shfl_xor(s1[nt], 1);  ss1[nt] += __shfl_xor(ss1[nt], 1);
    s1[nt] += __shfl_xor(s1[nt], 2);  ss1[nt] += __shfl_xor(ss1[nt], 2);
    s1[nt] += __shfl_xor(s1[nt], 4);  ss1[nt] += __shfl_xor(ss1[nt], 4);
    s1[nt] += __shfl_xor(s1[nt], 8);  ss1[nt] += __shfl_xor(ss1[nt], 8);
    s1[nt] += __shfl_xor(s1[nt], 16); ss1[nt] += __shfl_xor(ss1[nt], 16);
    s1[nt] += __shfl_xor(s1[nt], 32); ss1[nt] += __shfl_xor(ss1[nt], 32);
  }
  if (l == 0) {
#pragma unroll
    for (int nt = 0; nt < 8; nt++) { wred[wave][nt][0] = s1[nt]; wred[wave][nt][1] = ss1[nt]; }
  }
  __syncthreads();
  if (tid < 8) {
    float S = wred[0][tid][0] + wred[1][tid][0] + wred[2][tid][0] + wred[3][tid][0];
    float SS = wred[0][tid][1] + wred[1][tid][1] + wred[2][tid][1] + wred[3][tid][1];
    sums1[(((size_t)b * 8 + tid) * 256 + blockIdx.x) * 2 + 0] = S;
    sums1[(((size_t)b * 8 + tid) * 256 + blockIdx.x) * 2 + 1] = SS;
  }
}

// ---------------- K2: MFMA 3x3 circular conv with fused GN1+GELU staging + gnsum2 ----------------
__device__ __forceinline__ int cswz2(int row, int colw, int c) {
  int byte = ((row * 10 + colw) << 8) + (c << 1);
  return byte ^ ((row & 7) << 4);
}
__global__ __launch_bounds__(256) void k_conv3g(
    const float* __restrict__ t1, const float* __restrict__ sums1,
    const float* __restrict__ g1, const float* __restrict__ bt1,
    const unsigned short* __restrict__ w2p,
    float* __restrict__ t2, float* __restrict__ sums2) {
  __shared__ unsigned short tile[16 * 10 * 128];  // 40960 B
  __shared__ float st[8][2];
  __shared__ float wred[4][2][4][2];
  int b = blockIdx.y;
  int w0 = blockIdx.x * 8;
  int tid = threadIdx.x;
  if (tid < 8) {
    int g = tid;
    float S = 0.f, SS = 0.f;
    for (int ch = 0; ch < 256; ch++) {
      S += sums1[(((size_t)b * 8 + g) * 256 + ch) * 2];
      SS += sums1[(((size_t)b * 8 + g) * 256 + ch) * 2 + 1];
    }
    float m = S * (1.0f / 262144.0f);
    float var = SS * (1.0f / 262144.0f) - m * m;
    st[g][0] = m;
    st[g][1] = rsqrtf(var + 1e-5f);
  }
  __syncthreads();
  // stage 16 rows x 10 cols x 32 float4-quads with GN+GELU applied, bf16 into LDS
  for (int i = tid; i < 5120; i += 256) {
    int row = i / 320;
    int rem = i - row * 320;
    int colw = rem >> 5;
    int c4 = (rem & 31) * 4;
    int wc = (w0 + colw - 1 + WRV) & (WRV - 1);
    float4 x4 = *(const float4*)(t1 + ((size_t)b * NPIX + row * WRV + wc) * 128 + c4);
    int g = c4 >> 4;
    float m = st[g][0], is = st[g][1];
    float4 g4 = *(const float4*)(g1 + c4);
    float4 b4 = *(const float4*)(bt1 + c4);
    float y0 = geluf((x4.x - m) * is * g4.x + b4.x);
    float y1 = geluf((x4.y - m) * is * g4.y + b4.y);
    float y2 = geluf((x4.z - m) * is * g4.z + b4.z);
    float y3 = geluf((x4.w - m) * is * g4.w + b4.w);
    uint2 o;
    o.x = (unsigned int)f2bf(y0) | ((unsigned int)f2bf(y1) << 16);
    o.y = (unsigned int)f2bf(y2) | ((unsigned int)f2bf(y3) << 16);
    *(uint2*)((char*)tile + cswz2(row, colw, c4)) = o;
  }
  __syncthreads();
  int wave = tid >> 6, l = tid & 63;
  int lr = l & 15, lk = l >> 4;
  f32x4 acc[2][4];
#pragma unroll
  for (int cc2 = 0; cc2 < 2; cc2++)
#pragma unroll
    for (int nt = 0; nt < 4; nt++) acc[cc2][nt] = (f32x4){0.f, 0.f, 0.f, 0.f};
#pragma unroll
  for (int kpos = 0; kpos < 9; kpos++) {
    int ky = kpos / 3, kx = kpos - ky * 3;
    int arow = (lr + ky - 1 + 16) & 15;
#pragma unroll
    for (int cc2 = 0; cc2 < 2; cc2++) {
      int acol = wave * 2 + cc2 + kx;
#pragma unroll
      for (int ks = 0; ks < 4; ks++) {
        short8 a = *(const short8*)((const char*)tile + cswz2(arow, acol, ks * 32 + lk * 8));
#pragma unroll
        for (int nt = 0; nt < 4; nt++) {
          short8 bv = *(const short8*)(w2p + (size_t)(kpos * 64 + nt * 16 + lr) * 128 +
                                       ks * 32 + lk * 8);
          acc[cc2][nt] = __builtin_amdgcn_mfma_f32_16x16x32_bf16(a, bv, acc[cc2][nt], 0, 0, 0);
        }
      }
    }
  }
#pragma unroll
  for (int cc2 = 0; cc2 < 2; cc2++) {
    int cc = wave * 2 + cc2;
#pragma unroll
    for (int nt = 0; nt < 4; nt++) {
      int o = nt * 16 + lr;
#pragma unroll
      for (int r = 0; r < 4; r++) {
        int p = (lk * 4 + r) * WRV + w0 + cc;
        t2[((size_t)b * NPIX + p) * 64 + o] = acc[cc2][nt][r];
      }
    }
  }
  // fused gnsum2 partial: group g = nt*2 + (lr>>3)
  float ps[4], pss[4];
#pragma unroll
  for (int nt = 0; nt < 4; nt++) { ps[nt] = 0.f; pss[nt] = 0.f; }
#pragma unroll
  for (int cc2 = 0; cc2 < 2; cc2++)
#pragma unroll
    for (int nt = 0; nt < 4; nt++)
#pragma unroll
      for (int r = 0; r < 4; r++) {
        float v = acc[cc2][nt][r];
        ps[nt] += v;
        pss[nt] += v * v;
      }
#pragma unroll
  for (int nt = 0; nt < 4; nt++) {
    ps[nt] += __shfl_xor(ps[nt], 1);  pss[nt] += __shfl_xor(pss[nt], 1);
    ps[nt] += __shfl_xor(ps[nt], 2);  pss[nt] += __shfl_xor(pss[nt], 2);
    ps[nt] += __shfl_xor(ps[nt], 4);  pss[nt] += __shfl_xor(pss[nt], 4);
    ps[nt] += __shfl_xor(ps[nt], 16); pss[nt] += __shfl_xor(pss[nt], 16);
    ps[nt] += __shfl_xor(ps[nt], 32); pss[nt] += __shfl_xor(pss[nt], 32);
  }
  if ((l & 0x37) == 0) {  // lanes 0 and 8 only
    int b3 = (l >> 3) & 1;
#pragma unroll
    for (int nt = 0; nt < 4; nt++) {
      wred[wave][b3][nt][0] = ps[nt];
      wred[wave][b3][nt][1] = pss[nt];
    }
  }
  __syncthreads();
  if (tid < 8) {
    int nt = tid >> 1, b3 = tid & 1;
    float S = 0.f, SS = 0.f;
    for (int wv = 0; wv < 4; wv++) { S += wred[wv][b3][nt][0]; SS += wred[wv][b3][nt][1]; }
    int g = nt * 2 + b3;
    sums2[(((size_t)b * 8 + g) * 128 + blockIdx.x) * 2 + 0] = S;
    sums2[(((size_t)b * 8 + g) * 128 + blockIdx.x) * 2 + 1] = SS;
  }
}

// ---------------- K3: fused head (GN2+GELU+trig) + query MLP ----------------
__global__ __launch_bounds__(256) void k_headquery(
    const float* __restrict__ t2, const float* __restrict__ sums2,
    const float* __restrict__ g2, const float* __restrict__ bt2,
    const float* __restrict__ rh_w3, const float* __restrict__ rh_b3,
    const float* __restrict__ l2e, const unsigned short* __restrict__ q0,
    const unsigned short* __restrict__ qsW1p, const float* __restrict__ qs_b1,
    const float* __restrict__ qs_w1f,
    const unsigned short* __restrict__ qsW2p, const float* __restrict__ qs_b2,
    float* __restrict__ params, float* __restrict__ klpart,
    unsigned short* __restrict__ query, RVConsts C) {
  __shared__ float st2[8][2];
  __shared__ unsigned short qin[64][136];
  __shared__ unsigned short hq[64][136];
  __shared__ float sigf[64][6];
  __shared__ float klred[64];
  int b = blockIdx.y;
  int n0 = blockIdx.x * 64;
  int tid = threadIdx.x;
  if (tid < 8) {
    int g = tid;
    float S = 0.f, SS = 0.f;
    for (int ch = 0; ch < 128; ch++) {
      S += sums2[(((size_t)b * 8 + g) * 128 + ch) * 2];
      SS += sums2[(((size_t)b * 8 + g) * 128 + ch) * 2 + 1];
    }
    float m = S * (1.0f / 131072.0f);
    float var = SS * (1.0f / 131072.0f) - m * m;
    st2[g][0] = m;
    st2[g][1] = rsqrtf(var + 1e-5f);
  }
  const unsigned short* src = q0 + ((size_t)b * NPIX + n0) * 128;
  for (int i = tid; i < 1024; i += 256) {
    int p = i >> 4, c0 = (i & 15) * 8;
    *(uint4*)&qin[p][c0] = *(const uint4*)(src + p * 128 + c0);
  }
  __syncthreads();
  {  // head: 4 lanes per pixel split over channels
    int px = tid >> 2, q = tid & 3;
    int n = n0 + px;
    int h = n >> 10, w = n & 1023;
    const float* t = t2 + ((size_t)b * NPIX + n) * 64 + q * 16;
    float hd0 = 0.f, hd1 = 0.f, hd2 = 0.f, hd3 = 0.f;
#pragma unroll
    for (int j = 0; j < 16; j++) {
      int c = q * 16 + j;
      int g = c >> 3;
      float xv = geluf((t[j] - st2[g][0]) * st2[g][1] * g2[c] + bt2[c]);
      hd0 += rh_w3[c] * xv;
      hd1 += rh_w3[64 + c] * xv;
      hd2 += rh_w3[128 + c] * xv;
      hd3 += rh_w3[192 + c] * xv;
    }
    hd0 += __shfl_xor(hd0, 1); hd1 += __shfl_xor(hd1, 1);
    hd2 += __shfl_xor(hd2, 1); hd3 += __shfl_xor(hd3, 1);
    hd0 += __shfl_xor(hd0, 2); hd1 += __shfl_xor(hd1, 2);
    hd2 += __shfl_xor(hd2, 2); hd3 += __shfl_xor(hd3, 2);
    if (q == 0) {
      hd0 += rh_b3[0]; hd1 += rh_b3[1]; hd2 += rh_b3[2]; hd3 += rh_b3[3];
      float mu = sigmoidf_(hd0) * 55.0f;
      float sd = softplusf_(hd1) + 1e-3f;
      float stepw = C.steps[w & 15];
      float se = sigmoidf_(hd2) * stepw + 1e-3f;
      float sa = sigmoidf_(hd3) * C.az_step_f + 1e-3f;
      float E0 = C.means[h];
      float A0 = azimf(w, C.step_d, C.az0, C.az_half);
      float* P = params + ((size_t)b * NPIX + n) * 16;
      P[0] = sd; P[1] = se; P[2] = sa;
      sigf[px][0] = sd; sigf[px][1] = se; sigf[px][2] = sa;
      sigf[px][3] = 1.0f / (sd + 1e-6f);
      sigf[px][4] = 1.0f / (se + 1e-6f);
      sigf[px][5] = 1.0f / (sa + 1e-6f);
      float M00 = l2e[0], M01 = l2e[1], M10 = l2e[4], M11 = l2e[5];
      float M20 = l2e[8], M21 = l2e[9], M30 = l2e[12], M31 = l2e[13];
#pragma unroll
      for (int k = 0; k < 5; k++) {
        float off = -0.6f + 0.3f * (float)k;
        float d = mu + sd * off;
        float E = E0 + se * off;
        float A = A0 + sa * off;
        float ce = cosf(E);
        float xl = d * ce * cosf(A), yl = d * ce * sinf(A), zl = d * sinf(E);
        float px_ = xl * M00 + yl * M10 + zl * M20 + M30;
        float py_ = xl * M01 + yl * M11 + zl * M21 + M31;
        P[3 + 2 * k] = sigmoidf_(4.0f * ((px_ + 55.0f) * (1.0f / 110.0f) - 0.5f));
        P[4 + 2 * k] = sigmoidf_(4.0f * ((py_ + 55.0f) * (1.0f / 110.0f) - 0.5f));
      }
      float mu_n = mu * (1.0f / 55.0f);
      float sr = fmaxf(sd, 1e-6f);
      float saz = sa / C.az_step_f;
      float sel = se / stepw;
      klred[px] = 0.5f * (mu_n * mu_n + sr * sr - logf(sr * sr) - 1.0f) +
                  0.5f * (saz * saz - logf(saz * saz) - 1.0f) +
                  0.5f * (sel * sel - logf(sel * sel) - 1.0f);
    }
  }
  __syncthreads();
  if (tid == 0) {
    float sL = 0.f;
    for (int i = 0; i < 64; i++) sL += klred[i];
    klpart[b * 256 + blockIdx.x] = sL;
  }
  // query MLP
  int wave = tid >> 6, l = tid & 63;
  int lr = l & 15, lk = l >> 4;
  f32x4 acc[8];
#pragma unroll
  for (int nt = 0; nt < 8; nt++) {
    int n = nt * 16 + lr;
    float wt[6];
#pragma unroll
    for (int c = 0; c < 6; c++) wt[c] = qs_w1f[(size_t)n * 134 + 128 + c];
    float bias = qs_b1[n];
#pragma unroll
    for (int r = 0; r < 4; r++) {
      int pl = wave * 16 + lk * 4 + r;
      float a = bias;
#pragma unroll
      for (int c = 0; c < 6; c++) a += wt[c] * sigf[pl][c];
      acc[nt][r] = a;
    }
  }
#pragma unroll
  for (int ks = 0; ks < 4; ks++) {
    short8 a = *(const short8*)&qin[wave * 16 + lr][ks * 32 + lk * 8];
#pragma unroll
    for (int nt = 0; nt < 8; nt++) {
      short8 bv = *(const short8*)(qsW1p + (size_t)(nt * 16 + lr) * 128 + ks * 32 + lk * 8);
      acc[nt] = __builtin_amdgcn_mfma_f32_16x16x32_bf16(a, bv, acc[nt], 0, 0, 0);
    }
  }
#pragma unroll
  for (int nt = 0; nt < 8; nt++)
#pragma unroll
    for (int r = 0; r < 4; r++)
      hq[wave * 16 + lk * 4 + r][nt * 16 + lr] = f2bf(geluf(acc[nt][r]));
  __syncthreads();
#pragma unroll
  for (int nt = 0; nt < 8; nt++) {
    float bias = qs_b2[nt * 16 + lr];
    acc[nt] = (f32x4){bias, bias, bias, bias};
  }
#pragma unroll
  for (int ks = 0; ks < 4; ks++) {
    short8 a = *(const short8*)&hq[wave * 16 + lr][ks * 32 + lk * 8];
#pragma unroll
    for (int nt = 0; nt < 8; nt++) {
      short8 bv = *(const short8*)(qsW2p + (size_t)(nt * 16 + lr) * 128 + ks * 32 + lk * 8);
      acc[nt] = __builtin_amdgcn_mfma_f32_16x16x32_bf16(a, bv, acc[nt], 0, 0, 0);
    }
  }
#pragma unroll
  for (int nt = 0; nt < 8; nt++) {
    int n = nt * 16 + lr;
#pragma unroll
    for (int r = 0; r < 4; r++) {
      int p = n0 + wave * 16 + lk * 4 + r;
      query[((size_t)b * NPIX + p) * 128 + n] = f2bf(acc[nt][r]);
    }
  }
}

// ---------------- K4: pack weights to bf16 ----------------
__global__ __launch_bounds__(256) void k_pack(
    const float* __restrict__ val_w, const float* __restrict__ w_v,
    const float* __restrict__ b_v, const float* __restrict__ val_b,
    const float* __restrict__ off_w, const float* __restrict__ off_b,
    const float* __restrict__ aw_w, const float* __restrict__ aw_b,
    const float* __restrict__ out_w, const float* __restrict__ qs_w1,
    const float* __restrict__ qs_w2, const float* __restrict__ rh_w1,
    const float* __restrict__ w_q, const float* __restrict__ w_o,
    const float* __restrict__ rh_w2,
    unsigned short* __restrict__ wvv_bf, float* __restrict__ bvv,
    unsigned short* __restrict__ projW, float* __restrict__ projB,
    unsigned short* __restrict__ outW, unsigned short* __restrict__ qsW1p,
    unsigned short* __restrict__ qsW2p, unsigned short* __restrict__ rhW1p,
    unsigned short* __restrict__ wqp, unsigned short* __restrict__ woP,
    unsigned short* __restrict__ w2p) {
  int idx = blockIdx.x * 256 + threadIdx.x;
  if (idx < 16384) {
    int o = idx >> 7, c = idx & 127;
    float acc = 0.0f;
    for (int m = 0; m < 128; m++) acc += val_w[o * 128 + m] * w_v[m * 128 + c];
    wvv_bf[idx] = f2bf(acc);
  } else if (idx < 16512) {
    int o = idx - 16384;
    float acc = val_b[o];
    for (int m = 0; m < 128; m++) acc += val_w[o * 128 + m] * b_v[m];
    bvv[o] = acc;
  } else if (idx < 82048) {
    int j = idx - 16512;
    int r = j >> 7, c = j & 127;
    float w = (r < 320) ? off_w[r * 128 + c] : ((r < 480) ? aw_w[(r - 320) * 128 + c] : 0.0f);
    projW[j] = f2bf(w);
  } else if (idx < 82560) {
    int r = idx - 82048;
    projB[r] = (r < 320) ? off_b[r] : ((r < 480) ? aw_b[r - 320] : 0.0f);
  } else if (idx < 98944) {
    int j = idx - 82560;
    outW[j] = f2bf(out_w[j]);
  } else if (idx < 115328) {
    int j = idx - 98944;
    int r = j >> 7, c = j & 127;
    qsW1p[j] = f2bf(qs_w1[r * 134 + c]);
  } else if (idx < 131712) {
    int j = idx - 115328;
    qsW2p[j] = f2bf(qs_w2[j]);
  } else if (idx < 144000) {
    int j = idx - 131712;
    int r = j / 96, c = j - r * 96;
    rhW1p[j] = (c < 67) ? f2bf(rh_w1[r * 67 + c]) : 0;
  } else if (idx < 156288) {
    int j = idx - 144000;
    int r = j / 96, c = j - r * 96;
    wqp[j] = (c < 64) ? f2bf(w_q[r * 64 + c]) : 0;
  } else if (idx < 172672) {
    int j = idx - 156288;
    woP[j] = f2bf(w_o[j]);
  } else if (idx < 246400) {
    int j = idx - 172672;          // [kpos][o][c]
    int kpos = j >> 13;
    int rem = j & 8191;
    int o = rem >> 7, c = rem & 127;
    int ky = kpos / 3, kx = kpos - ky * 3;
    w2p[j] = f2bf(rh_w2[((size_t)(o * 128 + c) * 3 + ky) * 3 + kx]);
  }
}

// ---------------- K5: MFMA value projection -> bf16 v ----------------
__global__ __launch_bounds__(256) void k_value(
    const float* __restrict__ bev, const unsigned short* __restrict__ wvv_bf,
    const float* __restrict__ bvv, unsigned short* __restrict__ v) {
  __shared__ float lds[128 * 66];
  int b = blockIdx.y;
  int p0 = blockIdx.x * 64;
  int tid = threadIdx.x;
  int npx = NBEV - p0; if (npx > 64) npx = 64;
  for (int i = tid; i < 128 * 64; i += 256) {
    int c = i >> 6, p = i & 63;
    lds[c * 66 + p] = (p < npx) ? bev[((size_t)b * 128 + c) * NBEV + p0 + p] : 0.0f;
  }
  __syncthreads();
  int wave = tid >> 6, l = tid & 63;
  int lr = l & 15, lk = l >> 4;
  int ploc = wave * 16 + lr;
  f32x4 acc[8];
#pragma unroll
  for (int nt = 0; nt < 8; nt++) {
    float bias = bvv[nt * 16 + lr];
    acc[nt] = (f32x4){bias, bias, bias, bias};
  }
#pragma unroll
  for (int ks = 0; ks < 4; ks++) {
    int k0 = ks * 32 + lk * 8;
    short8 a;
#pragma unroll
    for (int j = 0; j < 8; j++) a[j] = (short)f2bf(lds[(k0 + j) * 66 + ploc]);
#pragma unroll
    for (int nt = 0; nt < 8; nt++) {
      short8 bf = *(const short8*)(wvv_bf + (size_t)(nt * 16 + lr) * 128 + k0);
      acc[nt] = __builtin_amdgcn_mfma_f32_16x16x32_bf16(a, bf, acc[nt], 0, 0, 0);
    }
  }
#pragma unroll
  for (int nt = 0; nt < 8; nt++) {
    int n = nt * 16 + lr;
#pragma unroll
    for (int r = 0; r < 4; r++) {
      int p = p0 + wave * 16 + lk * 4 + r;
      if (p < NBEV) v[((size_t)b * NBEV + p) * 128 + n] = f2bf(acc[nt][r]);
    }
  }
}

// ---------------- K6: MFMA projection, query LDS-staged once, 4 n-chunks ----------------
__global__ __launch_bounds__(256) void k_proj(
    const unsigned short* __restrict__ query, const unsigned short* __restrict__ projW,
    const float* __restrict__ projB, unsigned short* __restrict__ proj) {
  __shared__ unsigned short qlds[64][136];
  int b = blockIdx.y;
  int p0b = blockIdx.x * 64;
  int tid = threadIdx.x;
  const unsigned short* src = query + ((size_t)b * NPIX + p0b) * 128;
  for (int i = tid; i < 1024; i += 256) {
    int p = i >> 4, c0 = (i & 15) * 8;
    *(uint4*)&qlds[p][c0] = *(const uint4*)(src + p * 128 + c0);
  }
  __syncthreads();
  int wave = tid >> 6, l = tid & 63;
  int lr = l & 15, lk = l >> 4;
  int p0 = p0b + wave * 16;
  for (int nc = 0; nc < 4; nc++) {
    int n0 = nc * 128;
    f32x4 acc[8];
#pragma unroll
    for (int nt = 0; nt < 8; nt++) {
      float bias = projB[n0 + nt * 16 + lr];
      acc[nt] = (f32x4){bias, bias, bias, bias};
    }
#pragma unroll
    for (int ks = 0; ks < 4; ks++) {
      short8 a = *(const short8*)&qlds[wave * 16 + lr][ks * 32 + lk * 8];
#pragma unroll
      for (int nt = 0; nt < 8; nt++) {
        short8 bf = *(const short8*)(projW + (size_t)(n0 + nt * 16 + lr) * 128 +
                                     ks * 32 + lk * 8);
        acc[nt] = __builtin_amdgcn_mfma_f32_16x16x32_bf16(a, bf, acc[nt], 0, 0, 0);
      }
    }
#pragma unroll
    for (int nt = 0; nt < 8; nt++) {
      int n = n0 + nt * 16 + lr;
#pragma unroll
      for (int r = 0; r < 4; r++) {
        int p = p0 + lk * 4 + r;
        proj[((size_t)b * NPIX + p) * 512 + n] = f2bf(acc[nt][r]);
      }
    }
  }
}

// ---------------- K7: sampler — 4 lanes per (pixel,head), tap-split + shfl softmax ----------------
__global__ __launch_bounds__(256) void k_samp(
    const unsigned short* __restrict__ proj, const float* __restrict__ params,
    const unsigned short* __restrict__ v, unsigned short* __restrict__ S) {
  int b = blockIdx.y;
  int bid = blockIdx.x;
  int pb = (bid & 7) * 256 + (bid >> 3);
  int tid = threadIdx.x;
  int q = tid & 3, hh = (tid >> 2) & 7, pl = tid >> 5;
  int n = pb * 8 + pl;
  const unsigned short* base = proj + ((size_t)b * NPIX + n) * 512;
  float lg[5];
#pragma unroll
  for (int t = 0; t < 5; t++) lg[t] = bf2f(base[320 + hh * 20 + q * 5 + t]);
  float mx = fmaxf(fmaxf(fmaxf(lg[0], lg[1]), fmaxf(lg[2], lg[3])), lg[4]);
  mx = fmaxf(mx, __shfl_xor(mx, 1));
  mx = fmaxf(mx, __shfl_xor(mx, 2));
  float e[5];
  float s = 0.0f;
#pragma unroll
  for (int t = 0; t < 5; t++) { e[t] = expf(lg[t] - mx); s += e[t]; }
  s += __shfl_xor(s, 1);
  s += __shfl_xor(s, 2);
  float rs = 1.0f / s;
  const float* P = params + ((size_t)b * NPIX + n) * 16;
  const unsigned short* vb = v + (size_t)b * NBEV * 128 + hh * 16;
  float acc[16];
#pragma unroll
  for (int c = 0; c < 16; c++) acc[c] = 0.0f;
#pragma unroll
  for (int t = 0; t < 5; t++) {
    int kp = q * 5 + t;
    int k = kp >> 2;
    unsigned int u = *(const unsigned int*)(base + hh * 40 + kp * 2);
    float X = P[3 + 2 * k] * 220.0f - 0.5f + bf2f((unsigned short)(u & 0xffffu));
    float Y = P[4 + 2 * k] * 220.0f - 0.5f + bf2f((unsigned short)(u >> 16));
    float xf = floorf(X), yf = floorf(Y);
    float wx = X - xf, wy = Y - yf;
    int x0 = (int)xf, y0 = (int)yf;
    float wx0 = ((unsigned)x0 < 220u) ? (1.0f - wx) : 0.0f;
    float wx1 = ((unsigned)(x0 + 1) < 220u) ? wx : 0.0f;
    float wy0 = ((unsigned)y0 < 220u) ? (1.0f - wy) : 0.0f;
    float wy1 = ((unsigned)(y0 + 1) < 220u) ? wy : 0.0f;
    int cx0 = min(max(x0, 0), 219), cx1 = min(max(x0 + 1, 0), 219);
    int cy0 = min(max(y0, 0), 219) * 220, cy1 = min(max(y0 + 1, 0), 219) * 220;
    float a = e[t] * rs;
    float u0 = a * wy0, u1 = a * wy1;
    float w4[4] = {u0 * wx0, u0 * wx1, u1 * wx0, u1 * wx1};
    int i4[4] = {cy0 + cx0, cy0 + cx1, cy1 + cx0, cy1 + cx1};
#pragma unroll
    for (int c2 = 0; c2 < 4; c2++) {
      float w = w4[c2];
      const uint4* sp = (const uint4*)(vb + (size_t)i4[c2] * 128);
      uint4 r0 = sp[0], r1 = sp[1];
      acc[0] += w * bf2f((unsigned short)(r0.x & 0xffffu));
      acc[1] += w * bf2f((unsigned short)(r0.x >> 16));
      acc[2] += w * bf2f((unsigned short)(r0.y & 0xffffu));
      acc[3] += w * bf2f((unsigned short)(r0.y >> 16));
      acc[4] += w * bf2f((unsigned short)(r0.z & 0xffffu));
      acc[5] += w * bf2f((unsigned short)(r0.z >> 16));
      acc[6] += w * bf2f((unsigned short)(r0.w & 0xffffu));
      acc[7] += w * bf2f((unsigned short)(r0.w >> 16));
      acc[8] += w * bf2f((unsigned short)(r1.x & 0xffffu));
      acc[9] += w * bf2f((unsigned short)(r1.x >> 16));
      acc[10] += w * bf2f((unsigned short)(r1.y & 0xffffu));
      acc[11] += w * bf2f((unsigned short)(r1.y >> 16));
      acc[12] += w * bf2f((unsigned short)(r1.z & 0xffffu));
      acc[13] += w * bf2f((unsigned short)(r1.z >> 16));
      acc[14] += w * bf2f((unsigned short)(r1.w & 0xffffu));
      acc[15] += w * bf2f((unsigned short)(r1.w >> 16));
    }
  }
#pragma unroll
  for (int c = 0; c < 16; c++) {
    acc[c] += __shfl_xor(acc[c], 1);
    acc[c] += __shfl_xor(acc[c], 2);
  }
  if (q == 0) {
    uint4 o1, o2;
    o1.x = (unsigned int)f2bf(acc[0]) | ((unsigned int)f2bf(acc[1]) << 16);
    o1.y = (unsigned int)f2bf(acc[2]) | ((unsigned int)f2bf(acc[3]) << 16);
    o1.z = (unsigned int)f2bf(acc[4]) | ((unsigned int)f2bf(acc[5]) << 16);
    o1.w = (unsigned int)f2bf(acc[6]) | ((unsigned int)f2bf(acc[7]) << 16);
    o2.x = (unsigned int)f2bf(acc[8]) | ((unsigned int)f2bf(acc[9]) << 16);
    o2.y = (unsigned int)f2bf(acc[10]) | ((unsigned int)f2bf(acc[11]) << 16);
    o2.z = (unsigned int)f2bf(acc[12]) | ((unsigned int)f2bf(acc[13]) << 16);
    o2.w = (unsigned int)f2bf(acc[14]) | ((unsigned int)f2bf(acc[15]) << 16);
    unsigned short* dst = S + ((size_t)b * NPIX + n) * 128 + hh * 16;
    *(uint4*)dst = o1;
    *(uint4*)(dst + 8) = o2;
  }
}

// ---------------- K8: fused out-proj + residual + final conv1x1 + NCHW store + KL ----------------
__global__ __launch_bounds__(256) void k_outfinal(
    const unsigned short* __restrict__ S, const unsigned short* __restrict__ outW,
    const float* __restrict__ out_b, const unsigned short* __restrict__ query,
    const unsigned short* __restrict__ woP, const float* __restrict__ b_o,
    const float* __restrict__ klpart, float* __restrict__ out) {
  __shared__ unsigned short ylds[64][136];
  __shared__ float yt[128][67];
  int b = blockIdx.y;
  int p0b = blockIdx.x * 64;
  int tid = threadIdx.x;
  int wave = tid >> 6, l = tid & 63;
  int lr = l & 15, lk = l >> 4;
  {
    f32x4 acc[8];
#pragma unroll
    for (int nt = 0; nt < 8; nt++) {
      float bias = out_b[nt * 16 + lr];
      acc[nt] = (f32x4){bias, bias, bias, bias};
    }
    const unsigned short* ap = S + ((size_t)b * NPIX + p0b + wave * 16 + lr) * 128 + lk * 8;
#pragma unroll
    for (int ks = 0; ks < 4; ks++) {
      short8 a = *(const short8*)(ap + ks * 32);
#pragma unroll
      for (int nt = 0; nt < 8; nt++) {
        short8 bf = *(const short8*)(outW + (size_t)(nt * 16 + lr) * 128 + ks * 32 + lk * 8);
        acc[nt] = __builtin_amdgcn_mfma_f32_16x16x32_bf16(a, bf, acc[nt], 0, 0, 0);
      }
    }
#pragma unroll
    for (int nt = 0; nt < 8; nt++) {
      int n = nt * 16 + lr;
#pragma unroll
      for (int r = 0; r < 4; r++) {
        int p_local = wave * 16 + lk * 4 + r;
        size_t o = ((size_t)b * NPIX + p0b + p_local) * 128 + n;
        ylds[p_local][n] = f2bf(acc[nt][r] + bf2f(query[o]));
      }
    }
  }
  __syncthreads();
  {
    f32x4 acc[8];
#pragma unroll
    for (int nt = 0; nt < 8; nt++) {
      float bias = b_o[nt * 16 + lr];
      acc[nt] = (f32x4){bias, bias, bias, bias};
    }
#pragma unroll
    for (int ks = 0; ks < 4; ks++) {
      short8 a = *(const short8*)&ylds[wave * 16 + lr][ks * 32 + lk * 8];
#pragma unroll
      for (int nt = 0; nt < 8; nt++) {
        short8 bf = *(const short8*)(woP + (size_t)(nt * 16 + lr) * 128 + ks * 32 + lk * 8);
        acc[nt] = __builtin_amdgcn_mfma_f32_16x16x32_bf16(a, bf, acc[nt], 0, 0, 0);
      }
    }
#pragma unroll
    for (int nt = 0; nt < 8; nt++)
#pragma unroll
      for (int r = 0; r < 4; r++)
        yt[nt * 16 + lr][wave * 16 + lk * 4 + r] = acc[nt][r];
  }
  __syncthreads();
  int n = tid >> 1, half = tid & 1;
  float* dst = out + ((size_t)(b * 128 + n)) * NPIX + p0b + half * 32;
#pragma unroll
  for (int j = 0; j < 8; j++) {
    float4 v4 = {yt[n][half * 32 + j * 4], yt[n][half * 32 + j * 4 + 1],
                 yt[n][half * 32 + j * 4 + 2], yt[n][half * 32 + j * 4 + 3]};
    *(float4*)(dst + j * 4) = v4;
  }
  if (blockIdx.x == 0 && b == 0 && tid == 0) {
    float sL = 0.0f;
    for (int i = 0; i < 512; i++) sL += klpart[i];
    out[(size_t)BSZ * 128 * NPIX] = 1e-4f * (sL / 32768.0f);
  }
}

// ---------------- host ----------------
static RVConsts make_consts() {
  static const float ELEV[32] = {
      -30.67f, -29.33f, -28.0f, -26.66f, -25.33f, -24.0f, -22.67f, -21.33f,
      -20.0f,  -18.67f, -17.33f, -16.0f, -14.67f, -13.33f, -12.0f, -10.67f,
      -9.33f,  -8.0f,   -6.66f,  -5.33f, -4.0f,   -2.67f,  -1.33f, 0.0f,
      1.33f,   2.67f,   4.0f,    5.33f,  6.67f,   8.0f,    9.33f,  10.67f};
  RVConsts C;
  const float d2r = 0.017453292519943295f;
  for (int r = 0; r < 16; r++) {
    float a = ELEV[31 - 2 * r], b = ELEV[30 - 2 * r];
    float mx = fmaxf(a, b), mn = fminf(a, b);
    C.steps[r] = (mx - mn) * d2r;
    C.means[r] = ((a + b) * 0.5f) * d2r;
  }
  const double PI_D = 3.14159265358979323846;
  double step_d = (PI_D - (-PI_D)) / 1024.0;
  double az0 = -PI_D;
  double az1 = az0 + step_d;
  double az_step_d = az1 - az0;
  C.az_step_f = (float)az_step_d;
  C.pad_ = 0.0f;
  C.step_d = step_d;
  C.az0 = az0;
  C.az_half = az_step_d * 0.5;
  return C;
}

// Workspace layout (f32 words). Peak 21,632,128 words = 86.5 MB (< proven 94.4 MB).
#define OFF_T1     0u          /* f32 4,194,304 ; overlaid by proj after conv3g */
#define OFF_T2     8388608u    /* f32 2,097,152 ; overlaid by v after headquery */
#define OFF_Q0     10485760u   /* bf16 -> 2,097,152 w ; overlaid by v after headquery */
#define OFF_PARAMS 14680064u   /* f32 524,288 */
#define OFF_QUERY  15204352u   /* bf16 -> 2,097,152 w */
#define OFF_S      19398656u   /* bf16 -> 2,097,152 w */
#define OFF_SUMS1  21495808u   /* 8192 */
#define OFF_SUMS2  21504000u   /* 4096 */
#define OFF_KL     21508096u   /* 512 */
#define OFF_PROJ   0u          /* bf16 x 16,777,216 = 8,388,608 w */
#define OFF_V      8388608u    /* bf16 x 12,390,400 = 6,195,200 w */
#define OFF_WVV    21508608u
#define OFF_BVV    21516800u
#define OFF_PROJW  21516928u
#define OFF_PROJB  21549696u
#define OFF_OUTW   21550208u
#define OFF_QSW1   21558400u
#define OFF_QSW2   21566592u
#define OFF_RHW1   21574784u
#define OFF_WQP    21580928u
#define OFF_WOP    21587072u
#define OFF_W2P    21595264u   /* end 21,632,128 w */

extern "C" void kernel_launch(void* const* d_in, const int* in_sizes, int n_in,
                              void* d_out, int out_size, void* d_ws, size_t ws_size,
                              hipStream_t stream) {
  const float* x_rv = (const float*)d_in[0];
  const float* bev = (const float*)d_in[1];
  const float* l2e = (const float*)d_in[2];
  const float* w_q = (const float*)d_in[3];
  const float* b_q = (const float*)d_in[4];
  const float* w_v = (const float*)d_in[5];
  const float* b_v = (const float*)d_in[6];
  const float* w_o = (const float*)d_in[7];
  const float* b_o = (const float*)d_in[8];
  const float* qs_w1 = (const float*)d_in[9];
  const float* qs_b1 = (const float*)d_in[10];
  const float* qs_w2 = (const float*)d_in[11];
  const float* qs_b2 = (const float*)d_in[12];
  const float* rh_w1 = (const float*)d_in[13];
  const float* rh_b1 = (const float*)d_in[14];
  const float* rh_g1 = (const float*)d_in[15];
  const float* rh_bt1 = (const float*)d_in[16];
  const float* rh_w2 = (const float*)d_in[17];
  const float* rh_g2 = (const float*)d_in[18];
  const float* rh_bt2 = (const float*)d_in[19];
  const float* rh_w3 = (const float*)d_in[20];
  const float* rh_b3 = (const float*)d_in[21];
  const float* off_w = (const float*)d_in[22];
  const float* off_b = (const float*)d_in[23];
  const float* aw_w = (const float*)d_in[24];
  const float* aw_b = (const float*)d_in[25];
  const float* val_w = (const float*)d_in[26];
  const float* val_b = (const float*)d_in[27];
  const float* out_w = (const float*)d_in[28];
  const float* out_b = (const float*)d_in[29];

  float* ws = (float*)d_ws;
  float* t1 = ws + OFF_T1;
  float* t2 = ws + OFF_T2;
  float* params = ws + OFF_PARAMS;
  float* sums1 = ws + OFF_SUMS1;
  float* sums2 = ws + OFF_SUMS2;
  float* klpart = ws + OFF_KL;
  float* bvv = ws + OFF_BVV;
  float* projB = ws + OFF_PROJB;
  unsigned short* q0bf = (unsigned short*)(ws + OFF_Q0);
  unsigned short* querybf = (unsigned short*)(ws + OFF_QUERY);
  unsigned short* S_bf = (unsigned short*)(ws + OFF_S);
  unsigned short* proj_bf = (unsigned short*)(ws + OFF_PROJ);
  unsigned short* v_bf = (unsigned short*)(ws + OFF_V);
  unsigned short* wvv_bf = (unsigned short*)(ws + OFF_WVV);
  unsigned short* projW = (unsigned short*)(ws + OFF_PROJW);
  unsigned short* outW = (unsigned short*)(ws + OFF_OUTW);
  unsigned short* qsW1p = (unsigned short*)(ws + OFF_QSW1);
  unsigned short* qsW2p = (unsigned short*)(ws + OFF_QSW2);
  unsigned short* rhW1p = (unsigned short*)(ws + OFF_RHW1);
  unsigned short* wqp = (unsigned short*)(ws + OFF_WQP);
  unsigned short* woP = (unsigned short*)(ws + OFF_WOP);
  unsigned short* w2p = (unsigned short*)(ws + OFF_W2P);

  RVConsts C = make_consts();
  dim3 blk(256);

  k_pack<<<963, blk, 0, stream>>>(val_w, w_v, b_v, val_b, off_w, off_b, aw_w, aw_b, out_w,
                                  qs_w1, qs_w2, rh_w1, w_q, w_o, rh_w2,
                                  wvv_bf, bvv, projW, projB, outW, qsW1p, qsW2p, rhW1p,
                                  wqp, woP, w2p);
  k_rh1_q0<<<dim3(256, BSZ), blk, 0, stream>>>(x_rv, rhW1p, rh_b1, wqp, b_q, t1, q0bf,
                                               sums1, C);
  k_conv3g<<<dim3(128, BSZ), blk, 0, stream>>>(t1, sums1, rh_g1, rh_bt1, w2p, t2, sums2);
  k_headquery<<<dim3(256, BSZ), blk, 0, stream>>>(t2, sums2, rh_g2, rh_bt2, rh_w3, rh_b3,
                                                  l2e, q0bf, qsW1p, qs_b1, qs_w1, qsW2p,
                                                  qs_b2, params, klpart, querybf, C);
  k_value<<<dim3(757, BSZ), blk, 0, stream>>>(bev, wvv_bf, bvv, v_bf);
  k_proj<<<dim3(256, BSZ), blk, 0, stream>>>(querybf, projW, projB, proj_bf);
  k_samp<<<dim3(2048, BSZ), blk, 0, stream>>>(proj_bf, params, v_bf, S_bf);
  k_outfinal<<<dim3(256, BSZ), blk, 0, stream>>>(S_bf, outW, out_b, querybf, woP, b_o,
                                                 klpart, (float*)d_out);
}

// Round 10
// 277.029 us; speedup vs baseline: 2.2538x; 1.0619x over previous
//
#include <hip/hip_runtime.h>
#include <math.h>

#define HRV 16
#define WRV 1024
#define NPIX 16384
#define NBEV 48400
#define BSZ 2

typedef __attribute__((ext_vector_type(8))) short short8;
typedef __attribute__((ext_vector_type(4))) float f32x4;

struct RVConsts {
  float steps[16];
  float means[16];
  float az_step_f;
  float pad_;
  double step_d;
  double az0;
  double az_half;
};

__device__ __forceinline__ float geluf(float x) {
  return 0.5f * x * (1.0f + erff(x * 0.70710678118654752440f));
}
__device__ __forceinline__ float sigmoidf_(float x) {
  return 1.0f / (1.0f + expf(-x));
}
__device__ __forceinline__ float softplusf_(float x) {
  return fmaxf(x, 0.0f) + log1pf(expf(-fabsf(x)));
}
__device__ __forceinline__ float azimf(int w, double step_d, double az0, double az_half) {
  double az = (double)w * step_d + az0;
  az += az_half;
  return (float)az;
}
__device__ __forceinline__ unsigned short f2bf(float f) {
  unsigned int u = __builtin_bit_cast(unsigned int, f);
  u = u + 0x7FFFu + ((u >> 16) & 1u);
  return (unsigned short)(u >> 16);
}
__device__ __forceinline__ float bf2f(unsigned short h) {
  unsigned int u = ((unsigned int)h) << 16;
  return __builtin_bit_cast(float, u);
}

// ---------------- K1: MFMA rh-conv1 + Q0 conv + fused gnsum1 partials ----------------
__global__ __launch_bounds__(256) void k_rh1_q0(
    const float* __restrict__ x_rv,
    const unsigned short* __restrict__ rhW1p, const float* __restrict__ rh_b1,
    const unsigned short* __restrict__ wqp, const float* __restrict__ b_q,
    float* __restrict__ t1, unsigned short* __restrict__ q0,
    float* __restrict__ sums1, RVConsts C) {
  __shared__ unsigned short xin[64][104];
  __shared__ float wred[4][8][2];
  int b = blockIdx.y;
  int n0 = blockIdx.x * 64;
  int tid = threadIdx.x;
  const float* src = x_rv + ((size_t)b * NPIX + n0) * 64;
  for (int i = tid; i < 1024; i += 256) {
    int p = i >> 4, c = (i & 15) * 4;
    float4 v4 = *(const float4*)(src + p * 64 + c);
    xin[p][c] = f2bf(v4.x);
    xin[p][c + 1] = f2bf(v4.y);
    xin[p][c + 2] = f2bf(v4.z);
    xin[p][c + 3] = f2bf(v4.w);
  }
  if (tid < 64) {
    int n = n0 + tid;
    int h = n >> 10, w = n & 1023;
    float E = C.means[h];
    float A = azimf(w, C.step_d, C.az0, C.az_half);
    float ce = cosf(E);
    xin[tid][64] = f2bf(ce * cosf(A));
    xin[tid][65] = f2bf(ce * sinf(A));
    xin[tid][66] = f2bf(sinf(E));
    for (int c = 67; c < 104; c++) xin[tid][c] = 0;
  }
  __syncthreads();
  int wave = tid >> 6, l = tid & 63;
  int lr = l & 15, lk = l >> 4;
  f32x4 acc[8], accq[8];
#pragma unroll
  for (int nt = 0; nt < 8; nt++) {
    float b1 = rh_b1[nt * 16 + lr], b2 = b_q[nt * 16 + lr];
    acc[nt] = (f32x4){b1, b1, b1, b1};
    accq[nt] = (f32x4){b2, b2, b2, b2};
  }
#pragma unroll
  for (int ks = 0; ks < 3; ks++) {
    short8 a = *(const short8*)&xin[wave * 16 + lr][ks * 32 + lk * 8];
#pragma unroll
    for (int nt = 0; nt < 8; nt++) {
      short8 b1v = *(const short8*)(rhW1p + (size_t)(nt * 16 + lr) * 96 + ks * 32 + lk * 8);
      acc[nt] = __builtin_amdgcn_mfma_f32_16x16x32_bf16(a, b1v, acc[nt], 0, 0, 0);
      short8 b2v = *(const short8*)(wqp + (size_t)(nt * 16 + lr) * 96 + ks * 32 + lk * 8);
      accq[nt] = __builtin_amdgcn_mfma_f32_16x16x32_bf16(a, b2v, accq[nt], 0, 0, 0);
    }
  }
#pragma unroll
  for (int nt = 0; nt < 8; nt++) {
    int n = nt * 16 + lr;
#pragma unroll
    for (int r = 0; r < 4; r++) {
      int p = n0 + wave * 16 + lk * 4 + r;
      size_t o = ((size_t)b * NPIX + p) * 128 + n;
      t1[o] = acc[nt][r];
      q0[o] = f2bf(accq[nt][r]);
    }
  }
  float s1[8], ss1[8];
#pragma unroll
  for (int nt = 0; nt < 8; nt++) {
    float a0 = acc[nt][0], a1 = acc[nt][1], a2 = acc[nt][2], a3 = acc[nt][3];
    s1[nt] = a0 + a1 + a2 + a3;
    ss1[nt] = a0 * a0 + a1 * a1 + a2 * a2 + a3 * a3;
  }
#pragma unroll
  for (int nt = 0; nt < 8; nt++) {
    s1[nt] += __shfl_xor(s1[nt], 1);  ss1[nt] += __shfl_xor(ss1[nt], 1);
    s1[nt] += __shfl_xor(s1[nt], 2);  ss1[nt] += __shfl_xor(ss1[nt], 2);
    s1[nt] += __shfl_xor(s1[nt], 4);  ss1[nt] += __shfl_xor(ss1[nt], 4);
    s1[nt] += __shfl_xor(s1[nt], 8);  ss1[nt] += __shfl_xor(ss1[nt], 8);
    s1[nt] += __shfl_xor(s1[nt], 16); ss1[nt] += __shfl_xor(ss1[nt], 16);
    s1[nt] += __shfl_xor(s1[nt], 32); ss1[nt] += __shfl_xor(ss1[nt], 32);
  }
  if (l == 0) {
#pragma unroll
    for (int nt = 0; nt < 8; nt++) { wred[wave][nt][0] = s1[nt]; wred[wave][nt][1] = ss1[nt]; }
  }
  __syncthreads();
  if (tid < 8) {
    float S = wred[0][tid][0] + wred[1][tid][0] + wred[2][tid][0] + wred[3][tid][0];
    float SS = wred[0][tid][1] + wred[1][tid][1] + wred[2][tid][1] + wred[3][tid][1];
    sums1[(((size_t)b * 8 + tid) * 256 + blockIdx.x) * 2 + 0] = S;
    sums1[(((size_t)b * 8 + tid) * 256 + blockIdx.x) * 2 + 1] = SS;
  }
}

// ---------------- K2: MFMA 3x3 circular conv with fused GN1+GELU staging + gnsum2 ----------------
__device__ __forceinline__ int cswz2(int row, int colw, int c) {
  int byte = ((row * 10 + colw) << 8) + (c << 1);
  return byte ^ ((row & 7) << 4);
}
__global__ __launch_bounds__(256) void k_conv3g(
    const float* __restrict__ t1, const float* __restrict__ sums1,
    const float* __restrict__ g1, const float* __restrict__ bt1,
    const unsigned short* __restrict__ w2p,
    float* __restrict__ t2, float* __restrict__ sums2) {
  __shared__ unsigned short tile[16 * 10 * 128];
  __shared__ float st[8][2];
  __shared__ float wred[4][2][4][2];
  int b = blockIdx.y;
  int w0 = blockIdx.x * 8;
  int tid = threadIdx.x;
  if (tid < 8) {
    int g = tid;
    float S = 0.f, SS = 0.f;
    for (int ch = 0; ch < 256; ch++) {
      S += sums1[(((size_t)b * 8 + g) * 256 + ch) * 2];
      SS += sums1[(((size_t)b * 8 + g) * 256 + ch) * 2 + 1];
    }
    float m = S * (1.0f / 262144.0f);
    float var = SS * (1.0f / 262144.0f) - m * m;
    st[g][0] = m;
    st[g][1] = rsqrtf(var + 1e-5f);
  }
  __syncthreads();
  for (int i = tid; i < 5120; i += 256) {
    int row = i / 320;
    int rem = i - row * 320;
    int colw = rem >> 5;
    int c4 = (rem & 31) * 4;
    int wc = (w0 + colw - 1 + WRV) & (WRV - 1);
    float4 x4 = *(const float4*)(t1 + ((size_t)b * NPIX + row * WRV + wc) * 128 + c4);
    int g = c4 >> 4;
    float m = st[g][0], is = st[g][1];
    float4 g4 = *(const float4*)(g1 + c4);
    float4 b4 = *(const float4*)(bt1 + c4);
    float y0 = geluf((x4.x - m) * is * g4.x + b4.x);
    float y1 = geluf((x4.y - m) * is * g4.y + b4.y);
    float y2 = geluf((x4.z - m) * is * g4.z + b4.z);
    float y3 = geluf((x4.w - m) * is * g4.w + b4.w);
    uint2 o;
    o.x = (unsigned int)f2bf(y0) | ((unsigned int)f2bf(y1) << 16);
    o.y = (unsigned int)f2bf(y2) | ((unsigned int)f2bf(y3) << 16);
    *(uint2*)((char*)tile + cswz2(row, colw, c4)) = o;
  }
  __syncthreads();
  int wave = tid >> 6, l = tid & 63;
  int lr = l & 15, lk = l >> 4;
  f32x4 acc[2][4];
#pragma unroll
  for (int cc2 = 0; cc2 < 2; cc2++)
#pragma unroll
    for (int nt = 0; nt < 4; nt++) acc[cc2][nt] = (f32x4){0.f, 0.f, 0.f, 0.f};
#pragma unroll
  for (int kpos = 0; kpos < 9; kpos++) {
    int ky = kpos / 3, kx = kpos - ky * 3;
    int arow = (lr + ky - 1 + 16) & 15;
#pragma unroll
    for (int cc2 = 0; cc2 < 2; cc2++) {
      int acol = wave * 2 + cc2 + kx;
#pragma unroll
      for (int ks = 0; ks < 4; ks++) {
        short8 a = *(const short8*)((const char*)tile + cswz2(arow, acol, ks * 32 + lk * 8));
#pragma unroll
        for (int nt = 0; nt < 4; nt++) {
          short8 bv = *(const short8*)(w2p + (size_t)(kpos * 64 + nt * 16 + lr) * 128 +
                                       ks * 32 + lk * 8);
          acc[cc2][nt] = __builtin_amdgcn_mfma_f32_16x16x32_bf16(a, bv, acc[cc2][nt], 0, 0, 0);
        }
      }
    }
  }
#pragma unroll
  for (int cc2 = 0; cc2 < 2; cc2++) {
    int cc = wave * 2 + cc2;
#pragma unroll
    for (int nt = 0; nt < 4; nt++) {
      int o = nt * 16 + lr;
#pragma unroll
      for (int r = 0; r < 4; r++) {
        int p = (lk * 4 + r) * WRV + w0 + cc;
        t2[((size_t)b * NPIX + p) * 64 + o] = acc[cc2][nt][r];
      }
    }
  }
  float ps[4], pss[4];
#pragma unroll
  for (int nt = 0; nt < 4; nt++) { ps[nt] = 0.f; pss[nt] = 0.f; }
#pragma unroll
  for (int cc2 = 0; cc2 < 2; cc2++)
#pragma unroll
    for (int nt = 0; nt < 4; nt++)
#pragma unroll
      for (int r = 0; r < 4; r++) {
        float v = acc[cc2][nt][r];
        ps[nt] += v;
        pss[nt] += v * v;
      }
#pragma unroll
  for (int nt = 0; nt < 4; nt++) {
    ps[nt] += __shfl_xor(ps[nt], 1);  pss[nt] += __shfl_xor(pss[nt], 1);
    ps[nt] += __shfl_xor(ps[nt], 2);  pss[nt] += __shfl_xor(pss[nt], 2);
    ps[nt] += __shfl_xor(ps[nt], 4);  pss[nt] += __shfl_xor(pss[nt], 4);
    ps[nt] += __shfl_xor(ps[nt], 16); pss[nt] += __shfl_xor(pss[nt], 16);
    ps[nt] += __shfl_xor(ps[nt], 32); pss[nt] += __shfl_xor(pss[nt], 32);
  }
  if ((l & 0x37) == 0) {
    int b3 = (l >> 3) & 1;
#pragma unroll
    for (int nt = 0; nt < 4; nt++) {
      wred[wave][b3][nt][0] = ps[nt];
      wred[wave][b3][nt][1] = pss[nt];
    }
  }
  __syncthreads();
  if (tid < 8) {
    int nt = tid >> 1, b3 = tid & 1;
    float S = 0.f, SS = 0.f;
    for (int wv = 0; wv < 4; wv++) { S += wred[wv][b3][nt][0]; SS += wred[wv][b3][nt][1]; }
    int g = nt * 2 + b3;
    sums2[(((size_t)b * 8 + g) * 128 + blockIdx.x) * 2 + 0] = S;
    sums2[(((size_t)b * 8 + g) * 128 + blockIdx.x) * 2 + 1] = SS;
  }
}

// ---------------- K3: fused head (GN2+GELU+trig) + query MLP ----------------
__global__ __launch_bounds__(256) void k_headquery(
    const float* __restrict__ t2, const float* __restrict__ sums2,
    const float* __restrict__ g2, const float* __restrict__ bt2,
    const float* __restrict__ rh_w3, const float* __restrict__ rh_b3,
    const float* __restrict__ l2e, const unsigned short* __restrict__ q0,
    const unsigned short* __restrict__ qsW1p, const float* __restrict__ qs_b1,
    const float* __restrict__ qs_w1f,
    const unsigned short* __restrict__ qsW2p, const float* __restrict__ qs_b2,
    float* __restrict__ params, float* __restrict__ klpart,
    unsigned short* __restrict__ query, RVConsts C) {
  __shared__ float st2[8][2];
  __shared__ unsigned short qin[64][136];
  __shared__ unsigned short hq[64][136];
  __shared__ float sigf[64][6];
  __shared__ float klred[64];
  int b = blockIdx.y;
  int n0 = blockIdx.x * 64;
  int tid = threadIdx.x;
  if (tid < 8) {
    int g = tid;
    float S = 0.f, SS = 0.f;
    for (int ch = 0; ch < 128; ch++) {
      S += sums2[(((size_t)b * 8 + g) * 128 + ch) * 2];
      SS += sums2[(((size_t)b * 8 + g) * 128 + ch) * 2 + 1];
    }
    float m = S * (1.0f / 131072.0f);
    float var = SS * (1.0f / 131072.0f) - m * m;
    st2[g][0] = m;
    st2[g][1] = rsqrtf(var + 1e-5f);
  }
  const unsigned short* src = q0 + ((size_t)b * NPIX + n0) * 128;
  for (int i = tid; i < 1024; i += 256) {
    int p = i >> 4, c0 = (i & 15) * 8;
    *(uint4*)&qin[p][c0] = *(const uint4*)(src + p * 128 + c0);
  }
  __syncthreads();
  {
    int px = tid >> 2, q = tid & 3;
    int n = n0 + px;
    int h = n >> 10, w = n & 1023;
    const float* t = t2 + ((size_t)b * NPIX + n) * 64 + q * 16;
    float hd0 = 0.f, hd1 = 0.f, hd2 = 0.f, hd3 = 0.f;
#pragma unroll
    for (int j = 0; j < 16; j++) {
      int c = q * 16 + j;
      int g = c >> 3;
      float xv = geluf((t[j] - st2[g][0]) * st2[g][1] * g2[c] + bt2[c]);
      hd0 += rh_w3[c] * xv;
      hd1 += rh_w3[64 + c] * xv;
      hd2 += rh_w3[128 + c] * xv;
      hd3 += rh_w3[192 + c] * xv;
    }
    hd0 += __shfl_xor(hd0, 1); hd1 += __shfl_xor(hd1, 1);
    hd2 += __shfl_xor(hd2, 1); hd3 += __shfl_xor(hd3, 1);
    hd0 += __shfl_xor(hd0, 2); hd1 += __shfl_xor(hd1, 2);
    hd2 += __shfl_xor(hd2, 2); hd3 += __shfl_xor(hd3, 2);
    if (q == 0) {
      hd0 += rh_b3[0]; hd1 += rh_b3[1]; hd2 += rh_b3[2]; hd3 += rh_b3[3];
      float mu = sigmoidf_(hd0) * 55.0f;
      float sd = softplusf_(hd1) + 1e-3f;
      float stepw = C.steps[w & 15];
      float se = sigmoidf_(hd2) * stepw + 1e-3f;
      float sa = sigmoidf_(hd3) * C.az_step_f + 1e-3f;
      float E0 = C.means[h];
      float A0 = azimf(w, C.step_d, C.az0, C.az_half);
      float* P = params + ((size_t)b * NPIX + n) * 16;
      P[0] = sd; P[1] = se; P[2] = sa;
      sigf[px][0] = sd; sigf[px][1] = se; sigf[px][2] = sa;
      sigf[px][3] = 1.0f / (sd + 1e-6f);
      sigf[px][4] = 1.0f / (se + 1e-6f);
      sigf[px][5] = 1.0f / (sa + 1e-6f);
      float M00 = l2e[0], M01 = l2e[1], M10 = l2e[4], M11 = l2e[5];
      float M20 = l2e[8], M21 = l2e[9], M30 = l2e[12], M31 = l2e[13];
#pragma unroll
      for (int k = 0; k < 5; k++) {
        float off = -0.6f + 0.3f * (float)k;
        float d = mu + sd * off;
        float E = E0 + se * off;
        float A = A0 + sa * off;
        float ce = cosf(E);
        float xl = d * ce * cosf(A), yl = d * ce * sinf(A), zl = d * sinf(E);
        float px_ = xl * M00 + yl * M10 + zl * M20 + M30;
        float py_ = xl * M01 + yl * M11 + zl * M21 + M31;
        P[3 + 2 * k] = sigmoidf_(4.0f * ((px_ + 55.0f) * (1.0f / 110.0f) - 0.5f));
        P[4 + 2 * k] = sigmoidf_(4.0f * ((py_ + 55.0f) * (1.0f / 110.0f) - 0.5f));
      }
      float mu_n = mu * (1.0f / 55.0f);
      float sr = fmaxf(sd, 1e-6f);
      float saz = sa / C.az_step_f;
      float sel = se / stepw;
      klred[px] = 0.5f * (mu_n * mu_n + sr * sr - logf(sr * sr) - 1.0f) +
                  0.5f * (saz * saz - logf(saz * saz) - 1.0f) +
                  0.5f * (sel * sel - logf(sel * sel) - 1.0f);
    }
  }
  __syncthreads();
  if (tid == 0) {
    float sL = 0.f;
    for (int i = 0; i < 64; i++) sL += klred[i];
    klpart[b * 256 + blockIdx.x] = sL;
  }
  int wave = tid >> 6, l = tid & 63;
  int lr = l & 15, lk = l >> 4;
  f32x4 acc[8];
#pragma unroll
  for (int nt = 0; nt < 8; nt++) {
    int n = nt * 16 + lr;
    float wt[6];
#pragma unroll
    for (int c = 0; c < 6; c++) wt[c] = qs_w1f[(size_t)n * 134 + 128 + c];
    float bias = qs_b1[n];
#pragma unroll
    for (int r = 0; r < 4; r++) {
      int pl = wave * 16 + lk * 4 + r;
      float a = bias;
#pragma unroll
      for (int c = 0; c < 6; c++) a += wt[c] * sigf[pl][c];
      acc[nt][r] = a;
    }
  }
#pragma unroll
  for (int ks = 0; ks < 4; ks++) {
    short8 a = *(const short8*)&qin[wave * 16 + lr][ks * 32 + lk * 8];
#pragma unroll
    for (int nt = 0; nt < 8; nt++) {
      short8 bv = *(const short8*)(qsW1p + (size_t)(nt * 16 + lr) * 128 + ks * 32 + lk * 8);
      acc[nt] = __builtin_amdgcn_mfma_f32_16x16x32_bf16(a, bv, acc[nt], 0, 0, 0);
    }
  }
#pragma unroll
  for (int nt = 0; nt < 8; nt++)
#pragma unroll
    for (int r = 0; r < 4; r++)
      hq[wave * 16 + lk * 4 + r][nt * 16 + lr] = f2bf(geluf(acc[nt][r]));
  __syncthreads();
#pragma unroll
  for (int nt = 0; nt < 8; nt++) {
    float bias = qs_b2[nt * 16 + lr];
    acc[nt] = (f32x4){bias, bias, bias, bias};
  }
#pragma unroll
  for (int ks = 0; ks < 4; ks++) {
    short8 a = *(const short8*)&hq[wave * 16 + lr][ks * 32 + lk * 8];
#pragma unroll
    for (int nt = 0; nt < 8; nt++) {
      short8 bv = *(const short8*)(qsW2p + (size_t)(nt * 16 + lr) * 128 + ks * 32 + lk * 8);
      acc[nt] = __builtin_amdgcn_mfma_f32_16x16x32_bf16(a, bv, acc[nt], 0, 0, 0);
    }
  }
#pragma unroll
  for (int nt = 0; nt < 8; nt++) {
    int n = nt * 16 + lr;
#pragma unroll
    for (int r = 0; r < 4; r++) {
      int p = n0 + wave * 16 + lk * 4 + r;
      query[((size_t)b * NPIX + p) * 128 + n] = f2bf(acc[nt][r]);
    }
  }
}

// ---------------- K4: pack weights to bf16 ----------------
__global__ __launch_bounds__(256) void k_pack(
    const float* __restrict__ val_w, const float* __restrict__ w_v,
    const float* __restrict__ b_v, const float* __restrict__ val_b,
    const float* __restrict__ off_w, const float* __restrict__ off_b,
    const float* __restrict__ aw_w, const float* __restrict__ aw_b,
    const float* __restrict__ out_w, const float* __restrict__ qs_w1,
    const float* __restrict__ qs_w2, const float* __restrict__ rh_w1,
    const float* __restrict__ w_q, const float* __restrict__ w_o,
    const float* __restrict__ rh_w2,
    unsigned short* __restrict__ wvv_bf, float* __restrict__ bvv,
    unsigned short* __restrict__ projW, float* __restrict__ projB,
    unsigned short* __restrict__ outW, unsigned short* __restrict__ qsW1p,
    unsigned short* __restrict__ qsW2p, unsigned short* __restrict__ rhW1p,
    unsigned short* __restrict__ wqp, unsigned short* __restrict__ woP,
    unsigned short* __restrict__ w2p) {
  int idx = blockIdx.x * 256 + threadIdx.x;
  if (idx < 16384) {
    int o = idx >> 7, c = idx & 127;
    float acc = 0.0f;
    for (int m = 0; m < 128; m++) acc += val_w[o * 128 + m] * w_v[m * 128 + c];
    wvv_bf[idx] = f2bf(acc);
  } else if (idx < 16512) {
    int o = idx - 16384;
    float acc = val_b[o];
    for (int m = 0; m < 128; m++) acc += val_w[o * 128 + m] * b_v[m];
    bvv[o] = acc;
  } else if (idx < 82048) {
    int j = idx - 16512;
    int r = j >> 7, c = j & 127;
    float w = (r < 320) ? off_w[r * 128 + c] : ((r < 480) ? aw_w[(r - 320) * 128 + c] : 0.0f);
    projW[j] = f2bf(w);
  } else if (idx < 82560) {
    int r = idx - 82048;
    projB[r] = (r < 320) ? off_b[r] : ((r < 480) ? aw_b[r - 320] : 0.0f);
  } else if (idx < 98944) {
    int j = idx - 82560;
    outW[j] = f2bf(out_w[j]);
  } else if (idx < 115328) {
    int j = idx - 98944;
    int r = j >> 7, c = j & 127;
    qsW1p[j] = f2bf(qs_w1[r * 134 + c]);
  } else if (idx < 131712) {
    int j = idx - 115328;
    qsW2p[j] = f2bf(qs_w2[j]);
  } else if (idx < 144000) {
    int j = idx - 131712;
    int r = j / 96, c = j - r * 96;
    rhW1p[j] = (c < 67) ? f2bf(rh_w1[r * 67 + c]) : 0;
  } else if (idx < 156288) {
    int j = idx - 144000;
    int r = j / 96, c = j - r * 96;
    wqp[j] = (c < 64) ? f2bf(w_q[r * 64 + c]) : 0;
  } else if (idx < 172672) {
    int j = idx - 156288;
    woP[j] = f2bf(w_o[j]);
  } else if (idx < 246400) {
    int j = idx - 172672;
    int kpos = j >> 13;
    int rem = j & 8191;
    int o = rem >> 7, c = rem & 127;
    int ky = kpos / 3, kx = kpos - ky * 3;
    w2p[j] = f2bf(rh_w2[((size_t)(o * 128 + c) * 3 + ky) * 3 + kx]);
  }
}

// ---------------- K5: MFMA value projection -> bf16 v ----------------
__global__ __launch_bounds__(256) void k_value(
    const float* __restrict__ bev, const unsigned short* __restrict__ wvv_bf,
    const float* __restrict__ bvv, unsigned short* __restrict__ v) {
  __shared__ float lds[128 * 66];
  int b = blockIdx.y;
  int p0 = blockIdx.x * 64;
  int tid = threadIdx.x;
  int npx = NBEV - p0; if (npx > 64) npx = 64;
  for (int i = tid; i < 128 * 64; i += 256) {
    int c = i >> 6, p = i & 63;
    lds[c * 66 + p] = (p < npx) ? bev[((size_t)b * 128 + c) * NBEV + p0 + p] : 0.0f;
  }
  __syncthreads();
  int wave = tid >> 6, l = tid & 63;
  int lr = l & 15, lk = l >> 4;
  int ploc = wave * 16 + lr;
  f32x4 acc[8];
#pragma unroll
  for (int nt = 0; nt < 8; nt++) {
    float bias = bvv[nt * 16 + lr];
    acc[nt] = (f32x4){bias, bias, bias, bias};
  }
#pragma unroll
  for (int ks = 0; ks < 4; ks++) {
    int k0 = ks * 32 + lk * 8;
    short8 a;
#pragma unroll
    for (int j = 0; j < 8; j++) a[j] = (short)f2bf(lds[(k0 + j) * 66 + ploc]);
#pragma unroll
    for (int nt = 0; nt < 8; nt++) {
      short8 bf = *(const short8*)(wvv_bf + (size_t)(nt * 16 + lr) * 128 + k0);
      acc[nt] = __builtin_amdgcn_mfma_f32_16x16x32_bf16(a, bf, acc[nt], 0, 0, 0);
    }
  }
#pragma unroll
  for (int nt = 0; nt < 8; nt++) {
    int n = nt * 16 + lr;
#pragma unroll
    for (int r = 0; r < 4; r++) {
      int p = p0 + wave * 16 + lk * 4 + r;
      if (p < NBEV) v[((size_t)b * NBEV + p) * 128 + n] = f2bf(acc[nt][r]);
    }
  }
}

// ---------------- K6: MFMA projection, query LDS-staged once, 4 n-chunks ----------------
__global__ __launch_bounds__(256) void k_proj(
    const unsigned short* __restrict__ query, const unsigned short* __restrict__ projW,
    const float* __restrict__ projB, unsigned short* __restrict__ proj) {
  __shared__ unsigned short qlds[64][136];
  int b = blockIdx.y;
  int p0b = blockIdx.x * 64;
  int tid = threadIdx.x;
  const unsigned short* src = query + ((size_t)b * NPIX + p0b) * 128;
  for (int i = tid; i < 1024; i += 256) {
    int p = i >> 4, c0 = (i & 15) * 8;
    *(uint4*)&qlds[p][c0] = *(const uint4*)(src + p * 128 + c0);
  }
  __syncthreads();
  int wave = tid >> 6, l = tid & 63;
  int lr = l & 15, lk = l >> 4;
  int p0 = p0b + wave * 16;
  for (int nc = 0; nc < 4; nc++) {
    int n0 = nc * 128;
    f32x4 acc[8];
#pragma unroll
    for (int nt = 0; nt < 8; nt++) {
      float bias = projB[n0 + nt * 16 + lr];
      acc[nt] = (f32x4){bias, bias, bias, bias};
    }
#pragma unroll
    for (int ks = 0; ks < 4; ks++) {
      short8 a = *(const short8*)&qlds[wave * 16 + lr][ks * 32 + lk * 8];
#pragma unroll
      for (int nt = 0; nt < 8; nt++) {
        short8 bf = *(const short8*)(projW + (size_t)(n0 + nt * 16 + lr) * 128 +
                                     ks * 32 + lk * 8);
        acc[nt] = __builtin_amdgcn_mfma_f32_16x16x32_bf16(a, bf, acc[nt], 0, 0, 0);
      }
    }
#pragma unroll
    for (int nt = 0; nt < 8; nt++) {
      int n = n0 + nt * 16 + lr;
#pragma unroll
      for (int r = 0; r < 4; r++) {
        int p = p0 + lk * 4 + r;
        proj[((size_t)b * NPIX + p) * 512 + n] = f2bf(acc[nt][r]);
      }
    }
  }
}

// ---------------- K7: sampler — 8 lanes per (pixel,head): tap-set x channel-half ----------------
// lane g in [0,8): ts = g>>1 (5 taps each), th = g&1 (8 channels each).
// Softmax reduce over ts: shfl_xor(2), shfl_xor(4). Channel reduce likewise. g<2 stores.
__global__ __launch_bounds__(256) void k_samp(
    const unsigned short* __restrict__ proj, const float* __restrict__ params,
    const unsigned short* __restrict__ v, unsigned short* __restrict__ S) {
  int b = blockIdx.y;
  int bid = blockIdx.x;
  int pb = (bid & 7) * 512 + (bid >> 3);  // XCD-chunked swizzle (4096 = 8*512)
  int tid = threadIdx.x;
  int g = tid & 7;
  int hh = (tid >> 3) & 7;
  int pl = tid >> 6;
  int ts = g >> 1, th = g & 1;
  int n = pb * 4 + pl;
  const unsigned short* base = proj + ((size_t)b * NPIX + n) * 512;
  float lg[5];
#pragma unroll
  for (int t = 0; t < 5; t++) lg[t] = bf2f(base[320 + hh * 20 + ts * 5 + t]);
  float mx = fmaxf(fmaxf(fmaxf(lg[0], lg[1]), fmaxf(lg[2], lg[3])), lg[4]);
  mx = fmaxf(mx, __shfl_xor(mx, 2));
  mx = fmaxf(mx, __shfl_xor(mx, 4));
  float e[5];
  float s = 0.0f;
#pragma unroll
  for (int t = 0; t < 5; t++) { e[t] = expf(lg[t] - mx); s += e[t]; }
  s += __shfl_xor(s, 2);
  s += __shfl_xor(s, 4);
  float rs = 1.0f / s;
  const float* P = params + ((size_t)b * NPIX + n) * 16;
  const unsigned short* vb = v + (size_t)b * NBEV * 128 + hh * 16 + th * 8;
  float acc[8];
#pragma unroll
  for (int c = 0; c < 8; c++) acc[c] = 0.0f;
#pragma unroll
  for (int t = 0; t < 5; t++) {
    int kp = ts * 5 + t;
    int k = kp >> 2;
    unsigned int u = *(const unsigned int*)(base + hh * 40 + kp * 2);
    float X = P[3 + 2 * k] * 220.0f - 0.5f + bf2f((unsigned short)(u & 0xffffu));
    float Y = P[4 + 2 * k] * 220.0f - 0.5f + bf2f((unsigned short)(u >> 16));
    float xf = floorf(X), yf = floorf(Y);
    float wx = X - xf, wy = Y - yf;
    int x0 = (int)xf, y0 = (int)yf;
    float wx0 = ((unsigned)x0 < 220u) ? (1.0f - wx) : 0.0f;
    float wx1 = ((unsigned)(x0 + 1) < 220u) ? wx : 0.0f;
    float wy0 = ((unsigned)y0 < 220u) ? (1.0f - wy) : 0.0f;
    float wy1 = ((unsigned)(y0 + 1) < 220u) ? wy : 0.0f;
    int cx0 = min(max(x0, 0), 219), cx1 = min(max(x0 + 1, 0), 219);
    int cy0 = min(max(y0, 0), 219) * 220, cy1 = min(max(y0 + 1, 0), 219) * 220;
    float a = e[t] * rs;
    float u0 = a * wy0, u1 = a * wy1;
    float w4[4] = {u0 * wx0, u0 * wx1, u1 * wx0, u1 * wx1};
    int i4[4] = {cy0 + cx0, cy0 + cx1, cy1 + cx0, cy1 + cx1};
#pragma unroll
    for (int c2 = 0; c2 < 4; c2++) {
      float w = w4[c2];
      const uint2* sp = (const uint2*)(vb + (size_t)i4[c2] * 128);
      uint2 r0 = sp[0], r1 = sp[1];
      acc[0] += w * bf2f((unsigned short)(r0.x & 0xffffu));
      acc[1] += w * bf2f((unsigned short)(r0.x >> 16));
      acc[2] += w * bf2f((unsigned short)(r0.y & 0xffffu));
      acc[3] += w * bf2f((unsigned short)(r0.y >> 16));
      acc[4] += w * bf2f((unsigned short)(r1.x & 0xffffu));
      acc[5] += w * bf2f((unsigned short)(r1.x >> 16));
      acc[6] += w * bf2f((unsigned short)(r1.y & 0xffffu));
      acc[7] += w * bf2f((unsigned short)(r1.y >> 16));
    }
  }
#pragma unroll
  for (int c = 0; c < 8; c++) {
    acc[c] += __shfl_xor(acc[c], 2);
    acc[c] += __shfl_xor(acc[c], 4);
  }
  if (ts == 0) {
    uint4 o1;
    o1.x = (unsigned int)f2bf(acc[0]) | ((unsigned int)f2bf(acc[1]) << 16);
    o1.y = (unsigned int)f2bf(acc[2]) | ((unsigned int)f2bf(acc[3]) << 16);
    o1.z = (unsigned int)f2bf(acc[4]) | ((unsigned int)f2bf(acc[5]) << 16);
    o1.w = (unsigned int)f2bf(acc[6]) | ((unsigned int)f2bf(acc[7]) << 16);
    *(uint4*)(S + ((size_t)b * NPIX + n) * 128 + hh * 16 + th * 8) = o1;
  }
}

// ---------------- K8: fused out-proj + residual + final conv1x1 + NCHW store + KL ----------------
__global__ __launch_bounds__(256) void k_outfinal(
    const unsigned short* __restrict__ S, const unsigned short* __restrict__ outW,
    const float* __restrict__ out_b, const unsigned short* __restrict__ query,
    const unsigned short* __restrict__ woP, const float* __restrict__ b_o,
    const float* __restrict__ klpart, float* __restrict__ out) {
  __shared__ unsigned short ylds[64][136];
  __shared__ float yt[128][67];
  int b = blockIdx.y;
  int p0b = blockIdx.x * 64;
  int tid = threadIdx.x;
  int wave = tid >> 6, l = tid & 63;
  int lr = l & 15, lk = l >> 4;
  {
    f32x4 acc[8];
#pragma unroll
    for (int nt = 0; nt < 8; nt++) {
      float bias = out_b[nt * 16 + lr];
      acc[nt] = (f32x4){bias, bias, bias, bias};
    }
    const unsigned short* ap = S + ((size_t)b * NPIX + p0b + wave * 16 + lr) * 128 + lk * 8;
#pragma unroll
    for (int ks = 0; ks < 4; ks++) {
      short8 a = *(const short8*)(ap + ks * 32);
#pragma unroll
      for (int nt = 0; nt < 8; nt++) {
        short8 bf = *(const short8*)(outW + (size_t)(nt * 16 + lr) * 128 + ks * 32 + lk * 8);
        acc[nt] = __builtin_amdgcn_mfma_f32_16x16x32_bf16(a, bf, acc[nt], 0, 0, 0);
      }
    }
#pragma unroll
    for (int nt = 0; nt < 8; nt++) {
      int n = nt * 16 + lr;
#pragma unroll
      for (int r = 0; r < 4; r++) {
        int p_local = wave * 16 + lk * 4 + r;
        size_t o = ((size_t)b * NPIX + p0b + p_local) * 128 + n;
        ylds[p_local][n] = f2bf(acc[nt][r] + bf2f(query[o]));
      }
    }
  }
  __syncthreads();
  {
    f32x4 acc[8];
#pragma unroll
    for (int nt = 0; nt < 8; nt++) {
      float bias = b_o[nt * 16 + lr];
      acc[nt] = (f32x4){bias, bias, bias, bias};
    }
#pragma unroll
    for (int ks = 0; ks < 4; ks++) {
      short8 a = *(const short8*)&ylds[wave * 16 + lr][ks * 32 + lk * 8];
#pragma unroll
      for (int nt = 0; nt < 8; nt++) {
        short8 bf = *(const short8*)(woP + (size_t)(nt * 16 + lr) * 128 + ks * 32 + lk * 8);
        acc[nt] = __builtin_amdgcn_mfma_f32_16x16x32_bf16(a, bf, acc[nt], 0, 0, 0);
      }
    }
#pragma unroll
    for (int nt = 0; nt < 8; nt++)
#pragma unroll
      for (int r = 0; r < 4; r++)
        yt[nt * 16 + lr][wave * 16 + lk * 4 + r] = acc[nt][r];
  }
  __syncthreads();
  int n = tid >> 1, half = tid & 1;
  float* dst = out + ((size_t)(b * 128 + n)) * NPIX + p0b + half * 32;
#pragma unroll
  for (int j = 0; j < 8; j++) {
    float4 v4 = {yt[n][half * 32 + j * 4], yt[n][half * 32 + j * 4 + 1],
                 yt[n][half * 32 + j * 4 + 2], yt[n][half * 32 + j * 4 + 3]};
    *(float4*)(dst + j * 4) = v4;
  }
  if (blockIdx.x == 0 && b == 0 && tid == 0) {
    float sL = 0.0f;
    for (int i = 0; i < 512; i++) sL += klpart[i];
    out[(size_t)BSZ * 128 * NPIX] = 1e-4f * (sL / 32768.0f);
  }
}

// ---------------- host ----------------
static RVConsts make_consts() {
  static const float ELEV[32] = {
      -30.67f, -29.33f, -28.0f, -26.66f, -25.33f, -24.0f, -22.67f, -21.33f,
      -20.0f,  -18.67f, -17.33f, -16.0f, -14.67f, -13.33f, -12.0f, -10.67f,
      -9.33f,  -8.0f,   -6.66f,  -5.33f, -4.0f,   -2.67f,  -1.33f, 0.0f,
      1.33f,   2.67f,   4.0f,    5.33f,  6.67f,   8.0f,    9.33f,  10.67f};
  RVConsts C;
  const float d2r = 0.017453292519943295f;
  for (int r = 0; r < 16; r++) {
    float a = ELEV[31 - 2 * r], b = ELEV[30 - 2 * r];
    float mx = fmaxf(a, b), mn = fminf(a, b);
    C.steps[r] = (mx - mn) * d2r;
    C.means[r] = ((a + b) * 0.5f) * d2r;
  }
  const double PI_D = 3.14159265358979323846;
  double step_d = (PI_D - (-PI_D)) / 1024.0;
  double az0 = -PI_D;
  double az1 = az0 + step_d;
  double az_step_d = az1 - az0;
  C.az_step_f = (float)az_step_d;
  C.pad_ = 0.0f;
  C.step_d = step_d;
  C.az0 = az0;
  C.az_half = az_step_d * 0.5;
  return C;
}

// Workspace layout (f32 words). Peak 21,632,128 words = 86.5 MB.
#define OFF_T1     0u
#define OFF_T2     8388608u
#define OFF_Q0     10485760u
#define OFF_PARAMS 14680064u
#define OFF_QUERY  15204352u
#define OFF_S      19398656u
#define OFF_SUMS1  21495808u
#define OFF_SUMS2  21504000u
#define OFF_KL     21508096u
#define OFF_PROJ   0u
#define OFF_V      8388608u
#define OFF_WVV    21508608u
#define OFF_BVV    21516800u
#define OFF_PROJW  21516928u
#define OFF_PROJB  21549696u
#define OFF_OUTW   21550208u
#define OFF_QSW1   21558400u
#define OFF_QSW2   21566592u
#define OFF_RHW1   21574784u
#define OFF_WQP    21580928u
#define OFF_WOP    21587072u
#define OFF_W2P    21595264u

extern "C" void kernel_launch(void* const* d_in, const int* in_sizes, int n_in,
                              void* d_out, int out_size, void* d_ws, size_t ws_size,
                              hipStream_t stream) {
  const float* x_rv = (const float*)d_in[0];
  const float* bev = (const float*)d_in[1];
  const float* l2e = (const float*)d_in[2];
  const float* w_q = (const float*)d_in[3];
  const float* b_q = (const float*)d_in[4];
  const float* w_v = (const float*)d_in[5];
  const float* b_v = (const float*)d_in[6];
  const float* w_o = (const float*)d_in[7];
  const float* b_o = (const float*)d_in[8];
  const float* qs_w1 = (const float*)d_in[9];
  const float* qs_b1 = (const float*)d_in[10];
  const float* qs_w2 = (const float*)d_in[11];
  const float* qs_b2 = (const float*)d_in[12];
  const float* rh_w1 = (const float*)d_in[13];
  const float* rh_b1 = (const float*)d_in[14];
  const float* rh_g1 = (const float*)d_in[15];
  const float* rh_bt1 = (const float*)d_in[16];
  const float* rh_w2 = (const float*)d_in[17];
  const float* rh_g2 = (const float*)d_in[18];
  const float* rh_bt2 = (const float*)d_in[19];
  const float* rh_w3 = (const float*)d_in[20];
  const float* rh_b3 = (const float*)d_in[21];
  const float* off_w = (const float*)d_in[22];
  const float* off_b = (const float*)d_in[23];
  const float* aw_w = (const float*)d_in[24];
  const float* aw_b = (const float*)d_in[25];
  const float* val_w = (const float*)d_in[26];
  const float* val_b = (const float*)d_in[27];
  const float* out_w = (const float*)d_in[28];
  const float* out_b = (const float*)d_in[29];

  float* ws = (float*)d_ws;
  float* t1 = ws + OFF_T1;
  float* t2 = ws + OFF_T2;
  float* params = ws + OFF_PARAMS;
  float* sums1 = ws + OFF_SUMS1;
  float* sums2 = ws + OFF_SUMS2;
  float* klpart = ws + OFF_KL;
  float* bvv = ws + OFF_BVV;
  float* projB = ws + OFF_PROJB;
  unsigned short* q0bf = (unsigned short*)(ws + OFF_Q0);
  unsigned short* querybf = (unsigned short*)(ws + OFF_QUERY);
  unsigned short* S_bf = (unsigned short*)(ws + OFF_S);
  unsigned short* proj_bf = (unsigned short*)(ws + OFF_PROJ);
  unsigned short* v_bf = (unsigned short*)(ws + OFF_V);
  unsigned short* wvv_bf = (unsigned short*)(ws + OFF_WVV);
  unsigned short* projW = (unsigned short*)(ws + OFF_PROJW);
  unsigned short* outW = (unsigned short*)(ws + OFF_OUTW);
  unsigned short* qsW1p = (unsigned short*)(ws + OFF_QSW1);
  unsigned short* qsW2p = (unsigned short*)(ws + OFF_QSW2);
  unsigned short* rhW1p = (unsigned short*)(ws + OFF_RHW1);
  unsigned short* wqp = (unsigned short*)(ws + OFF_WQP);
  unsigned short* woP = (unsigned short*)(ws + OFF_WOP);
  unsigned short* w2p = (unsigned short*)(ws + OFF_W2P);

  RVConsts C = make_consts();
  dim3 blk(256);

  k_pack<<<963, blk, 0, stream>>>(val_w, w_v, b_v, val_b, off_w, off_b, aw_w, aw_b, out_w,
                                  qs_w1, qs_w2, rh_w1, w_q, w_o, rh_w2,
                                  wvv_bf, bvv, projW, projB, outW, qsW1p, qsW2p, rhW1p,
                                  wqp, woP, w2p);
  k_rh1_q0<<<dim3(256, BSZ), blk, 0, stream>>>(x_rv, rhW1p, rh_b1, wqp, b_q, t1, q0bf,
                                               sums1, C);
  k_conv3g<<<dim3(128, BSZ), blk, 0, stream>>>(t1, sums1, rh_g1, rh_bt1, w2p, t2, sums2);
  k_headquery<<<dim3(256, BSZ), blk, 0, stream>>>(t2, sums2, rh_g2, rh_bt2, rh_w3, rh_b3,
                                                  l2e, q0bf, qsW1p, qs_b1, qs_w1, qsW2p,
                                                  qs_b2, params, klpart, querybf, C);
  k_value<<<dim3(757, BSZ), blk, 0, stream>>>(bev, wvv_bf, bvv, v_bf);
  k_proj<<<dim3(256, BSZ), blk, 0, stream>>>(querybf, projW, projB, proj_bf);
  k_samp<<<dim3(4096, BSZ), blk, 0, stream>>>(proj_bf, params, v_bf, S_bf);
  k_outfinal<<<dim3(256, BSZ), blk, 0, stream>>>(S_bf, outW, out_b, querybf, woP, b_o,
                                                 klpart, (float*)d_out);
}

// Round 11
// 270.771 us; speedup vs baseline: 2.3059x; 1.0231x over previous
//
#include <hip/hip_runtime.h>
#include <math.h>

#define HRV 16
#define WRV 1024
#define NPIX 16384
#define NBEV 48400
#define BSZ 2

typedef __attribute__((ext_vector_type(8))) short short8;
typedef __attribute__((ext_vector_type(4))) float f32x4;

struct RVConsts {
  float steps[16];
  float means[16];
  float az_step_f;
  float pad_;
  double step_d;
  double az0;
  double az_half;
};

__device__ __forceinline__ float geluf(float x) {
  return 0.5f * x * (1.0f + erff(x * 0.70710678118654752440f));
}
__device__ __forceinline__ float sigmoidf_(float x) {
  return 1.0f / (1.0f + expf(-x));
}
__device__ __forceinline__ float softplusf_(float x) {
  return fmaxf(x, 0.0f) + log1pf(expf(-fabsf(x)));
}
__device__ __forceinline__ float azimf(int w, double step_d, double az0, double az_half) {
  double az = (double)w * step_d + az0;
  az += az_half;
  return (float)az;
}
__device__ __forceinline__ unsigned short f2bf(float f) {
  unsigned int u = __builtin_bit_cast(unsigned int, f);
  u = u + 0x7FFFu + ((u >> 16) & 1u);
  return (unsigned short)(u >> 16);
}
__device__ __forceinline__ float bf2f(unsigned short h) {
  unsigned int u = ((unsigned int)h) << 16;
  return __builtin_bit_cast(float, u);
}

// ---------------- K1: MFMA rh-conv1 + Q0 conv + fused gnsum1 partials ----------------
__global__ __launch_bounds__(256) void k_rh1_q0(
    const float* __restrict__ x_rv,
    const unsigned short* __restrict__ rhW1p, const float* __restrict__ rh_b1,
    const unsigned short* __restrict__ wqp, const float* __restrict__ b_q,
    float* __restrict__ t1, unsigned short* __restrict__ q0,
    float* __restrict__ sums1, RVConsts C) {
  __shared__ unsigned short xin[64][104];
  __shared__ float wred[4][8][2];
  int b = blockIdx.y;
  int n0 = blockIdx.x * 64;
  int tid = threadIdx.x;
  const float* src = x_rv + ((size_t)b * NPIX + n0) * 64;
  for (int i = tid; i < 1024; i += 256) {
    int p = i >> 4, c = (i & 15) * 4;
    float4 v4 = *(const float4*)(src + p * 64 + c);
    xin[p][c] = f2bf(v4.x);
    xin[p][c + 1] = f2bf(v4.y);
    xin[p][c + 2] = f2bf(v4.z);
    xin[p][c + 3] = f2bf(v4.w);
  }
  if (tid < 64) {
    int n = n0 + tid;
    int h = n >> 10, w = n & 1023;
    float E = C.means[h];
    float A = azimf(w, C.step_d, C.az0, C.az_half);
    float ce = cosf(E);
    xin[tid][64] = f2bf(ce * cosf(A));
    xin[tid][65] = f2bf(ce * sinf(A));
    xin[tid][66] = f2bf(sinf(E));
    for (int c = 67; c < 104; c++) xin[tid][c] = 0;
  }
  __syncthreads();
  int wave = tid >> 6, l = tid & 63;
  int lr = l & 15, lk = l >> 4;
  f32x4 acc[8], accq[8];
#pragma unroll
  for (int nt = 0; nt < 8; nt++) {
    float b1 = rh_b1[nt * 16 + lr], b2 = b_q[nt * 16 + lr];
    acc[nt] = (f32x4){b1, b1, b1, b1};
    accq[nt] = (f32x4){b2, b2, b2, b2};
  }
#pragma unroll
  for (int ks = 0; ks < 3; ks++) {
    short8 a = *(const short8*)&xin[wave * 16 + lr][ks * 32 + lk * 8];
#pragma unroll
    for (int nt = 0; nt < 8; nt++) {
      short8 b1v = *(const short8*)(rhW1p + (size_t)(nt * 16 + lr) * 96 + ks * 32 + lk * 8);
      acc[nt] = __builtin_amdgcn_mfma_f32_16x16x32_bf16(a, b1v, acc[nt], 0, 0, 0);
      short8 b2v = *(const short8*)(wqp + (size_t)(nt * 16 + lr) * 96 + ks * 32 + lk * 8);
      accq[nt] = __builtin_amdgcn_mfma_f32_16x16x32_bf16(a, b2v, accq[nt], 0, 0, 0);
    }
  }
#pragma unroll
  for (int nt = 0; nt < 8; nt++) {
    int n = nt * 16 + lr;
#pragma unroll
    for (int r = 0; r < 4; r++) {
      int p = n0 + wave * 16 + lk * 4 + r;
      size_t o = ((size_t)b * NPIX + p) * 128 + n;
      t1[o] = acc[nt][r];
      q0[o] = f2bf(accq[nt][r]);
    }
  }
  float s1[8], ss1[8];
#pragma unroll
  for (int nt = 0; nt < 8; nt++) {
    float a0 = acc[nt][0], a1 = acc[nt][1], a2 = acc[nt][2], a3 = acc[nt][3];
    s1[nt] = a0 + a1 + a2 + a3;
    ss1[nt] = a0 * a0 + a1 * a1 + a2 * a2 + a3 * a3;
  }
#pragma unroll
  for (int nt = 0; nt < 8; nt++) {
    s1[nt] += __shfl_xor(s1[nt], 1);  ss1[nt] += __shfl_xor(ss1[nt], 1);
    s1[nt] += __shfl_xor(s1[nt], 2);  ss1[nt] += __shfl_xor(ss1[nt], 2);
    s1[nt] += __shfl_xor(s1[nt], 4);  ss1[nt] += __shfl_xor(ss1[nt], 4);
    s1[nt] += __shfl_xor(s1[nt], 8);  ss1[nt] += __shfl_xor(ss1[nt], 8);
    s1[nt] += __shfl_xor(s1[nt], 16); ss1[nt] += __shfl_xor(ss1[nt], 16);
    s1[nt] += __shfl_xor(s1[nt], 32); ss1[nt] += __shfl_xor(ss1[nt], 32);
  }
  if (l == 0) {
#pragma unroll
    for (int nt = 0; nt < 8; nt++) { wred[wave][nt][0] = s1[nt]; wred[wave][nt][1] = ss1[nt]; }
  }
  __syncthreads();
  if (tid < 8) {
    float S = wred[0][tid][0] + wred[1][tid][0] + wred[2][tid][0] + wred[3][tid][0];
    float SS = wred[0][tid][1] + wred[1][tid][1] + wred[2][tid][1] + wred[3][tid][1];
    sums1[(((size_t)b * 8 + tid) * 256 + blockIdx.x) * 2 + 0] = S;
    sums1[(((size_t)b * 8 + tid) * 256 + blockIdx.x) * 2 + 1] = SS;
  }
}

// ---------------- K2: MFMA 3x3 circular conv with fused GN1+GELU staging + gnsum2 ----------------
__device__ __forceinline__ int cswz2(int row, int colw, int c) {
  int byte = ((row * 10 + colw) << 8) + (c << 1);
  return byte ^ ((row & 7) << 4);
}
__global__ __launch_bounds__(256) void k_conv3g(
    const float* __restrict__ t1, const float* __restrict__ sums1,
    const float* __restrict__ g1, const float* __restrict__ bt1,
    const unsigned short* __restrict__ w2p,
    float* __restrict__ t2, float* __restrict__ sums2) {
  __shared__ unsigned short tile[16 * 10 * 128];
  __shared__ float st[8][2];
  __shared__ float wred[4][2][4][2];
  int b = blockIdx.y;
  int w0 = blockIdx.x * 8;
  int tid = threadIdx.x;
  if (tid < 8) {
    int g = tid;
    float S = 0.f, SS = 0.f;
    for (int ch = 0; ch < 256; ch++) {
      S += sums1[(((size_t)b * 8 + g) * 256 + ch) * 2];
      SS += sums1[(((size_t)b * 8 + g) * 256 + ch) * 2 + 1];
    }
    float m = S * (1.0f / 262144.0f);
    float var = SS * (1.0f / 262144.0f) - m * m;
    st[g][0] = m;
    st[g][1] = rsqrtf(var + 1e-5f);
  }
  __syncthreads();
  for (int i = tid; i < 5120; i += 256) {
    int row = i / 320;
    int rem = i - row * 320;
    int colw = rem >> 5;
    int c4 = (rem & 31) * 4;
    int wc = (w0 + colw - 1 + WRV) & (WRV - 1);
    float4 x4 = *(const float4*)(t1 + ((size_t)b * NPIX + row * WRV + wc) * 128 + c4);
    int g = c4 >> 4;
    float m = st[g][0], is = st[g][1];
    float4 g4 = *(const float4*)(g1 + c4);
    float4 b4 = *(const float4*)(bt1 + c4);
    float y0 = geluf((x4.x - m) * is * g4.x + b4.x);
    float y1 = geluf((x4.y - m) * is * g4.y + b4.y);
    float y2 = geluf((x4.z - m) * is * g4.z + b4.z);
    float y3 = geluf((x4.w - m) * is * g4.w + b4.w);
    uint2 o;
    o.x = (unsigned int)f2bf(y0) | ((unsigned int)f2bf(y1) << 16);
    o.y = (unsigned int)f2bf(y2) | ((unsigned int)f2bf(y3) << 16);
    *(uint2*)((char*)tile + cswz2(row, colw, c4)) = o;
  }
  __syncthreads();
  int wave = tid >> 6, l = tid & 63;
  int lr = l & 15, lk = l >> 4;
  f32x4 acc[2][4];
#pragma unroll
  for (int cc2 = 0; cc2 < 2; cc2++)
#pragma unroll
    for (int nt = 0; nt < 4; nt++) acc[cc2][nt] = (f32x4){0.f, 0.f, 0.f, 0.f};
#pragma unroll
  for (int kpos = 0; kpos < 9; kpos++) {
    int ky = kpos / 3, kx = kpos - ky * 3;
    int arow = (lr + ky - 1 + 16) & 15;
#pragma unroll
    for (int cc2 = 0; cc2 < 2; cc2++) {
      int acol = wave * 2 + cc2 + kx;
#pragma unroll
      for (int ks = 0; ks < 4; ks++) {
        short8 a = *(const short8*)((const char*)tile + cswz2(arow, acol, ks * 32 + lk * 8));
#pragma unroll
        for (int nt = 0; nt < 4; nt++) {
          short8 bv = *(const short8*)(w2p + (size_t)(kpos * 64 + nt * 16 + lr) * 128 +
                                       ks * 32 + lk * 8);
          acc[cc2][nt] = __builtin_amdgcn_mfma_f32_16x16x32_bf16(a, bv, acc[cc2][nt], 0, 0, 0);
        }
      }
    }
  }
#pragma unroll
  for (int cc2 = 0; cc2 < 2; cc2++) {
    int cc = wave * 2 + cc2;
#pragma unroll
    for (int nt = 0; nt < 4; nt++) {
      int o = nt * 16 + lr;
#pragma unroll
      for (int r = 0; r < 4; r++) {
        int p = (lk * 4 + r) * WRV + w0 + cc;
        t2[((size_t)b * NPIX + p) * 64 + o] = acc[cc2][nt][r];
      }
    }
  }
  float ps[4], pss[4];
#pragma unroll
  for (int nt = 0; nt < 4; nt++) { ps[nt] = 0.f; pss[nt] = 0.f; }
#pragma unroll
  for (int cc2 = 0; cc2 < 2; cc2++)
#pragma unroll
    for (int nt = 0; nt < 4; nt++)
#pragma unroll
      for (int r = 0; r < 4; r++) {
        float v = acc[cc2][nt][r];
        ps[nt] += v;
        pss[nt] += v * v;
      }
#pragma unroll
  for (int nt = 0; nt < 4; nt++) {
    ps[nt] += __shfl_xor(ps[nt], 1);  pss[nt] += __shfl_xor(pss[nt], 1);
    ps[nt] += __shfl_xor(ps[nt], 2);  pss[nt] += __shfl_xor(pss[nt], 2);
    ps[nt] += __shfl_xor(ps[nt], 4);  pss[nt] += __shfl_xor(pss[nt], 4);
    ps[nt] += __shfl_xor(ps[nt], 16); pss[nt] += __shfl_xor(pss[nt], 16);
    ps[nt] += __shfl_xor(ps[nt], 32); pss[nt] += __shfl_xor(pss[nt], 32);
  }
  if ((l & 0x37) == 0) {
    int b3 = (l >> 3) & 1;
#pragma unroll
    for (int nt = 0; nt < 4; nt++) {
      wred[wave][b3][nt][0] = ps[nt];
      wred[wave][b3][nt][1] = pss[nt];
    }
  }
  __syncthreads();
  if (tid < 8) {
    int nt = tid >> 1, b3 = tid & 1;
    float S = 0.f, SS = 0.f;
    for (int wv = 0; wv < 4; wv++) { S += wred[wv][b3][nt][0]; SS += wred[wv][b3][nt][1]; }
    int g = nt * 2 + b3;
    sums2[(((size_t)b * 8 + g) * 128 + blockIdx.x) * 2 + 0] = S;
    sums2[(((size_t)b * 8 + g) * 128 + blockIdx.x) * 2 + 1] = SS;
  }
}

// ---------------- K3: fused head (GN2+GELU+trig) + query MLP ----------------
__global__ __launch_bounds__(256) void k_headquery(
    const float* __restrict__ t2, const float* __restrict__ sums2,
    const float* __restrict__ g2, const float* __restrict__ bt2,
    const float* __restrict__ rh_w3, const float* __restrict__ rh_b3,
    const float* __restrict__ l2e, const unsigned short* __restrict__ q0,
    const unsigned short* __restrict__ qsW1p, const float* __restrict__ qs_b1,
    const float* __restrict__ qs_w1f,
    const unsigned short* __restrict__ qsW2p, const float* __restrict__ qs_b2,
    float* __restrict__ params, float* __restrict__ klpart,
    unsigned short* __restrict__ query, RVConsts C) {
  __shared__ float st2[8][2];
  __shared__ unsigned short qin[64][136];
  __shared__ unsigned short hq[64][136];
  __shared__ float sigf[64][6];
  __shared__ float klred[64];
  int b = blockIdx.y;
  int n0 = blockIdx.x * 64;
  int tid = threadIdx.x;
  if (tid < 8) {
    int g = tid;
    float S = 0.f, SS = 0.f;
    for (int ch = 0; ch < 128; ch++) {
      S += sums2[(((size_t)b * 8 + g) * 128 + ch) * 2];
      SS += sums2[(((size_t)b * 8 + g) * 128 + ch) * 2 + 1];
    }
    float m = S * (1.0f / 131072.0f);
    float var = SS * (1.0f / 131072.0f) - m * m;
    st2[g][0] = m;
    st2[g][1] = rsqrtf(var + 1e-5f);
  }
  const unsigned short* src = q0 + ((size_t)b * NPIX + n0) * 128;
  for (int i = tid; i < 1024; i += 256) {
    int p = i >> 4, c0 = (i & 15) * 8;
    *(uint4*)&qin[p][c0] = *(const uint4*)(src + p * 128 + c0);
  }
  __syncthreads();
  {
    int px = tid >> 2, q = tid & 3;
    int n = n0 + px;
    int h = n >> 10, w = n & 1023;
    const float* t = t2 + ((size_t)b * NPIX + n) * 64 + q * 16;
    float hd0 = 0.f, hd1 = 0.f, hd2 = 0.f, hd3 = 0.f;
#pragma unroll
    for (int j = 0; j < 16; j++) {
      int c = q * 16 + j;
      int g = c >> 3;
      float xv = geluf((t[j] - st2[g][0]) * st2[g][1] * g2[c] + bt2[c]);
      hd0 += rh_w3[c] * xv;
      hd1 += rh_w3[64 + c] * xv;
      hd2 += rh_w3[128 + c] * xv;
      hd3 += rh_w3[192 + c] * xv;
    }
    hd0 += __shfl_xor(hd0, 1); hd1 += __shfl_xor(hd1, 1);
    hd2 += __shfl_xor(hd2, 1); hd3 += __shfl_xor(hd3, 1);
    hd0 += __shfl_xor(hd0, 2); hd1 += __shfl_xor(hd1, 2);
    hd2 += __shfl_xor(hd2, 2); hd3 += __shfl_xor(hd3, 2);
    if (q == 0) {
      hd0 += rh_b3[0]; hd1 += rh_b3[1]; hd2 += rh_b3[2]; hd3 += rh_b3[3];
      float mu = sigmoidf_(hd0) * 55.0f;
      float sd = softplusf_(hd1) + 1e-3f;
      float stepw = C.steps[w & 15];
      float se = sigmoidf_(hd2) * stepw + 1e-3f;
      float sa = sigmoidf_(hd3) * C.az_step_f + 1e-3f;
      float E0 = C.means[h];
      float A0 = azimf(w, C.step_d, C.az0, C.az_half);
      float* P = params + ((size_t)b * NPIX + n) * 16;
      P[0] = sd; P[1] = se; P[2] = sa;
      sigf[px][0] = sd; sigf[px][1] = se; sigf[px][2] = sa;
      sigf[px][3] = 1.0f / (sd + 1e-6f);
      sigf[px][4] = 1.0f / (se + 1e-6f);
      sigf[px][5] = 1.0f / (sa + 1e-6f);
      float M00 = l2e[0], M01 = l2e[1], M10 = l2e[4], M11 = l2e[5];
      float M20 = l2e[8], M21 = l2e[9], M30 = l2e[12], M31 = l2e[13];
#pragma unroll
      for (int k = 0; k < 5; k++) {
        float off = -0.6f + 0.3f * (float)k;
        float d = mu + sd * off;
        float E = E0 + se * off;
        float A = A0 + sa * off;
        float ce = cosf(E);
        float xl = d * ce * cosf(A), yl = d * ce * sinf(A), zl = d * sinf(E);
        float px_ = xl * M00 + yl * M10 + zl * M20 + M30;
        float py_ = xl * M01 + yl * M11 + zl * M21 + M31;
        P[3 + 2 * k] = sigmoidf_(4.0f * ((px_ + 55.0f) * (1.0f / 110.0f) - 0.5f));
        P[4 + 2 * k] = sigmoidf_(4.0f * ((py_ + 55.0f) * (1.0f / 110.0f) - 0.5f));
      }
      float mu_n = mu * (1.0f / 55.0f);
      float sr = fmaxf(sd, 1e-6f);
      float saz = sa / C.az_step_f;
      float sel = se / stepw;
      klred[px] = 0.5f * (mu_n * mu_n + sr * sr - logf(sr * sr) - 1.0f) +
                  0.5f * (saz * saz - logf(saz * saz) - 1.0f) +
                  0.5f * (sel * sel - logf(sel * sel) - 1.0f);
    }
  }
  __syncthreads();
  if (tid == 0) {
    float sL = 0.f;
    for (int i = 0; i < 64; i++) sL += klred[i];
    klpart[b * 256 + blockIdx.x] = sL;
  }
  int wave = tid >> 6, l = tid & 63;
  int lr = l & 15, lk = l >> 4;
  f32x4 acc[8];
#pragma unroll
  for (int nt = 0; nt < 8; nt++) {
    int n = nt * 16 + lr;
    float wt[6];
#pragma unroll
    for (int c = 0; c < 6; c++) wt[c] = qs_w1f[(size_t)n * 134 + 128 + c];
    float bias = qs_b1[n];
#pragma unroll
    for (int r = 0; r < 4; r++) {
      int pl = wave * 16 + lk * 4 + r;
      float a = bias;
#pragma unroll
      for (int c = 0; c < 6; c++) a += wt[c] * sigf[pl][c];
      acc[nt][r] = a;
    }
  }
#pragma unroll
  for (int ks = 0; ks < 4; ks++) {
    short8 a = *(const short8*)&qin[wave * 16 + lr][ks * 32 + lk * 8];
#pragma unroll
    for (int nt = 0; nt < 8; nt++) {
      short8 bv = *(const short8*)(qsW1p + (size_t)(nt * 16 + lr) * 128 + ks * 32 + lk * 8);
      acc[nt] = __builtin_amdgcn_mfma_f32_16x16x32_bf16(a, bv, acc[nt], 0, 0, 0);
    }
  }
#pragma unroll
  for (int nt = 0; nt < 8; nt++)
#pragma unroll
    for (int r = 0; r < 4; r++)
      hq[wave * 16 + lk * 4 + r][nt * 16 + lr] = f2bf(geluf(acc[nt][r]));
  __syncthreads();
#pragma unroll
  for (int nt = 0; nt < 8; nt++) {
    float bias = qs_b2[nt * 16 + lr];
    acc[nt] = (f32x4){bias, bias, bias, bias};
  }
#pragma unroll
  for (int ks = 0; ks < 4; ks++) {
    short8 a = *(const short8*)&hq[wave * 16 + lr][ks * 32 + lk * 8];
#pragma unroll
    for (int nt = 0; nt < 8; nt++) {
      short8 bv = *(const short8*)(qsW2p + (size_t)(nt * 16 + lr) * 128 + ks * 32 + lk * 8);
      acc[nt] = __builtin_amdgcn_mfma_f32_16x16x32_bf16(a, bv, acc[nt], 0, 0, 0);
    }
  }
#pragma unroll
  for (int nt = 0; nt < 8; nt++) {
    int n = nt * 16 + lr;
#pragma unroll
    for (int r = 0; r < 4; r++) {
      int p = n0 + wave * 16 + lk * 4 + r;
      query[((size_t)b * NPIX + p) * 128 + n] = f2bf(acc[nt][r]);
    }
  }
}

// ---------------- K4: pack weights to bf16 ----------------
__global__ __launch_bounds__(256) void k_pack(
    const float* __restrict__ val_w, const float* __restrict__ w_v,
    const float* __restrict__ b_v, const float* __restrict__ val_b,
    const float* __restrict__ off_w, const float* __restrict__ off_b,
    const float* __restrict__ aw_w, const float* __restrict__ aw_b,
    const float* __restrict__ out_w, const float* __restrict__ qs_w1,
    const float* __restrict__ qs_w2, const float* __restrict__ rh_w1,
    const float* __restrict__ w_q, const float* __restrict__ w_o,
    const float* __restrict__ rh_w2,
    unsigned short* __restrict__ wvv_bf, float* __restrict__ bvv,
    unsigned short* __restrict__ projW, float* __restrict__ projB,
    unsigned short* __restrict__ outW, unsigned short* __restrict__ qsW1p,
    unsigned short* __restrict__ qsW2p, unsigned short* __restrict__ rhW1p,
    unsigned short* __restrict__ wqp, unsigned short* __restrict__ woP,
    unsigned short* __restrict__ w2p) {
  int idx = blockIdx.x * 256 + threadIdx.x;
  if (idx < 16384) {
    int o = idx >> 7, c = idx & 127;
    float acc = 0.0f;
    for (int m = 0; m < 128; m++) acc += val_w[o * 128 + m] * w_v[m * 128 + c];
    wvv_bf[idx] = f2bf(acc);
  } else if (idx < 16512) {
    int o = idx - 16384;
    float acc = val_b[o];
    for (int m = 0; m < 128; m++) acc += val_w[o * 128 + m] * b_v[m];
    bvv[o] = acc;
  } else if (idx < 82048) {
    int j = idx - 16512;
    int r = j >> 7, c = j & 127;
    float w = (r < 320) ? off_w[r * 128 + c] : ((r < 480) ? aw_w[(r - 320) * 128 + c] : 0.0f);
    projW[j] = f2bf(w);
  } else if (idx < 82560) {
    int r = idx - 82048;
    projB[r] = (r < 320) ? off_b[r] : ((r < 480) ? aw_b[r - 320] : 0.0f);
  } else if (idx < 98944) {
    int j = idx - 82560;
    outW[j] = f2bf(out_w[j]);
  } else if (idx < 115328) {
    int j = idx - 98944;
    int r = j >> 7, c = j & 127;
    qsW1p[j] = f2bf(qs_w1[r * 134 + c]);
  } else if (idx < 131712) {
    int j = idx - 115328;
    qsW2p[j] = f2bf(qs_w2[j]);
  } else if (idx < 144000) {
    int j = idx - 131712;
    int r = j / 96, c = j - r * 96;
    rhW1p[j] = (c < 67) ? f2bf(rh_w1[r * 67 + c]) : 0;
  } else if (idx < 156288) {
    int j = idx - 144000;
    int r = j / 96, c = j - r * 96;
    wqp[j] = (c < 64) ? f2bf(w_q[r * 64 + c]) : 0;
  } else if (idx < 172672) {
    int j = idx - 156288;
    woP[j] = f2bf(w_o[j]);
  } else if (idx < 246400) {
    int j = idx - 172672;
    int kpos = j >> 13;
    int rem = j & 8191;
    int o = rem >> 7, c = rem & 127;
    int ky = kpos / 3, kx = kpos - ky * 3;
    w2p[j] = f2bf(rh_w2[((size_t)(o * 128 + c) * 3 + ky) * 3 + kx]);
  }
}

// ---------------- K5: MFMA value projection, 256-px tile (1KB bursts) -> bf16 v ----------------
// LDS [k=128][p=256] bf16 (64 KB), XOR-swizzled by ((k>>3)&7)<<4 (write & read same involution).
__global__ __launch_bounds__(256) void k_value(
    const float* __restrict__ bev, const unsigned short* __restrict__ wvv_bf,
    const float* __restrict__ bvv, unsigned short* __restrict__ v) {
  __shared__ unsigned short lds[128 * 256];  // 65536 B
  int b = blockIdx.y;
  int p0 = blockIdx.x * 256;
  int tid = threadIdx.x;
  // stage: 128 c-rows x 64 float4 (256 p) = 8192 items, 32 per thread
  for (int i = tid; i < 8192; i += 256) {
    int c = i >> 6;
    int p4 = (i & 63) * 4;
    int p = p0 + p4;
    float4 x;
    if (p + 3 < NBEV) {
      x = *(const float4*)(bev + ((size_t)b * 128 + c) * NBEV + p);
    } else {
      const float* row = bev + ((size_t)b * 128 + c) * NBEV;
      x.x = (p + 0 < NBEV) ? row[p + 0] : 0.0f;
      x.y = (p + 1 < NBEV) ? row[p + 1] : 0.0f;
      x.z = (p + 2 < NBEV) ? row[p + 2] : 0.0f;
      x.w = (p + 3 < NBEV) ? row[p + 3] : 0.0f;
    }
    uint2 o;
    o.x = (unsigned int)f2bf(x.x) | ((unsigned int)f2bf(x.y) << 16);
    o.y = (unsigned int)f2bf(x.z) | ((unsigned int)f2bf(x.w) << 16);
    int byte = (c << 9) + (p4 << 1);
    byte ^= ((c >> 3) & 7) << 4;
    *(uint2*)((char*)lds + byte) = o;
  }
  __syncthreads();
  int wave = tid >> 6, l = tid & 63;
  int lr = l & 15, lk = l >> 4;
#pragma unroll
  for (int sub = 0; sub < 4; sub++) {
    int ploc = sub * 64 + wave * 16 + lr;
    f32x4 acc[8];
#pragma unroll
    for (int nt = 0; nt < 8; nt++) {
      float bias = bvv[nt * 16 + lr];
      acc[nt] = (f32x4){bias, bias, bias, bias};
    }
#pragma unroll
    for (int ks = 0; ks < 4; ks++) {
      int k0 = ks * 32 + lk * 8;
      short8 a;
#pragma unroll
      for (int j = 0; j < 8; j++) {
        int k = k0 + j;
        int byte = (k << 9) + (ploc << 1);
        byte ^= ((k >> 3) & 7) << 4;
        a[j] = *(const short*)((const char*)lds + byte);
      }
#pragma unroll
      for (int nt = 0; nt < 8; nt++) {
        short8 bf = *(const short8*)(wvv_bf + (size_t)(nt * 16 + lr) * 128 + k0);
        acc[nt] = __builtin_amdgcn_mfma_f32_16x16x32_bf16(a, bf, acc[nt], 0, 0, 0);
      }
    }
#pragma unroll
    for (int nt = 0; nt < 8; nt++) {
      int n = nt * 16 + lr;
#pragma unroll
      for (int r = 0; r < 4; r++) {
        int p = p0 + sub * 64 + wave * 16 + lk * 4 + r;
        if (p < NBEV) v[((size_t)b * NBEV + p) * 128 + n] = f2bf(acc[nt][r]);
      }
    }
  }
}

// ---------------- K6: MFMA projection, query LDS-staged once, 4 n-chunks ----------------
__global__ __launch_bounds__(256) void k_proj(
    const unsigned short* __restrict__ query, const unsigned short* __restrict__ projW,
    const float* __restrict__ projB, unsigned short* __restrict__ proj) {
  __shared__ unsigned short qlds[64][136];
  int b = blockIdx.y;
  int p0b = blockIdx.x * 64;
  int tid = threadIdx.x;
  const unsigned short* src = query + ((size_t)b * NPIX + p0b) * 128;
  for (int i = tid; i < 1024; i += 256) {
    int p = i >> 4, c0 = (i & 15) * 8;
    *(uint4*)&qlds[p][c0] = *(const uint4*)(src + p * 128 + c0);
  }
  __syncthreads();
  int wave = tid >> 6, l = tid & 63;
  int lr = l & 15, lk = l >> 4;
  int p0 = p0b + wave * 16;
  for (int nc = 0; nc < 4; nc++) {
    int n0 = nc * 128;
    f32x4 acc[8];
#pragma unroll
    for (int nt = 0; nt < 8; nt++) {
      float bias = projB[n0 + nt * 16 + lr];
      acc[nt] = (f32x4){bias, bias, bias, bias};
    }
#pragma unroll
    for (int ks = 0; ks < 4; ks++) {
      short8 a = *(const short8*)&qlds[wave * 16 + lr][ks * 32 + lk * 8];
#pragma unroll
      for (int nt = 0; nt < 8; nt++) {
        short8 bf = *(const short8*)(projW + (size_t)(n0 + nt * 16 + lr) * 128 +
                                     ks * 32 + lk * 8);
        acc[nt] = __builtin_amdgcn_mfma_f32_16x16x32_bf16(a, bf, acc[nt], 0, 0, 0);
      }
    }
#pragma unroll
    for (int nt = 0; nt < 8; nt++) {
      int n = n0 + nt * 16 + lr;
#pragma unroll
      for (int r = 0; r < 4; r++) {
        int p = p0 + lk * 4 + r;
        proj[((size_t)b * NPIX + p) * 512 + n] = f2bf(acc[nt][r]);
      }
    }
  }
}

// ---------------- K7: sampler — 8 lanes per (pixel,head): tap-set x channel-half ----------------
__global__ __launch_bounds__(256) void k_samp(
    const unsigned short* __restrict__ proj, const float* __restrict__ params,
    const unsigned short* __restrict__ v, unsigned short* __restrict__ S) {
  int b = blockIdx.y;
  int bid = blockIdx.x;
  int pb = (bid & 7) * 512 + (bid >> 3);
  int tid = threadIdx.x;
  int g = tid & 7;
  int hh = (tid >> 3) & 7;
  int pl = tid >> 6;
  int ts = g >> 1, th = g & 1;
  int n = pb * 4 + pl;
  const unsigned short* base = proj + ((size_t)b * NPIX + n) * 512;
  float lg[5];
#pragma unroll
  for (int t = 0; t < 5; t++) lg[t] = bf2f(base[320 + hh * 20 + ts * 5 + t]);
  float mx = fmaxf(fmaxf(fmaxf(lg[0], lg[1]), fmaxf(lg[2], lg[3])), lg[4]);
  mx = fmaxf(mx, __shfl_xor(mx, 2));
  mx = fmaxf(mx, __shfl_xor(mx, 4));
  float e[5];
  float s = 0.0f;
#pragma unroll
  for (int t = 0; t < 5; t++) { e[t] = expf(lg[t] - mx); s += e[t]; }
  s += __shfl_xor(s, 2);
  s += __shfl_xor(s, 4);
  float rs = 1.0f / s;
  const float* P = params + ((size_t)b * NPIX + n) * 16;
  const unsigned short* vb = v + (size_t)b * NBEV * 128 + hh * 16 + th * 8;
  float acc[8];
#pragma unroll
  for (int c = 0; c < 8; c++) acc[c] = 0.0f;
#pragma unroll
  for (int t = 0; t < 5; t++) {
    int kp = ts * 5 + t;
    int k = kp >> 2;
    unsigned int u = *(const unsigned int*)(base + hh * 40 + kp * 2);
    float X = P[3 + 2 * k] * 220.0f - 0.5f + bf2f((unsigned short)(u & 0xffffu));
    float Y = P[4 + 2 * k] * 220.0f - 0.5f + bf2f((unsigned short)(u >> 16));
    float xf = floorf(X), yf = floorf(Y);
    float wx = X - xf, wy = Y - yf;
    int x0 = (int)xf, y0 = (int)yf;
    float wx0 = ((unsigned)x0 < 220u) ? (1.0f - wx) : 0.0f;
    float wx1 = ((unsigned)(x0 + 1) < 220u) ? wx : 0.0f;
    float wy0 = ((unsigned)y0 < 220u) ? (1.0f - wy) : 0.0f;
    float wy1 = ((unsigned)(y0 + 1) < 220u) ? wy : 0.0f;
    int cx0 = min(max(x0, 0), 219), cx1 = min(max(x0 + 1, 0), 219);
    int cy0 = min(max(y0, 0), 219) * 220, cy1 = min(max(y0 + 1, 0), 219) * 220;
    float a = e[t] * rs;
    float u0 = a * wy0, u1 = a * wy1;
    float w4[4] = {u0 * wx0, u0 * wx1, u1 * wx0, u1 * wx1};
    int i4[4] = {cy0 + cx0, cy0 + cx1, cy1 + cx0, cy1 + cx1};
#pragma unroll
    for (int c2 = 0; c2 < 4; c2++) {
      float w = w4[c2];
      const uint2* sp = (const uint2*)(vb + (size_t)i4[c2] * 128);
      uint2 r0 = sp[0], r1 = sp[1];
      acc[0] += w * bf2f((unsigned short)(r0.x & 0xffffu));
      acc[1] += w * bf2f((unsigned short)(r0.x >> 16));
      acc[2] += w * bf2f((unsigned short)(r0.y & 0xffffu));
      acc[3] += w * bf2f((unsigned short)(r0.y >> 16));
      acc[4] += w * bf2f((unsigned short)(r1.x & 0xffffu));
      acc[5] += w * bf2f((unsigned short)(r1.x >> 16));
      acc[6] += w * bf2f((unsigned short)(r1.y & 0xffffu));
      acc[7] += w * bf2f((unsigned short)(r1.y >> 16));
    }
  }
#pragma unroll
  for (int c = 0; c < 8; c++) {
    acc[c] += __shfl_xor(acc[c], 2);
    acc[c] += __shfl_xor(acc[c], 4);
  }
  if (ts == 0) {
    uint4 o1;
    o1.x = (unsigned int)f2bf(acc[0]) | ((unsigned int)f2bf(acc[1]) << 16);
    o1.y = (unsigned int)f2bf(acc[2]) | ((unsigned int)f2bf(acc[3]) << 16);
    o1.z = (unsigned int)f2bf(acc[4]) | ((unsigned int)f2bf(acc[5]) << 16);
    o1.w = (unsigned int)f2bf(acc[6]) | ((unsigned int)f2bf(acc[7]) << 16);
    *(uint4*)(S + ((size_t)b * NPIX + n) * 128 + hh * 16 + th * 8) = o1;
  }
}

// ---------------- K8: fused out-proj + residual + final conv1x1 + NCHW store + KL ----------------
__global__ __launch_bounds__(256) void k_outfinal(
    const unsigned short* __restrict__ S, const unsigned short* __restrict__ outW,
    const float* __restrict__ out_b, const unsigned short* __restrict__ query,
    const unsigned short* __restrict__ woP, const float* __restrict__ b_o,
    const float* __restrict__ klpart, float* __restrict__ out) {
  __shared__ unsigned short ylds[64][136];
  __shared__ float yt[128][67];
  int b = blockIdx.y;
  int p0b = blockIdx.x * 64;
  int tid = threadIdx.x;
  int wave = tid >> 6, l = tid & 63;
  int lr = l & 15, lk = l >> 4;
  {
    f32x4 acc[8];
#pragma unroll
    for (int nt = 0; nt < 8; nt++) {
      float bias = out_b[nt * 16 + lr];
      acc[nt] = (f32x4){bias, bias, bias, bias};
    }
    const unsigned short* ap = S + ((size_t)b * NPIX + p0b + wave * 16 + lr) * 128 + lk * 8;
#pragma unroll
    for (int ks = 0; ks < 4; ks++) {
      short8 a = *(const short8*)(ap + ks * 32);
#pragma unroll
      for (int nt = 0; nt < 8; nt++) {
        short8 bf = *(const short8*)(outW + (size_t)(nt * 16 + lr) * 128 + ks * 32 + lk * 8);
        acc[nt] = __builtin_amdgcn_mfma_f32_16x16x32_bf16(a, bf, acc[nt], 0, 0, 0);
      }
    }
#pragma unroll
    for (int nt = 0; nt < 8; nt++) {
      int n = nt * 16 + lr;
#pragma unroll
      for (int r = 0; r < 4; r++) {
        int p_local = wave * 16 + lk * 4 + r;
        size_t o = ((size_t)b * NPIX + p0b + p_local) * 128 + n;
        ylds[p_local][n] = f2bf(acc[nt][r] + bf2f(query[o]));
      }
    }
  }
  __syncthreads();
  {
    f32x4 acc[8];
#pragma unroll
    for (int nt = 0; nt < 8; nt++) {
      float bias = b_o[nt * 16 + lr];
      acc[nt] = (f32x4){bias, bias, bias, bias};
    }
#pragma unroll
    for (int ks = 0; ks < 4; ks++) {
      short8 a = *(const short8*)&ylds[wave * 16 + lr][ks * 32 + lk * 8];
#pragma unroll
      for (int nt = 0; nt < 8; nt++) {
        short8 bf = *(const short8*)(woP + (size_t)(nt * 16 + lr) * 128 + ks * 32 + lk * 8);
        acc[nt] = __builtin_amdgcn_mfma_f32_16x16x32_bf16(a, bf, acc[nt], 0, 0, 0);
      }
    }
#pragma unroll
    for (int nt = 0; nt < 8; nt++)
#pragma unroll
      for (int r = 0; r < 4; r++)
        yt[nt * 16 + lr][wave * 16 + lk * 4 + r] = acc[nt][r];
  }
  __syncthreads();
  int n = tid >> 1, half = tid & 1;
  float* dst = out + ((size_t)(b * 128 + n)) * NPIX + p0b + half * 32;
#pragma unroll
  for (int j = 0; j < 8; j++) {
    float4 v4 = {yt[n][half * 32 + j * 4], yt[n][half * 32 + j * 4 + 1],
                 yt[n][half * 32 + j * 4 + 2], yt[n][half * 32 + j * 4 + 3]};
    *(float4*)(dst + j * 4) = v4;
  }
  if (blockIdx.x == 0 && b == 0 && tid == 0) {
    float sL = 0.0f;
    for (int i = 0; i < 512; i++) sL += klpart[i];
    out[(size_t)BSZ * 128 * NPIX] = 1e-4f * (sL / 32768.0f);
  }
}

// ---------------- host ----------------
static RVConsts make_consts() {
  static const float ELEV[32] = {
      -30.67f, -29.33f, -28.0f, -26.66f, -25.33f, -24.0f, -22.67f, -21.33f,
      -20.0f,  -18.67f, -17.33f, -16.0f, -14.67f, -13.33f, -12.0f, -10.67f,
      -9.33f,  -8.0f,   -6.66f,  -5.33f, -4.0f,   -2.67f,  -1.33f, 0.0f,
      1.33f,   2.67f,   4.0f,    5.33f,  6.67f,   8.0f,    9.33f,  10.67f};
  RVConsts C;
  const float d2r = 0.017453292519943295f;
  for (int r = 0; r < 16; r++) {
    float a = ELEV[31 - 2 * r], b = ELEV[30 - 2 * r];
    float mx = fmaxf(a, b), mn = fminf(a, b);
    C.steps[r] = (mx - mn) * d2r;
    C.means[r] = ((a + b) * 0.5f) * d2r;
  }
  const double PI_D = 3.14159265358979323846;
  double step_d = (PI_D - (-PI_D)) / 1024.0;
  double az0 = -PI_D;
  double az1 = az0 + step_d;
  double az_step_d = az1 - az0;
  C.az_step_f = (float)az_step_d;
  C.pad_ = 0.0f;
  C.step_d = step_d;
  C.az0 = az0;
  C.az_half = az_step_d * 0.5;
  return C;
}

// Workspace layout (f32 words). Peak 21,632,128 words = 86.5 MB.
#define OFF_T1     0u
#define OFF_T2     8388608u
#define OFF_Q0     10485760u
#define OFF_PARAMS 14680064u
#define OFF_QUERY  15204352u
#define OFF_S      19398656u
#define OFF_SUMS1  21495808u
#define OFF_SUMS2  21504000u
#define OFF_KL     21508096u
#define OFF_PROJ   0u
#define OFF_V      8388608u
#define OFF_WVV    21508608u
#define OFF_BVV    21516800u
#define OFF_PROJW  21516928u
#define OFF_PROJB  21549696u
#define OFF_OUTW   21550208u
#define OFF_QSW1   21558400u
#define OFF_QSW2   21566592u
#define OFF_RHW1   21574784u
#define OFF_WQP    21580928u
#define OFF_WOP    21587072u
#define OFF_W2P    21595264u

extern "C" void kernel_launch(void* const* d_in, const int* in_sizes, int n_in,
                              void* d_out, int out_size, void* d_ws, size_t ws_size,
                              hipStream_t stream) {
  const float* x_rv = (const float*)d_in[0];
  const float* bev = (const float*)d_in[1];
  const float* l2e = (const float*)d_in[2];
  const float* w_q = (const float*)d_in[3];
  const float* b_q = (const float*)d_in[4];
  const float* w_v = (const float*)d_in[5];
  const float* b_v = (const float*)d_in[6];
  const float* w_o = (const float*)d_in[7];
  const float* b_o = (const float*)d_in[8];
  const float* qs_w1 = (const float*)d_in[9];
  const float* qs_b1 = (const float*)d_in[10];
  const float* qs_w2 = (const float*)d_in[11];
  const float* qs_b2 = (const float*)d_in[12];
  const float* rh_w1 = (const float*)d_in[13];
  const float* rh_b1 = (const float*)d_in[14];
  const float* rh_g1 = (const float*)d_in[15];
  const float* rh_bt1 = (const float*)d_in[16];
  const float* rh_w2 = (const float*)d_in[17];
  const float* rh_g2 = (const float*)d_in[18];
  const float* rh_bt2 = (const float*)d_in[19];
  const float* rh_w3 = (const float*)d_in[20];
  const float* rh_b3 = (const float*)d_in[21];
  const float* off_w = (const float*)d_in[22];
  const float* off_b = (const float*)d_in[23];
  const float* aw_w = (const float*)d_in[24];
  const float* aw_b = (const float*)d_in[25];
  const float* val_w = (const float*)d_in[26];
  const float* val_b = (const float*)d_in[27];
  const float* out_w = (const float*)d_in[28];
  const float* out_b = (const float*)d_in[29];

  float* ws = (float*)d_ws;
  float* t1 = ws + OFF_T1;
  float* t2 = ws + OFF_T2;
  float* params = ws + OFF_PARAMS;
  float* sums1 = ws + OFF_SUMS1;
  float* sums2 = ws + OFF_SUMS2;
  float* klpart = ws + OFF_KL;
  float* bvv = ws + OFF_BVV;
  float* projB = ws + OFF_PROJB;
  unsigned short* q0bf = (unsigned short*)(ws + OFF_Q0);
  unsigned short* querybf = (unsigned short*)(ws + OFF_QUERY);
  unsigned short* S_bf = (unsigned short*)(ws + OFF_S);
  unsigned short* proj_bf = (unsigned short*)(ws + OFF_PROJ);
  unsigned short* v_bf = (unsigned short*)(ws + OFF_V);
  unsigned short* wvv_bf = (unsigned short*)(ws + OFF_WVV);
  unsigned short* projW = (unsigned short*)(ws + OFF_PROJW);
  unsigned short* outW = (unsigned short*)(ws + OFF_OUTW);
  unsigned short* qsW1p = (unsigned short*)(ws + OFF_QSW1);
  unsigned short* qsW2p = (unsigned short*)(ws + OFF_QSW2);
  unsigned short* rhW1p = (unsigned short*)(ws + OFF_RHW1);
  unsigned short* wqp = (unsigned short*)(ws + OFF_WQP);
  unsigned short* woP = (unsigned short*)(ws + OFF_WOP);
  unsigned short* w2p = (unsigned short*)(ws + OFF_W2P);

  RVConsts C = make_consts();
  dim3 blk(256);

  k_pack<<<963, blk, 0, stream>>>(val_w, w_v, b_v, val_b, off_w, off_b, aw_w, aw_b, out_w,
                                  qs_w1, qs_w2, rh_w1, w_q, w_o, rh_w2,
                                  wvv_bf, bvv, projW, projB, outW, qsW1p, qsW2p, rhW1p,
                                  wqp, woP, w2p);
  k_rh1_q0<<<dim3(256, BSZ), blk, 0, stream>>>(x_rv, rhW1p, rh_b1, wqp, b_q, t1, q0bf,
                                               sums1, C);
  k_conv3g<<<dim3(128, BSZ), blk, 0, stream>>>(t1, sums1, rh_g1, rh_bt1, w2p, t2, sums2);
  k_headquery<<<dim3(256, BSZ), blk, 0, stream>>>(t2, sums2, rh_g2, rh_bt2, rh_w3, rh_b3,
                                                  l2e, q0bf, qsW1p, qs_b1, qs_w1, qsW2p,
                                                  qs_b2, params, klpart, querybf, C);
  k_value<<<dim3(190, BSZ), blk, 0, stream>>>(bev, wvv_bf, bvv, v_bf);
  k_proj<<<dim3(256, BSZ), blk, 0, stream>>>(querybf, projW, projB, proj_bf);
  k_samp<<<dim3(4096, BSZ), blk, 0, stream>>>(proj_bf, params, v_bf, S_bf);
  k_outfinal<<<dim3(256, BSZ), blk, 0, stream>>>(S_bf, outW, out_b, querybf, woP, b_o,
                                                 klpart, (float*)d_out);
}

// Round 12
// 257.474 us; speedup vs baseline: 2.4250x; 1.0516x over previous
//
#include <hip/hip_runtime.h>
#include <math.h>

#define HRV 16
#define WRV 1024
#define NPIX 16384
#define NBEV 48400
#define BSZ 2

typedef __attribute__((ext_vector_type(8))) short short8;
typedef __attribute__((ext_vector_type(4))) float f32x4;

struct RVConsts {
  float steps[16];
  float means[16];
  float az_step_f;
  float pad_;
  double step_d;
  double az0;
  double az_half;
};

__device__ __forceinline__ float geluf(float x) {
  return 0.5f * x * (1.0f + erff(x * 0.70710678118654752440f));
}
__device__ __forceinline__ float sigmoidf_(float x) {
  return 1.0f / (1.0f + expf(-x));
}
__device__ __forceinline__ float softplusf_(float x) {
  return fmaxf(x, 0.0f) + log1pf(expf(-fabsf(x)));
}
__device__ __forceinline__ float azimf(int w, double step_d, double az0, double az_half) {
  double az = (double)w * step_d + az0;
  az += az_half;
  return (float)az;
}
__device__ __forceinline__ unsigned short f2bf(float f) {
  unsigned int u = __builtin_bit_cast(unsigned int, f);
  u = u + 0x7FFFu + ((u >> 16) & 1u);
  return (unsigned short)(u >> 16);
}
__device__ __forceinline__ float bf2f(unsigned short h) {
  unsigned int u = ((unsigned int)h) << 16;
  return __builtin_bit_cast(float, u);
}

// ---------------- K1: MFMA rh-conv1 + Q0 conv + fused gnsum1 partials ----------------
__global__ __launch_bounds__(256) void k_rh1_q0(
    const float* __restrict__ x_rv,
    const unsigned short* __restrict__ rhW1p, const float* __restrict__ rh_b1,
    const unsigned short* __restrict__ wqp, const float* __restrict__ b_q,
    float* __restrict__ t1, unsigned short* __restrict__ q0,
    float* __restrict__ sums1, RVConsts C) {
  __shared__ unsigned short xin[64][104];
  __shared__ float wred[4][8][2];
  int b = blockIdx.y;
  int n0 = blockIdx.x * 64;
  int tid = threadIdx.x;
  const float* src = x_rv + ((size_t)b * NPIX + n0) * 64;
  for (int i = tid; i < 1024; i += 256) {
    int p = i >> 4, c = (i & 15) * 4;
    float4 v4 = *(const float4*)(src + p * 64 + c);
    xin[p][c] = f2bf(v4.x);
    xin[p][c + 1] = f2bf(v4.y);
    xin[p][c + 2] = f2bf(v4.z);
    xin[p][c + 3] = f2bf(v4.w);
  }
  if (tid < 64) {
    int n = n0 + tid;
    int h = n >> 10, w = n & 1023;
    float E = C.means[h];
    float A = azimf(w, C.step_d, C.az0, C.az_half);
    float ce = cosf(E);
    xin[tid][64] = f2bf(ce * cosf(A));
    xin[tid][65] = f2bf(ce * sinf(A));
    xin[tid][66] = f2bf(sinf(E));
    for (int c = 67; c < 104; c++) xin[tid][c] = 0;
  }
  __syncthreads();
  int wave = tid >> 6, l = tid & 63;
  int lr = l & 15, lk = l >> 4;
  f32x4 acc[8], accq[8];
#pragma unroll
  for (int nt = 0; nt < 8; nt++) {
    float b1 = rh_b1[nt * 16 + lr], b2 = b_q[nt * 16 + lr];
    acc[nt] = (f32x4){b1, b1, b1, b1};
    accq[nt] = (f32x4){b2, b2, b2, b2};
  }
#pragma unroll
  for (int ks = 0; ks < 3; ks++) {
    short8 a = *(const short8*)&xin[wave * 16 + lr][ks * 32 + lk * 8];
#pragma unroll
    for (int nt = 0; nt < 8; nt++) {
      short8 b1v = *(const short8*)(rhW1p + (size_t)(nt * 16 + lr) * 96 + ks * 32 + lk * 8);
      acc[nt] = __builtin_amdgcn_mfma_f32_16x16x32_bf16(a, b1v, acc[nt], 0, 0, 0);
      short8 b2v = *(const short8*)(wqp + (size_t)(nt * 16 + lr) * 96 + ks * 32 + lk * 8);
      accq[nt] = __builtin_amdgcn_mfma_f32_16x16x32_bf16(a, b2v, accq[nt], 0, 0, 0);
    }
  }
#pragma unroll
  for (int nt = 0; nt < 8; nt++) {
    int n = nt * 16 + lr;
#pragma unroll
    for (int r = 0; r < 4; r++) {
      int p = n0 + wave * 16 + lk * 4 + r;
      size_t o = ((size_t)b * NPIX + p) * 128 + n;
      t1[o] = acc[nt][r];
      q0[o] = f2bf(accq[nt][r]);
    }
  }
  float s1[8], ss1[8];
#pragma unroll
  for (int nt = 0; nt < 8; nt++) {
    float a0 = acc[nt][0], a1 = acc[nt][1], a2 = acc[nt][2], a3 = acc[nt][3];
    s1[nt] = a0 + a1 + a2 + a3;
    ss1[nt] = a0 * a0 + a1 * a1 + a2 * a2 + a3 * a3;
  }
#pragma unroll
  for (int nt = 0; nt < 8; nt++) {
    s1[nt] += __shfl_xor(s1[nt], 1);  ss1[nt] += __shfl_xor(ss1[nt], 1);
    s1[nt] += __shfl_xor(s1[nt], 2);  ss1[nt] += __shfl_xor(ss1[nt], 2);
    s1[nt] += __shfl_xor(s1[nt], 4);  ss1[nt] += __shfl_xor(ss1[nt], 4);
    s1[nt] += __shfl_xor(s1[nt], 8);  ss1[nt] += __shfl_xor(ss1[nt], 8);
    s1[nt] += __shfl_xor(s1[nt], 16); ss1[nt] += __shfl_xor(ss1[nt], 16);
    s1[nt] += __shfl_xor(s1[nt], 32); ss1[nt] += __shfl_xor(ss1[nt], 32);
  }
  if (l == 0) {
#pragma unroll
    for (int nt = 0; nt < 8; nt++) { wred[wave][nt][0] = s1[nt]; wred[wave][nt][1] = ss1[nt]; }
  }
  __syncthreads();
  if (tid < 8) {
    float S = wred[0][tid][0] + wred[1][tid][0] + wred[2][tid][0] + wred[3][tid][0];
    float SS = wred[0][tid][1] + wred[1][tid][1] + wred[2][tid][1] + wred[3][tid][1];
    sums1[(((size_t)b * 8 + tid) * 256 + blockIdx.x) * 2 + 0] = S;
    sums1[(((size_t)b * 8 + tid) * 256 + blockIdx.x) * 2 + 1] = SS;
  }
}

// ---------------- K2: MFMA 3x3 circular conv with fused GN1+GELU staging + gnsum2 ----------------
__device__ __forceinline__ int cswz2(int row, int colw, int c) {
  int byte = ((row * 10 + colw) << 8) + (c << 1);
  return byte ^ ((row & 7) << 4);
}
__global__ __launch_bounds__(256) void k_conv3g(
    const float* __restrict__ t1, const float* __restrict__ sums1,
    const float* __restrict__ g1, const float* __restrict__ bt1,
    const unsigned short* __restrict__ w2p,
    float* __restrict__ t2, float* __restrict__ sums2) {
  __shared__ unsigned short tile[16 * 10 * 128];
  __shared__ float st[8][2];
  __shared__ float wred[4][2][4][2];
  int b = blockIdx.y;
  int w0 = blockIdx.x * 8;
  int tid = threadIdx.x;
  if (tid < 8) {
    int g = tid;
    float S = 0.f, SS = 0.f;
    for (int ch = 0; ch < 256; ch++) {
      S += sums1[(((size_t)b * 8 + g) * 256 + ch) * 2];
      SS += sums1[(((size_t)b * 8 + g) * 256 + ch) * 2 + 1];
    }
    float m = S * (1.0f / 262144.0f);
    float var = SS * (1.0f / 262144.0f) - m * m;
    st[g][0] = m;
    st[g][1] = rsqrtf(var + 1e-5f);
  }
  __syncthreads();
  for (int i = tid; i < 5120; i += 256) {
    int row = i / 320;
    int rem = i - row * 320;
    int colw = rem >> 5;
    int c4 = (rem & 31) * 4;
    int wc = (w0 + colw - 1 + WRV) & (WRV - 1);
    float4 x4 = *(const float4*)(t1 + ((size_t)b * NPIX + row * WRV + wc) * 128 + c4);
    int g = c4 >> 4;
    float m = st[g][0], is = st[g][1];
    float4 g4 = *(const float4*)(g1 + c4);
    float4 b4 = *(const float4*)(bt1 + c4);
    float y0 = geluf((x4.x - m) * is * g4.x + b4.x);
    float y1 = geluf((x4.y - m) * is * g4.y + b4.y);
    float y2 = geluf((x4.z - m) * is * g4.z + b4.z);
    float y3 = geluf((x4.w - m) * is * g4.w + b4.w);
    uint2 o;
    o.x = (unsigned int)f2bf(y0) | ((unsigned int)f2bf(y1) << 16);
    o.y = (unsigned int)f2bf(y2) | ((unsigned int)f2bf(y3) << 16);
    *(uint2*)((char*)tile + cswz2(row, colw, c4)) = o;
  }
  __syncthreads();
  int wave = tid >> 6, l = tid & 63;
  int lr = l & 15, lk = l >> 4;
  f32x4 acc[2][4];
#pragma unroll
  for (int cc2 = 0; cc2 < 2; cc2++)
#pragma unroll
    for (int nt = 0; nt < 4; nt++) acc[cc2][nt] = (f32x4){0.f, 0.f, 0.f, 0.f};
#pragma unroll
  for (int kpos = 0; kpos < 9; kpos++) {
    int ky = kpos / 3, kx = kpos - ky * 3;
    int arow = (lr + ky - 1 + 16) & 15;
#pragma unroll
    for (int cc2 = 0; cc2 < 2; cc2++) {
      int acol = wave * 2 + cc2 + kx;
#pragma unroll
      for (int ks = 0; ks < 4; ks++) {
        short8 a = *(const short8*)((const char*)tile + cswz2(arow, acol, ks * 32 + lk * 8));
#pragma unroll
        for (int nt = 0; nt < 4; nt++) {
          short8 bv = *(const short8*)(w2p + (size_t)(kpos * 64 + nt * 16 + lr) * 128 +
                                       ks * 32 + lk * 8);
          acc[cc2][nt] = __builtin_amdgcn_mfma_f32_16x16x32_bf16(a, bv, acc[cc2][nt], 0, 0, 0);
        }
      }
    }
  }
#pragma unroll
  for (int cc2 = 0; cc2 < 2; cc2++) {
    int cc = wave * 2 + cc2;
#pragma unroll
    for (int nt = 0; nt < 4; nt++) {
      int o = nt * 16 + lr;
#pragma unroll
      for (int r = 0; r < 4; r++) {
        int p = (lk * 4 + r) * WRV + w0 + cc;
        t2[((size_t)b * NPIX + p) * 64 + o] = acc[cc2][nt][r];
      }
    }
  }
  float ps[4], pss[4];
#pragma unroll
  for (int nt = 0; nt < 4; nt++) { ps[nt] = 0.f; pss[nt] = 0.f; }
#pragma unroll
  for (int cc2 = 0; cc2 < 2; cc2++)
#pragma unroll
    for (int nt = 0; nt < 4; nt++)
#pragma unroll
      for (int r = 0; r < 4; r++) {
        float v = acc[cc2][nt][r];
        ps[nt] += v;
        pss[nt] += v * v;
      }
#pragma unroll
  for (int nt = 0; nt < 4; nt++) {
    ps[nt] += __shfl_xor(ps[nt], 1);  pss[nt] += __shfl_xor(pss[nt], 1);
    ps[nt] += __shfl_xor(ps[nt], 2);  pss[nt] += __shfl_xor(pss[nt], 2);
    ps[nt] += __shfl_xor(ps[nt], 4);  pss[nt] += __shfl_xor(pss[nt], 4);
    ps[nt] += __shfl_xor(ps[nt], 16); pss[nt] += __shfl_xor(pss[nt], 16);
    ps[nt] += __shfl_xor(ps[nt], 32); pss[nt] += __shfl_xor(pss[nt], 32);
  }
  if ((l & 0x37) == 0) {
    int b3 = (l >> 3) & 1;
#pragma unroll
    for (int nt = 0; nt < 4; nt++) {
      wred[wave][b3][nt][0] = ps[nt];
      wred[wave][b3][nt][1] = pss[nt];
    }
  }
  __syncthreads();
  if (tid < 8) {
    int nt = tid >> 1, b3 = tid & 1;
    float S = 0.f, SS = 0.f;
    for (int wv = 0; wv < 4; wv++) { S += wred[wv][b3][nt][0]; SS += wred[wv][b3][nt][1]; }
    int g = nt * 2 + b3;
    sums2[(((size_t)b * 8 + g) * 128 + blockIdx.x) * 2 + 0] = S;
    sums2[(((size_t)b * 8 + g) * 128 + blockIdx.x) * 2 + 1] = SS;
  }
}

// ---------------- K3: fused head (GN2+GELU+trig) + query MLP ----------------
__global__ __launch_bounds__(256) void k_headquery(
    const float* __restrict__ t2, const float* __restrict__ sums2,
    const float* __restrict__ g2, const float* __restrict__ bt2,
    const float* __restrict__ rh_w3, const float* __restrict__ rh_b3,
    const float* __restrict__ l2e, const unsigned short* __restrict__ q0,
    const unsigned short* __restrict__ qsW1p, const float* __restrict__ qs_b1,
    const float* __restrict__ qs_w1f,
    const unsigned short* __restrict__ qsW2p, const float* __restrict__ qs_b2,
    float* __restrict__ params, float* __restrict__ klpart,
    unsigned short* __restrict__ query, RVConsts C) {
  __shared__ float st2[8][2];
  __shared__ unsigned short qin[64][136];
  __shared__ unsigned short hq[64][136];
  __shared__ float sigf[64][6];
  __shared__ float klred[64];
  int b = blockIdx.y;
  int n0 = blockIdx.x * 64;
  int tid = threadIdx.x;
  if (tid < 8) {
    int g = tid;
    float S = 0.f, SS = 0.f;
    for (int ch = 0; ch < 128; ch++) {
      S += sums2[(((size_t)b * 8 + g) * 128 + ch) * 2];
      SS += sums2[(((size_t)b * 8 + g) * 128 + ch) * 2 + 1];
    }
    float m = S * (1.0f / 131072.0f);
    float var = SS * (1.0f / 131072.0f) - m * m;
    st2[g][0] = m;
    st2[g][1] = rsqrtf(var + 1e-5f);
  }
  const unsigned short* src = q0 + ((size_t)b * NPIX + n0) * 128;
  for (int i = tid; i < 1024; i += 256) {
    int p = i >> 4, c0 = (i & 15) * 8;
    *(uint4*)&qin[p][c0] = *(const uint4*)(src + p * 128 + c0);
  }
  __syncthreads();
  {
    int px = tid >> 2, q = tid & 3;
    int n = n0 + px;
    int h = n >> 10, w = n & 1023;
    const float* t = t2 + ((size_t)b * NPIX + n) * 64 + q * 16;
    float hd0 = 0.f, hd1 = 0.f, hd2 = 0.f, hd3 = 0.f;
#pragma unroll
    for (int j = 0; j < 16; j++) {
      int c = q * 16 + j;
      int g = c >> 3;
      float xv = geluf((t[j] - st2[g][0]) * st2[g][1] * g2[c] + bt2[c]);
      hd0 += rh_w3[c] * xv;
      hd1 += rh_w3[64 + c] * xv;
      hd2 += rh_w3[128 + c] * xv;
      hd3 += rh_w3[192 + c] * xv;
    }
    hd0 += __shfl_xor(hd0, 1); hd1 += __shfl_xor(hd1, 1);
    hd2 += __shfl_xor(hd2, 1); hd3 += __shfl_xor(hd3, 1);
    hd0 += __shfl_xor(hd0, 2); hd1 += __shfl_xor(hd1, 2);
    hd2 += __shfl_xor(hd2, 2); hd3 += __shfl_xor(hd3, 2);
    if (q == 0) {
      hd0 += rh_b3[0]; hd1 += rh_b3[1]; hd2 += rh_b3[2]; hd3 += rh_b3[3];
      float mu = sigmoidf_(hd0) * 55.0f;
      float sd = softplusf_(hd1) + 1e-3f;
      float stepw = C.steps[w & 15];
      float se = sigmoidf_(hd2) * stepw + 1e-3f;
      float sa = sigmoidf_(hd3) * C.az_step_f + 1e-3f;
      float E0 = C.means[h];
      float A0 = azimf(w, C.step_d, C.az0, C.az_half);
      float* P = params + ((size_t)b * NPIX + n) * 16;
      P[0] = sd; P[1] = se; P[2] = sa;
      sigf[px][0] = sd; sigf[px][1] = se; sigf[px][2] = sa;
      sigf[px][3] = 1.0f / (sd + 1e-6f);
      sigf[px][4] = 1.0f / (se + 1e-6f);
      sigf[px][5] = 1.0f / (sa + 1e-6f);
      float M00 = l2e[0], M01 = l2e[1], M10 = l2e[4], M11 = l2e[5];
      float M20 = l2e[8], M21 = l2e[9], M30 = l2e[12], M31 = l2e[13];
#pragma unroll
      for (int k = 0; k < 5; k++) {
        float off = -0.6f + 0.3f * (float)k;
        float d = mu + sd * off;
        float E = E0 + se * off;
        float A = A0 + sa * off;
        float ce = cosf(E);
        float xl = d * ce * cosf(A), yl = d * ce * sinf(A), zl = d * sinf(E);
        float px_ = xl * M00 + yl * M10 + zl * M20 + M30;
        float py_ = xl * M01 + yl * M11 + zl * M21 + M31;
        P[3 + 2 * k] = sigmoidf_(4.0f * ((px_ + 55.0f) * (1.0f / 110.0f) - 0.5f));
        P[4 + 2 * k] = sigmoidf_(4.0f * ((py_ + 55.0f) * (1.0f / 110.0f) - 0.5f));
      }
      float mu_n = mu * (1.0f / 55.0f);
      float sr = fmaxf(sd, 1e-6f);
      float saz = sa / C.az_step_f;
      float sel = se / stepw;
      klred[px] = 0.5f * (mu_n * mu_n + sr * sr - logf(sr * sr) - 1.0f) +
                  0.5f * (saz * saz - logf(saz * saz) - 1.0f) +
                  0.5f * (sel * sel - logf(sel * sel) - 1.0f);
    }
  }
  __syncthreads();
  if (tid == 0) {
    float sL = 0.f;
    for (int i = 0; i < 64; i++) sL += klred[i];
    klpart[b * 256 + blockIdx.x] = sL;
  }
  int wave = tid >> 6, l = tid & 63;
  int lr = l & 15, lk = l >> 4;
  f32x4 acc[8];
#pragma unroll
  for (int nt = 0; nt < 8; nt++) {
    int n = nt * 16 + lr;
    float wt[6];
#pragma unroll
    for (int c = 0; c < 6; c++) wt[c] = qs_w1f[(size_t)n * 134 + 128 + c];
    float bias = qs_b1[n];
#pragma unroll
    for (int r = 0; r < 4; r++) {
      int pl = wave * 16 + lk * 4 + r;
      float a = bias;
#pragma unroll
      for (int c = 0; c < 6; c++) a += wt[c] * sigf[pl][c];
      acc[nt][r] = a;
    }
  }
#pragma unroll
  for (int ks = 0; ks < 4; ks++) {
    short8 a = *(const short8*)&qin[wave * 16 + lr][ks * 32 + lk * 8];
#pragma unroll
    for (int nt = 0; nt < 8; nt++) {
      short8 bv = *(const short8*)(qsW1p + (size_t)(nt * 16 + lr) * 128 + ks * 32 + lk * 8);
      acc[nt] = __builtin_amdgcn_mfma_f32_16x16x32_bf16(a, bv, acc[nt], 0, 0, 0);
    }
  }
#pragma unroll
  for (int nt = 0; nt < 8; nt++)
#pragma unroll
    for (int r = 0; r < 4; r++)
      hq[wave * 16 + lk * 4 + r][nt * 16 + lr] = f2bf(geluf(acc[nt][r]));
  __syncthreads();
#pragma unroll
  for (int nt = 0; nt < 8; nt++) {
    float bias = qs_b2[nt * 16 + lr];
    acc[nt] = (f32x4){bias, bias, bias, bias};
  }
#pragma unroll
  for (int ks = 0; ks < 4; ks++) {
    short8 a = *(const short8*)&hq[wave * 16 + lr][ks * 32 + lk * 8];
#pragma unroll
    for (int nt = 0; nt < 8; nt++) {
      short8 bv = *(const short8*)(qsW2p + (size_t)(nt * 16 + lr) * 128 + ks * 32 + lk * 8);
      acc[nt] = __builtin_amdgcn_mfma_f32_16x16x32_bf16(a, bv, acc[nt], 0, 0, 0);
    }
  }
#pragma unroll
  for (int nt = 0; nt < 8; nt++) {
    int n = nt * 16 + lr;
#pragma unroll
    for (int r = 0; r < 4; r++) {
      int p = n0 + wave * 16 + lk * 4 + r;
      query[((size_t)b * NPIX + p) * 128 + n] = f2bf(acc[nt][r]);
    }
  }
}

// ---------------- K4: pack weights to bf16 ----------------
__global__ __launch_bounds__(256) void k_pack(
    const float* __restrict__ val_w, const float* __restrict__ w_v,
    const float* __restrict__ b_v, const float* __restrict__ val_b,
    const float* __restrict__ off_w, const float* __restrict__ off_b,
    const float* __restrict__ aw_w, const float* __restrict__ aw_b,
    const float* __restrict__ out_w, const float* __restrict__ qs_w1,
    const float* __restrict__ qs_w2, const float* __restrict__ rh_w1,
    const float* __restrict__ w_q, const float* __restrict__ w_o,
    const float* __restrict__ rh_w2,
    unsigned short* __restrict__ wvv_bf, float* __restrict__ bvv,
    unsigned short* __restrict__ projW, float* __restrict__ projB,
    unsigned short* __restrict__ outW, unsigned short* __restrict__ qsW1p,
    unsigned short* __restrict__ qsW2p, unsigned short* __restrict__ rhW1p,
    unsigned short* __restrict__ wqp, unsigned short* __restrict__ woP,
    unsigned short* __restrict__ w2p) {
  int idx = blockIdx.x * 256 + threadIdx.x;
  if (idx < 16384) {
    int o = idx >> 7, c = idx & 127;
    float acc = 0.0f;
    for (int m = 0; m < 128; m++) acc += val_w[o * 128 + m] * w_v[m * 128 + c];
    wvv_bf[idx] = f2bf(acc);
  } else if (idx < 16512) {
    int o = idx - 16384;
    float acc = val_b[o];
    for (int m = 0; m < 128; m++) acc += val_w[o * 128 + m] * b_v[m];
    bvv[o] = acc;
  } else if (idx < 82048) {
    int j = idx - 16512;
    int r = j >> 7, c = j & 127;
    float w = (r < 320) ? off_w[r * 128 + c] : ((r < 480) ? aw_w[(r - 320) * 128 + c] : 0.0f);
    projW[j] = f2bf(w);
  } else if (idx < 82560) {
    int r = idx - 82048;
    projB[r] = (r < 320) ? off_b[r] : ((r < 480) ? aw_b[r - 320] : 0.0f);
  } else if (idx < 98944) {
    int j = idx - 82560;
    outW[j] = f2bf(out_w[j]);
  } else if (idx < 115328) {
    int j = idx - 98944;
    int r = j >> 7, c = j & 127;
    qsW1p[j] = f2bf(qs_w1[r * 134 + c]);
  } else if (idx < 131712) {
    int j = idx - 115328;
    qsW2p[j] = f2bf(qs_w2[j]);
  } else if (idx < 144000) {
    int j = idx - 131712;
    int r = j / 96, c = j - r * 96;
    rhW1p[j] = (c < 67) ? f2bf(rh_w1[r * 67 + c]) : 0;
  } else if (idx < 156288) {
    int j = idx - 144000;
    int r = j / 96, c = j - r * 96;
    wqp[j] = (c < 64) ? f2bf(w_q[r * 64 + c]) : 0;
  } else if (idx < 172672) {
    int j = idx - 156288;
    woP[j] = f2bf(w_o[j]);
  } else if (idx < 246400) {
    int j = idx - 172672;
    int kpos = j >> 13;
    int rem = j & 8191;
    int o = rem >> 7, c = rem & 127;
    int ky = kpos / 3, kx = kpos - ky * 3;
    w2p[j] = f2bf(rh_w2[((size_t)(o * 128 + c) * 3 + ky) * 3 + kx]);
  }
}

// ---------------- K5: MFMA value projection, [p][k] LDS + coalesced uint4 stores ----------------
// ash swizzle: byte ^= (((p>>2)^p)&15)<<4 ; vout swizzle: byte ^= (pl&15)<<4.
__device__ __forceinline__ int aswz(int p, int k) {
  int byte = (p << 8) + (k << 1);
  return byte ^ (((((p >> 2) ^ p)) & 15) << 4);
}
__device__ __forceinline__ int vswz(int pl, int n) {
  int byte = (pl << 8) + (n << 1);
  return byte ^ ((pl & 15) << 4);
}
__global__ __launch_bounds__(256) void k_value(
    const float* __restrict__ bev, const unsigned short* __restrict__ wvv_bf,
    const float* __restrict__ bvv, unsigned short* __restrict__ v) {
  __shared__ unsigned short ash[128 * 128];   // [p][k], 32 KB
  __shared__ unsigned short vout[64 * 128];   // [pl][n], 16 KB
  int b = blockIdx.y;
  int p0 = blockIdx.x * 128;
  int tid = threadIdx.x;
  // stage: 128 c-rows x 32 float4 (128 p) = 4096 items, 16 per thread; transpose to [p][c]
  for (int i = tid; i < 4096; i += 256) {
    int c = i >> 5;
    int p4 = (i & 31) * 4;
    int p = p0 + p4;
    float4 x;
    if (p + 3 < NBEV) {
      x = *(const float4*)(bev + ((size_t)b * 128 + c) * NBEV + p);
    } else {
      const float* row = bev + ((size_t)b * 128 + c) * NBEV;
      x.x = (p + 0 < NBEV) ? row[p + 0] : 0.0f;
      x.y = (p + 1 < NBEV) ? row[p + 1] : 0.0f;
      x.z = (p + 2 < NBEV) ? row[p + 2] : 0.0f;
      x.w = (p + 3 < NBEV) ? row[p + 3] : 0.0f;
    }
    unsigned short hv0 = f2bf(x.x), hv1 = f2bf(x.y), hv2 = f2bf(x.z), hv3 = f2bf(x.w);
    *(unsigned short*)((char*)ash + aswz(p4 + 0, c)) = hv0;
    *(unsigned short*)((char*)ash + aswz(p4 + 1, c)) = hv1;
    *(unsigned short*)((char*)ash + aswz(p4 + 2, c)) = hv2;
    *(unsigned short*)((char*)ash + aswz(p4 + 3, c)) = hv3;
  }
  __syncthreads();
  int wave = tid >> 6, l = tid & 63;
  int lr = l & 15, lk = l >> 4;
  for (int sub = 0; sub < 2; sub++) {
    int plb = sub * 64;
    int ploc = plb + wave * 16 + lr;
    f32x4 acc[8];
#pragma unroll
    for (int nt = 0; nt < 8; nt++) {
      float bias = bvv[nt * 16 + lr];
      acc[nt] = (f32x4){bias, bias, bias, bias};
    }
#pragma unroll
    for (int ks = 0; ks < 4; ks++) {
      int k0 = ks * 32 + lk * 8;
      short8 a = *(const short8*)((const char*)ash + aswz(ploc, k0));
#pragma unroll
      for (int nt = 0; nt < 8; nt++) {
        short8 bf = *(const short8*)(wvv_bf + (size_t)(nt * 16 + lr) * 128 + k0);
        acc[nt] = __builtin_amdgcn_mfma_f32_16x16x32_bf16(a, bf, acc[nt], 0, 0, 0);
      }
    }
#pragma unroll
    for (int nt = 0; nt < 8; nt++) {
      int n = nt * 16 + lr;
#pragma unroll
      for (int r = 0; r < 4; r++) {
        int pl = wave * 16 + lk * 4 + r;
        *(unsigned short*)((char*)vout + vswz(pl, n)) = f2bf(acc[nt][r]);
      }
    }
    __syncthreads();
    // coalesced store: 64 rows x 256B
#pragma unroll
    for (int j = 0; j < 4; j++) {
      int idx = tid + j * 256;
      int pl = idx >> 4;
      int ns = (idx & 15) * 8;
      uint4 val = *(const uint4*)((const char*)vout + vswz(pl, ns));
      int p = p0 + plb + pl;
      if (p < NBEV) *(uint4*)(v + ((size_t)b * NBEV + p) * 128 + ns) = val;
    }
    __syncthreads();
  }
}

// ---------------- K6: MFMA projection, query LDS-staged once, 4 n-chunks ----------------
__global__ __launch_bounds__(256) void k_proj(
    const unsigned short* __restrict__ query, const unsigned short* __restrict__ projW,
    const float* __restrict__ projB, unsigned short* __restrict__ proj) {
  __shared__ unsigned short qlds[64][136];
  int b = blockIdx.y;
  int p0b = blockIdx.x * 64;
  int tid = threadIdx.x;
  const unsigned short* src = query + ((size_t)b * NPIX + p0b) * 128;
  for (int i = tid; i < 1024; i += 256) {
    int p = i >> 4, c0 = (i & 15) * 8;
    *(uint4*)&qlds[p][c0] = *(const uint4*)(src + p * 128 + c0);
  }
  __syncthreads();
  int wave = tid >> 6, l = tid & 63;
  int lr = l & 15, lk = l >> 4;
  int p0 = p0b + wave * 16;
  for (int nc = 0; nc < 4; nc++) {
    int n0 = nc * 128;
    f32x4 acc[8];
#pragma unroll
    for (int nt = 0; nt < 8; nt++) {
      float bias = projB[n0 + nt * 16 + lr];
      acc[nt] = (f32x4){bias, bias, bias, bias};
    }
#pragma unroll
    for (int ks = 0; ks < 4; ks++) {
      short8 a = *(const short8*)&qlds[wave * 16 + lr][ks * 32 + lk * 8];
#pragma unroll
      for (int nt = 0; nt < 8; nt++) {
        short8 bf = *(const short8*)(projW + (size_t)(n0 + nt * 16 + lr) * 128 +
                                     ks * 32 + lk * 8);
        acc[nt] = __builtin_amdgcn_mfma_f32_16x16x32_bf16(a, bf, acc[nt], 0, 0, 0);
      }
    }
#pragma unroll
    for (int nt = 0; nt < 8; nt++) {
      int n = n0 + nt * 16 + lr;
#pragma unroll
      for (int r = 0; r < 4; r++) {
        int p = p0 + lk * 4 + r;
        proj[((size_t)b * NPIX + p) * 512 + n] = f2bf(acc[nt][r]);
      }
    }
  }
}

// ---------------- K7: sampler — 8 lanes per (pixel,head): tap-set x channel-half ----------------
__global__ __launch_bounds__(256) void k_samp(
    const unsigned short* __restrict__ proj, const float* __restrict__ params,
    const unsigned short* __restrict__ v, unsigned short* __restrict__ S) {
  int b = blockIdx.y;
  int bid = blockIdx.x;
  int pb = (bid & 7) * 512 + (bid >> 3);
  int tid = threadIdx.x;
  int g = tid & 7;
  int hh = (tid >> 3) & 7;
  int pl = tid >> 6;
  int ts = g >> 1, th = g & 1;
  int n = pb * 4 + pl;
  const unsigned short* base = proj + ((size_t)b * NPIX + n) * 512;
  float lg[5];
#pragma unroll
  for (int t = 0; t < 5; t++) lg[t] = bf2f(base[320 + hh * 20 + ts * 5 + t]);
  float mx = fmaxf(fmaxf(fmaxf(lg[0], lg[1]), fmaxf(lg[2], lg[3])), lg[4]);
  mx = fmaxf(mx, __shfl_xor(mx, 2));
  mx = fmaxf(mx, __shfl_xor(mx, 4));
  float e[5];
  float s = 0.0f;
#pragma unroll
  for (int t = 0; t < 5; t++) { e[t] = expf(lg[t] - mx); s += e[t]; }
  s += __shfl_xor(s, 2);
  s += __shfl_xor(s, 4);
  float rs = 1.0f / s;
  const float* P = params + ((size_t)b * NPIX + n) * 16;
  const unsigned short* vb = v + (size_t)b * NBEV * 128 + hh * 16 + th * 8;
  float acc[8];
#pragma unroll
  for (int c = 0; c < 8; c++) acc[c] = 0.0f;
#pragma unroll
  for (int t = 0; t < 5; t++) {
    int kp = ts * 5 + t;
    int k = kp >> 2;
    unsigned int u = *(const unsigned int*)(base + hh * 40 + kp * 2);
    float X = P[3 + 2 * k] * 220.0f - 0.5f + bf2f((unsigned short)(u & 0xffffu));
    float Y = P[4 + 2 * k] * 220.0f - 0.5f + bf2f((unsigned short)(u >> 16));
    float xf = floorf(X), yf = floorf(Y);
    float wx = X - xf, wy = Y - yf;
    int x0 = (int)xf, y0 = (int)yf;
    float wx0 = ((unsigned)x0 < 220u) ? (1.0f - wx) : 0.0f;
    float wx1 = ((unsigned)(x0 + 1) < 220u) ? wx : 0.0f;
    float wy0 = ((unsigned)y0 < 220u) ? (1.0f - wy) : 0.0f;
    float wy1 = ((unsigned)(y0 + 1) < 220u) ? wy : 0.0f;
    int cx0 = min(max(x0, 0), 219), cx1 = min(max(x0 + 1, 0), 219);
    int cy0 = min(max(y0, 0), 219) * 220, cy1 = min(max(y0 + 1, 0), 219) * 220;
    float a = e[t] * rs;
    float u0 = a * wy0, u1 = a * wy1;
    float w4[4] = {u0 * wx0, u0 * wx1, u1 * wx0, u1 * wx1};
    int i4[4] = {cy0 + cx0, cy0 + cx1, cy1 + cx0, cy1 + cx1};
#pragma unroll
    for (int c2 = 0; c2 < 4; c2++) {
      float w = w4[c2];
      const uint2* sp = (const uint2*)(vb + (size_t)i4[c2] * 128);
      uint2 r0 = sp[0], r1 = sp[1];
      acc[0] += w * bf2f((unsigned short)(r0.x & 0xffffu));
      acc[1] += w * bf2f((unsigned short)(r0.x >> 16));
      acc[2] += w * bf2f((unsigned short)(r0.y & 0xffffu));
      acc[3] += w * bf2f((unsigned short)(r0.y >> 16));
      acc[4] += w * bf2f((unsigned short)(r1.x & 0xffffu));
      acc[5] += w * bf2f((unsigned short)(r1.x >> 16));
      acc[6] += w * bf2f((unsigned short)(r1.y & 0xffffu));
      acc[7] += w * bf2f((unsigned short)(r1.y >> 16));
    }
  }
#pragma unroll
  for (int c = 0; c < 8; c++) {
    acc[c] += __shfl_xor(acc[c], 2);
    acc[c] += __shfl_xor(acc[c], 4);
  }
  if (ts == 0) {
    uint4 o1;
    o1.x = (unsigned int)f2bf(acc[0]) | ((unsigned int)f2bf(acc[1]) << 16);
    o1.y = (unsigned int)f2bf(acc[2]) | ((unsigned int)f2bf(acc[3]) << 16);
    o1.z = (unsigned int)f2bf(acc[4]) | ((unsigned int)f2bf(acc[5]) << 16);
    o1.w = (unsigned int)f2bf(acc[6]) | ((unsigned int)f2bf(acc[7]) << 16);
    *(uint4*)(S + ((size_t)b * NPIX + n) * 128 + hh * 16 + th * 8) = o1;
  }
}

// ---------------- K8: fused out-proj + residual + final conv1x1 + NCHW store + KL ----------------
__global__ __launch_bounds__(256) void k_outfinal(
    const unsigned short* __restrict__ S, const unsigned short* __restrict__ outW,
    const float* __restrict__ out_b, const unsigned short* __restrict__ query,
    const unsigned short* __restrict__ woP, const float* __restrict__ b_o,
    const float* __restrict__ klpart, float* __restrict__ out) {
  __shared__ unsigned short ylds[64][136];
  __shared__ float yt[128][67];
  int b = blockIdx.y;
  int p0b = blockIdx.x * 64;
  int tid = threadIdx.x;
  int wave = tid >> 6, l = tid & 63;
  int lr = l & 15, lk = l >> 4;
  {
    f32x4 acc[8];
#pragma unroll
    for (int nt = 0; nt < 8; nt++) {
      float bias = out_b[nt * 16 + lr];
      acc[nt] = (f32x4){bias, bias, bias, bias};
    }
    const unsigned short* ap = S + ((size_t)b * NPIX + p0b + wave * 16 + lr) * 128 + lk * 8;
#pragma unroll
    for (int ks = 0; ks < 4; ks++) {
      short8 a = *(const short8*)(ap + ks * 32);
#pragma unroll
      for (int nt = 0; nt < 8; nt++) {
        short8 bf = *(const short8*)(outW + (size_t)(nt * 16 + lr) * 128 + ks * 32 + lk * 8);
        acc[nt] = __builtin_amdgcn_mfma_f32_16x16x32_bf16(a, bf, acc[nt], 0, 0, 0);
      }
    }
#pragma unroll
    for (int nt = 0; nt < 8; nt++) {
      int n = nt * 16 + lr;
#pragma unroll
      for (int r = 0; r < 4; r++) {
        int p_local = wave * 16 + lk * 4 + r;
        size_t o = ((size_t)b * NPIX + p0b + p_local) * 128 + n;
        ylds[p_local][n] = f2bf(acc[nt][r] + bf2f(query[o]));
      }
    }
  }
  __syncthreads();
  {
    f32x4 acc[8];
#pragma unroll
    for (int nt = 0; nt < 8; nt++) {
      float bias = b_o[nt * 16 + lr];
      acc[nt] = (f32x4){bias, bias, bias, bias};
    }
#pragma unroll
    for (int ks = 0; ks < 4; ks++) {
      short8 a = *(const short8*)&ylds[wave * 16 + lr][ks * 32 + lk * 8];
#pragma unroll
      for (int nt = 0; nt < 8; nt++) {
        short8 bf = *(const short8*)(woP + (size_t)(nt * 16 + lr) * 128 + ks * 32 + lk * 8);
        acc[nt] = __builtin_amdgcn_mfma_f32_16x16x32_bf16(a, bf, acc[nt], 0, 0, 0);
      }
    }
#pragma unroll
    for (int nt = 0; nt < 8; nt++)
#pragma unroll
      for (int r = 0; r < 4; r++)
        yt[nt * 16 + lr][wave * 16 + lk * 4 + r] = acc[nt][r];
  }
  __syncthreads();
  int n = tid >> 1, half = tid & 1;
  float* dst = out + ((size_t)(b * 128 + n)) * NPIX + p0b + half * 32;
#pragma unroll
  for (int j = 0; j < 8; j++) {
    float4 v4 = {yt[n][half * 32 + j * 4], yt[n][half * 32 + j * 4 + 1],
                 yt[n][half * 32 + j * 4 + 2], yt[n][half * 32 + j * 4 + 3]};
    *(float4*)(dst + j * 4) = v4;
  }
  if (blockIdx.x == 0 && b == 0 && tid == 0) {
    float sL = 0.0f;
    for (int i = 0; i < 512; i++) sL += klpart[i];
    out[(size_t)BSZ * 128 * NPIX] = 1e-4f * (sL / 32768.0f);
  }
}

// ---------------- host ----------------
static RVConsts make_consts() {
  static const float ELEV[32] = {
      -30.67f, -29.33f, -28.0f, -26.66f, -25.33f, -24.0f, -22.67f, -21.33f,
      -20.0f,  -18.67f, -17.33f, -16.0f, -14.67f, -13.33f, -12.0f, -10.67f,
      -9.33f,  -8.0f,   -6.66f,  -5.33f, -4.0f,   -2.67f,  -1.33f, 0.0f,
      1.33f,   2.67f,   4.0f,    5.33f,  6.67f,   8.0f,    9.33f,  10.67f};
  RVConsts C;
  const float d2r = 0.017453292519943295f;
  for (int r = 0; r < 16; r++) {
    float a = ELEV[31 - 2 * r], b = ELEV[30 - 2 * r];
    float mx = fmaxf(a, b), mn = fminf(a, b);
    C.steps[r] = (mx - mn) * d2r;
    C.means[r] = ((a + b) * 0.5f) * d2r;
  }
  const double PI_D = 3.14159265358979323846;
  double step_d = (PI_D - (-PI_D)) / 1024.0;
  double az0 = -PI_D;
  double az1 = az0 + step_d;
  double az_step_d = az1 - az0;
  C.az_step_f = (float)az_step_d;
  C.pad_ = 0.0f;
  C.step_d = step_d;
  C.az0 = az0;
  C.az_half = az_step_d * 0.5;
  return C;
}

// Workspace layout (f32 words). Peak 21,632,128 words = 86.5 MB.
#define OFF_T1     0u
#define OFF_T2     8388608u
#define OFF_Q0     10485760u
#define OFF_PARAMS 14680064u
#define OFF_QUERY  15204352u
#define OFF_S      19398656u
#define OFF_SUMS1  21495808u
#define OFF_SUMS2  21504000u
#define OFF_KL     21508096u
#define OFF_PROJ   0u
#define OFF_V      8388608u
#define OFF_WVV    21508608u
#define OFF_BVV    21516800u
#define OFF_PROJW  21516928u
#define OFF_PROJB  21549696u
#define OFF_OUTW   21550208u
#define OFF_QSW1   21558400u
#define OFF_QSW2   21566592u
#define OFF_RHW1   21574784u
#define OFF_WQP    21580928u
#define OFF_WOP    21587072u
#define OFF_W2P    21595264u

extern "C" void kernel_launch(void* const* d_in, const int* in_sizes, int n_in,
                              void* d_out, int out_size, void* d_ws, size_t ws_size,
                              hipStream_t stream) {
  const float* x_rv = (const float*)d_in[0];
  const float* bev = (const float*)d_in[1];
  const float* l2e = (const float*)d_in[2];
  const float* w_q = (const float*)d_in[3];
  const float* b_q = (const float*)d_in[4];
  const float* w_v = (const float*)d_in[5];
  const float* b_v = (const float*)d_in[6];
  const float* w_o = (const float*)d_in[7];
  const float* b_o = (const float*)d_in[8];
  const float* qs_w1 = (const float*)d_in[9];
  const float* qs_b1 = (const float*)d_in[10];
  const float* qs_w2 = (const float*)d_in[11];
  const float* qs_b2 = (const float*)d_in[12];
  const float* rh_w1 = (const float*)d_in[13];
  const float* rh_b1 = (const float*)d_in[14];
  const float* rh_g1 = (const float*)d_in[15];
  const float* rh_bt1 = (const float*)d_in[16];
  const float* rh_w2 = (const float*)d_in[17];
  const float* rh_g2 = (const float*)d_in[18];
  const float* rh_bt2 = (const float*)d_in[19];
  const float* rh_w3 = (const float*)d_in[20];
  const float* rh_b3 = (const float*)d_in[21];
  const float* off_w = (const float*)d_in[22];
  const float* off_b = (const float*)d_in[23];
  const float* aw_w = (const float*)d_in[24];
  const float* aw_b = (const float*)d_in[25];
  const float* val_w = (const float*)d_in[26];
  const float* val_b = (const float*)d_in[27];
  const float* out_w = (const float*)d_in[28];
  const float* out_b = (const float*)d_in[29];

  float* ws = (float*)d_ws;
  float* t1 = ws + OFF_T1;
  float* t2 = ws + OFF_T2;
  float* params = ws + OFF_PARAMS;
  float* sums1 = ws + OFF_SUMS1;
  float* sums2 = ws + OFF_SUMS2;
  float* klpart = ws + OFF_KL;
  float* bvv = ws + OFF_BVV;
  float* projB = ws + OFF_PROJB;
  unsigned short* q0bf = (unsigned short*)(ws + OFF_Q0);
  unsigned short* querybf = (unsigned short*)(ws + OFF_QUERY);
  unsigned short* S_bf = (unsigned short*)(ws + OFF_S);
  unsigned short* proj_bf = (unsigned short*)(ws + OFF_PROJ);
  unsigned short* v_bf = (unsigned short*)(ws + OFF_V);
  unsigned short* wvv_bf = (unsigned short*)(ws + OFF_WVV);
  unsigned short* projW = (unsigned short*)(ws + OFF_PROJW);
  unsigned short* outW = (unsigned short*)(ws + OFF_OUTW);
  unsigned short* qsW1p = (unsigned short*)(ws + OFF_QSW1);
  unsigned short* qsW2p = (unsigned short*)(ws + OFF_QSW2);
  unsigned short* rhW1p = (unsigned short*)(ws + OFF_RHW1);
  unsigned short* wqp = (unsigned short*)(ws + OFF_WQP);
  unsigned short* woP = (unsigned short*)(ws + OFF_WOP);
  unsigned short* w2p = (unsigned short*)(ws + OFF_W2P);

  RVConsts C = make_consts();
  dim3 blk(256);

  k_pack<<<963, blk, 0, stream>>>(val_w, w_v, b_v, val_b, off_w, off_b, aw_w, aw_b, out_w,
                                  qs_w1, qs_w2, rh_w1, w_q, w_o, rh_w2,
                                  wvv_bf, bvv, projW, projB, outW, qsW1p, qsW2p, rhW1p,
                                  wqp, woP, w2p);
  k_rh1_q0<<<dim3(256, BSZ), blk, 0, stream>>>(x_rv, rhW1p, rh_b1, wqp, b_q, t1, q0bf,
                                               sums1, C);
  k_conv3g<<<dim3(128, BSZ), blk, 0, stream>>>(t1, sums1, rh_g1, rh_bt1, w2p, t2, sums2);
  k_headquery<<<dim3(256, BSZ), blk, 0, stream>>>(t2, sums2, rh_g2, rh_bt2, rh_w3, rh_b3,
                                                  l2e, q0bf, qsW1p, qs_b1, qs_w1, qsW2p,
                                                  qs_b2, params, klpart, querybf, C);
  k_value<<<dim3(379, BSZ), blk, 0, stream>>>(bev, wvv_bf, bvv, v_bf);
  k_proj<<<dim3(256, BSZ), blk, 0, stream>>>(querybf, projW, projB, proj_bf);
  k_samp<<<dim3(4096, BSZ), blk, 0, stream>>>(proj_bf, params, v_bf, S_bf);
  k_outfinal<<<dim3(256, BSZ), blk, 0, stream>>>(S_bf, outW, out_b, querybf, woP, b_o,
                                                 klpart, (float*)d_out);
}